// Round 15
// baseline (996.447 us; speedup 1.0000x reference)
//
#include <hip/hip_runtime.h>
#include <hip/hip_bf16.h>

typedef __attribute__((ext_vector_type(8))) short short8;
typedef __attribute__((ext_vector_type(4))) float f32x4;
typedef __hip_bfloat16 bf16;

#define QLEN 512
#define MLEN 512
#define KLEN 1024
#define BSZ  4
#define DM   1024
#define NH   16
#define DH   64
#define DI   4096
#define NL   4
#define KEMB 1408   // 1024 + 256 + 64 + 16 = 1360, padded to 1408 (x32)

// direct global->LDS DMA, 16 B per lane (wave-uniform LDS base + lane*16)
__device__ __forceinline__ void gload16(const bf16* g, const void* l) {
  __builtin_amdgcn_global_load_lds(
      (const __attribute__((address_space(1))) void*)g,
      (__attribute__((address_space(3))) void*)l, 16, 0, 0);
}

__device__ __forceinline__ bf16 bits2bf(short s) { bf16 h; *(short*)&h = s; return h; }

// ================= adaptive embedding as GEMM: gather A rows (2048 x KEMB, bf16) =================
__global__ __launch_bounds__(256) void embA_kernel(
    const int* __restrict__ ids,
    const float* __restrict__ e0, const float* __restrict__ e1,
    const float* __restrict__ e2, const float* __restrict__ e3,
    bf16* __restrict__ Aemb)
{
  const int t = blockIdx.x;          // t = q*BSZ + b
  const int q = t >> 2, b = t & 3;
  const int id = ids[b * QLEN + q];
  const float* tab; int d, off, koff;
  if (id < 20000)       { tab = e0; d = 1024; off = 0;      koff = 0; }
  else if (id < 40000)  { tab = e1; d = 256;  off = 20000;  koff = 1024; }
  else if (id < 200000) { tab = e2; d = 64;   off = 40000;  koff = 1280; }
  else                  { tab = e3; d = 16;   off = 200000; koff = 1344; }
  bf16* row = Aemb + (long)t * KEMB;
  const float* tr = tab + (long)(id - off) * d;
  for (int k = threadIdx.x; k < KEMB; k += 256) {
    const int kk = k - koff;
    float v = 0.f;
    if (kk >= 0 && kk < d) v = tr[kk];
    row[k] = __float2bfloat16(v);
  }
}

// ================= concat proj^T: projT[n][k] (1024 x KEMB, bf16), zero-padded =================
__global__ __launch_bounds__(256) void projT_kernel(
    const float* __restrict__ p0, const float* __restrict__ p1,
    const float* __restrict__ p2, const float* __restrict__ p3,
    bf16* __restrict__ out)
{
  __shared__ float t[32][33];
  const int k0 = blockIdx.x * 32, n0 = blockIdx.y * 32;
  const int nx = threadIdx.x & 31, ky = threadIdx.x >> 5;
#pragma unroll
  for (int p = 0; p < 4; ++p) {
    const int k = k0 + ky + p * 8;
    float v = 0.f;
    if (k < 1024)       v = p0[(long)k * 1024 + n0 + nx];
    else if (k < 1280)  v = p1[(long)(k - 1024) * 1024 + n0 + nx];
    else if (k < 1344)  v = p2[(long)(k - 1280) * 1024 + n0 + nx];
    else if (k < 1360)  v = p3[(long)(k - 1344) * 1024 + n0 + nx];
    t[ky + p * 8][nx] = v;
  }
  __syncthreads();
#pragma unroll
  for (int p = 0; p < 4; ++p)
    out[(long)(n0 + ky + p * 8) * KEMB + k0 + nx] = __float2bfloat16(t[nx][ky + p * 8]);
}

// ================= sum 2 fp32 partials -> h fp32 + cat bf16 (upper) =================
__global__ __launch_bounds__(256) void embsum_kernel(const float* __restrict__ part,
                                                     float* __restrict__ h, bf16* __restrict__ cat)
{
  const long i = ((long)blockIdx.x * 256 + threadIdx.x) * 4;
  const float4 a = *(const float4*)(part + i);
  const float4 b = *(const float4*)(part + 2097152 + i);
  float4 s; s.x = a.x + b.x; s.y = a.y + b.y; s.z = a.z + b.z; s.w = a.w + b.w;
  *(float4*)(h + i) = s;
  bf16* cr = cat + (long)2048 * 1024 + i;
  cr[0] = __float2bfloat16(s.x); cr[1] = __float2bfloat16(s.y);
  cr[2] = __float2bfloat16(s.z); cr[3] = __float2bfloat16(s.w);
}

// ================= sinusoidal pos emb -> bf16 =================
__global__ __launch_bounds__(256) void posemb_kernel(bf16* __restrict__ pe)
{
  const int j = blockIdx.x;
  const float pos = (float)(KLEN - 1 - j);
  for (int i = threadIdx.x; i < DM / 2; i += 256) {
    const float freq = expf(-9.210340371976184f * ((float)(2 * i) / (float)DM));
    const float ang = pos * freq;
    pe[(long)j * DM + i]          = __float2bfloat16(sinf(ang));
    pe[(long)j * DM + DM / 2 + i] = __float2bfloat16(cosf(ang));
  }
}

// ================= fp32 (R x C) -> bf16 transposed (C x R), z = layer =================
__global__ __launch_bounds__(256) void wtrans_kernel(const float* __restrict__ in,
                                                     bf16* __restrict__ out, int R, int C)
{
  __shared__ float t[32][33];
  in  += (long)blockIdx.z * R * C;
  out += (long)blockIdx.z * R * C;
  const int c0 = blockIdx.x * 32, r0 = blockIdx.y * 32;
  const int cx = threadIdx.x & 31, ry = threadIdx.x >> 5;
#pragma unroll
  for (int p = 0; p < 4; ++p)
    t[ry + p * 8][cx] = in[(long)(r0 + ry + p * 8) * C + c0 + cx];
  __syncthreads();
#pragma unroll
  for (int p = 0; p < 4; ++p)
    out[(long)(c0 + ry + p * 8) * R + r0 + cx] = __float2bfloat16(t[cx][ry + p * 8]);
}

// ================= all mems (NL x 2048 x 1024 fp32) -> lower halves of cats[l] =================
__global__ __launch_bounds__(256) void memsconv_kernel(const float* __restrict__ mems,
                                                       bf16* __restrict__ cat0)
{
  const long i = ((long)blockIdx.x * 256 + threadIdx.x) * 4;   // over NL*2048*1024
  const long l = i >> 21, rem = i & ((1 << 21) - 1);
  const float4 v = *(const float4*)(mems + i);
  bf16* dst = cat0 + l * 4194304 + rem;
  dst[0] = __float2bfloat16(v.x); dst[1] = __float2bfloat16(v.y);
  dst[2] = __float2bfloat16(v.z); dst[3] = __float2bfloat16(v.w);
}

// ================= bf16 MFMA GEMM:  C = scale*(A @ B^T_supplied + colbias)  =================
template<int BM, int BN>
__global__ __launch_bounds__(256) void gemm_bf16(
    const bf16* __restrict__ A, long aStrB, long aStrN, int lda,
    const bf16* __restrict__ B, long bStrB, long bStrN, int ldb,
    void* __restrict__ C, long cStrB, long cStrN, int ldc,
    int K, float scale, const float* __restrict__ bias, long biasStrB, long biasStrN,
    int flags, int zN, int zSplit, long cSplitStr)
{
  constexpr int RA = BM / 64, RB = BN / 64, FM = BM / 32, FN = BN / 32;
  __shared__ __align__(16) bf16 As[2][BM * 32];
  __shared__ __align__(16) bf16 Bs[2][BN * 32];
  const int zc = blockIdx.z % zSplit, zt = blockIdx.z / zSplit;
  const int zn = zt % zN, zb = zt / zN;
  A += (long)zb * aStrB + (long)zn * aStrN + (long)zc * K;
  B += (long)zb * bStrB + (long)zn * bStrN + (long)zc * K;
  const int tid = threadIdx.x, lane = tid & 63;
  const int w = tid >> 6, wr = w >> 1, wc = w & 1;
  const int m0 = blockIdx.y * BM, n0 = blockIdx.x * BN;
  const int l15 = lane & 15, l4 = lane >> 4;
  const int rowS = tid >> 2;
  const int cbS  = (tid & 3) * 16;
  const int swS  = cbS ^ (((rowS >> 1) & 3) << 4);
  const int wbase = w * 1024;
  const bf16* Ast = A + (size_t)(m0 + rowS) * lda + (swS >> 1);
  const bf16* Bst = B + (size_t)(n0 + rowS) * ldb + (swS >> 1);

#define STAGE_TILE(buf, kk)                                                       \
  {                                                                               \
    _Pragma("unroll")                                                             \
    for (int r = 0; r < RA; ++r)                                                  \
      gload16(Ast + (size_t)(r * 64) * lda + (kk), (char*)As[buf] + r * 4096 + wbase); \
    _Pragma("unroll")                                                             \
    for (int r = 0; r < RB; ++r)                                                  \
      gload16(Bst + (size_t)(r * 64) * ldb + (kk), (char*)Bs[buf] + r * 4096 + wbase); \
  }

  f32x4 acc[FM][FN] = {};
  STAGE_TILE(0, 0)
  asm volatile("s_waitcnt vmcnt(0)" ::: "memory");
  __syncthreads();
  int cur = 0;
  for (int k0 = 0; k0 < K; k0 += 32) {
    if (k0 + 32 < K) {
      if (cur == 0) STAGE_TILE(1, k0 + 32)
      else          STAGE_TILE(0, k0 + 32)
    }
    short8 af[FM], bfr[FN];
#pragma unroll
    for (int f = 0; f < FM; ++f) {
      const int row = wr * (BM / 2) + f * 16 + l15;
      af[f] = *(const short8*)((char*)As[cur] + row * 64 + ((16 * l4) ^ (((row >> 1) & 3) << 4)));
    }
#pragma unroll
    for (int f = 0; f < FN; ++f) {
      const int row = wc * (BN / 2) + f * 16 + l15;
      bfr[f] = *(const short8*)((char*)Bs[cur] + row * 64 + ((16 * l4) ^ (((row >> 1) & 3) << 4)));
    }
#pragma unroll
    for (int fm = 0; fm < FM; ++fm)
#pragma unroll
      for (int fn = 0; fn < FN; ++fn)
        acc[fm][fn] = __builtin_amdgcn_mfma_f32_16x16x32_bf16(af[fm], bfr[fn], acc[fm][fn], 0, 0, 0);
    asm volatile("s_waitcnt vmcnt(0)" ::: "memory");
    __syncthreads();
    cur ^= 1;
  }
#undef STAGE_TILE
  const int outbf = flags & 1, relu = flags & 4;
#pragma unroll
  for (int fm = 0; fm < FM; ++fm) {
#pragma unroll
    for (int fn = 0; fn < FN; ++fn) {
      const int col = n0 + wc * (BN / 2) + fn * 16 + l15;
      const int rw0 = m0 + wr * (BM / 2) + fm * 16 + l4 * 4;
      const float bv = (bias && zc == 0) ? bias[(size_t)zb * biasStrB + (size_t)zn * biasStrN + col] : 0.f;
#pragma unroll
      for (int r = 0; r < 4; ++r) {
        float v = (acc[fm][fn][r] + bv) * scale;
        if (relu) v = fmaxf(v, 0.f);
        const int row = rw0 + r;
        const size_t cOff = (size_t)zb * cStrB + (size_t)zn * cStrN + (size_t)zc * cSplitStr;
        if (outbf) {
          ((bf16*)C + cOff)[(size_t)row * ldc + col] = __float2bfloat16(v);
        } else {
          ((float*)C + cOff)[(size_t)row * ldc + col] = v;
        }
      }
    }
  }
}

// ================= V transpose (j-tile blocked) + K pack =================
__global__ __launch_bounds__(256) void vt_kernel(const bf16* __restrict__ wh,
                                                 bf16* __restrict__ vt, bf16* __restrict__ kb)
{
  const int bn = blockIdx.y, b = bn >> 4, n = bn & 15;
  const int j0 = blockIdx.x * 64;
  __shared__ bf16 t[64][72];
  const bf16* src = wh + (size_t)b * 3072 + 2048 + n * 64;
  const bf16* ksrc = wh + (size_t)b * 3072 + 1024 + n * 64;
  bf16* kdst = kb + (size_t)bn * 65536;
  const int tid = threadIdx.x;
#pragma unroll
  for (int r = 0; r < 16; ++r) {
    const int jl = r * 4 + (tid >> 6), d = tid & 63;
    t[jl][d] = src[(size_t)(j0 + jl) * 12288 + d];
    kdst[(size_t)(j0 + jl) * 64 + d] = ksrc[(size_t)(j0 + jl) * 12288 + d];
  }
  __syncthreads();
  bf16* dst = vt + (size_t)bn * 65536 + (size_t)j0 * 64;   // block [d][64]
#pragma unroll
  for (int r = 0; r < 16; ++r) {
    const int d = r * 4 + (tid >> 6), j = tid & 63;
    dst[(size_t)d * 64 + j] = t[j][d];
  }
}

// ================= rk repack: rkn[l][n][p][64] =================
__global__ __launch_bounds__(256) void rkpack_kernel(const bf16* __restrict__ rkb,
                                                     bf16* __restrict__ rkn)
{
  const int ln = blockIdx.y, l = ln >> 4, n = ln & 15;
  const int p0 = blockIdx.x * 64;
  const int d = threadIdx.x & 63, pr = threadIdx.x >> 6;
  const bf16* src = rkb + (size_t)l * 1048576 + n * 64 + d;
  bf16* dst = rkn + (size_t)ln * 65536 + d;
#pragma unroll
  for (int r = 0; r < 16; ++r) {
    const int p = p0 + r * 4 + pr;
    dst[(size_t)p * 64] = src[(size_t)p * 1024];
  }
}

// ================= fused flash attention, split-KV x4, DOUBLE-BUFFERED LDS staging =================
// grid (64 bn, 8 q-tiles, 4 ck). Per j-tile the WG stages K (8 KB) + V (8 KB) +
// rk band (16 KB) once; staging for tile t+4 is issued into buffer cur^1 BEFORE
// computing on cur (2-phase pipeline, single vmcnt(0)+barrier per tile after
// compute) — hides the L2 staging latency under AC/BD/softmax/PV.
// Tl/Pl scratch are UNIONED (disjoint phases of the same wave) to fit 2 WG/CU.
__global__ __launch_bounds__(256) void fattn_kernel(
    const bf16* __restrict__ wh,     // 4096 x 3072 (row = 4*token + b) — Q only
    const bf16* __restrict__ kb,     // [bn][1024 j][64 d]
    const bf16* __restrict__ rkn_l,  // [16 n][1024 p][64 d] (this layer, 16 KB guard after)
    const bf16* __restrict__ vt,     // [bn][16 jt][64 d][64 jl]
    const float* __restrict__ rwb,   // 16 x 64 (this layer)
    const float* __restrict__ rrb,   // 16 x 64
    float* __restrict__ po, float* __restrict__ pm, float* __restrict__ pl)
{
  const int bn = blockIdx.x, b = bn >> 4, n = bn & 15;
  const int q0 = blockIdx.y * 64;
  const int ck = blockIdx.z;
  const int tid = threadIdx.x, w = tid >> 6, lane = tid & 63;
  const int l15 = lane & 15, l4 = lane >> 4;
  __shared__ __align__(16) bf16 Ks[2][64 * 64];    // 16 KB  [buf][row j][128 B]
  __shared__ __align__(16) bf16 Vs[2][64 * 64];    // 16 KB  [buf][row d][128 B]
  __shared__ __align__(16) bf16 Rs[2][128 * 64];   // 32 KB  [buf][row p-pstart][128 B]
  __shared__ bf16 TP[4][16][84];                   // wave-private union: BD-shift strips / P staging

  // ---- load Q fragments, fold biases AND 0.125 scale (exact 2^-3) ----
  short8 qa[2], qb[2];
  {
    const bf16* qp = wh + (size_t)(2048 + b) * 3072 + (size_t)(q0 + 16 * w + l15) * 12288 + n * 64;
#pragma unroll
    for (int kk = 0; kk < 2; ++kk) {
      const short8 qv = *(const short8*)(qp + kk * 32 + 8 * l4);
      const float* wv = rwb + n * 64 + kk * 32 + 8 * l4;
      const float* rv = rrb + n * 64 + kk * 32 + 8 * l4;
      short8 a, c;
#pragma unroll
      for (int e = 0; e < 8; ++e) {
        const float q = __bfloat162float(bits2bf(qv[e]));
        const bf16 ab = __float2bfloat16((q + wv[e]) * 0.125f);
        const bf16 cb = __float2bfloat16((q + rv[e]) * 0.125f);
        a[e] = *(const short*)&ab;  c[e] = *(const short*)&cb;
      }
      qa[kk] = a; qb[kk] = c;
    }
  }

  const bf16* kbase = kb + (size_t)bn * 65536;                  // + j*64
  const bf16* rbase = rkn_l + (size_t)n * 65536;                // + p*64
  const bf16* vbase = vt + (size_t)bn * 65536;                  // + j0*64 + d*64 + jl
  const int ntiles = 9 + (q0 >> 6);

  // staging geometry: thread tid covers linear LDS bytes [tid*16, tid*16+16) per 4 KB slab
  const int stRow0 = tid >> 3;                  // row within 4 KB slab (32 rows/slab)
  const int stColb = (tid & 7) * 16;
  const int wbase = w * 1024;                   // wave-uniform LDS base within slab
  const int srd = (l15 & 7) << 4;               // read-side swizzle (== row&7 <<4 for all reads)

#define FA_STAGE(buf, j0s)                                                                   \
  {                                                                                          \
    const int psrt = (j0s) - q0 + 448;                                                       \
    _Pragma("unroll")                                                                        \
    for (int r = 0; r < 2; ++r) {                                                            \
      const int row = r * 32 + stRow0;                                                       \
      gload16(kbase + (size_t)((j0s) + row) * 64 + ((stColb ^ ((row & 7) << 4)) >> 1),       \
              (char*)Ks + (buf) * 8192 + r * 4096 + wbase);                                  \
    }                                                                                        \
    _Pragma("unroll")                                                                        \
    for (int r = 0; r < 2; ++r) {                                                            \
      const int row = r * 32 + stRow0;                                                       \
      gload16(vbase + (size_t)(j0s) * 64 + (size_t)row * 64 + ((stColb ^ ((row & 7) << 4)) >> 1), \
              (char*)Vs + (buf) * 8192 + r * 4096 + wbase);                                  \
    }                                                                                        \
    _Pragma("unroll")                                                                        \
    for (int r = 0; r < 4; ++r) {                                                            \
      const int row = r * 32 + stRow0;                                                       \
      gload16(rbase + (size_t)(psrt + row) * 64 + ((stColb ^ ((row & 7) << 4)) >> 1),        \
              (char*)Rs + (buf) * 16384 + r * 4096 + wbase);                                 \
    }                                                                                        \
  }

  f32x4 accO[4] = {};
  float mrow[4] = { -1e30f, -1e30f, -1e30f, -1e30f };
  float lrow[4] = { 0.f, 0.f, 0.f, 0.f };

  FA_STAGE(0, ck * 64)
  asm volatile("s_waitcnt vmcnt(0)" ::: "memory");
  __syncthreads();
  int cur = 0;

  for (int t = ck; t < ntiles; t += 4) {
    const int j0 = t * 64;
    // ---- prefetch next tile into the other buffer (no wait) ----
    if (t + 4 < ntiles) {
      if (cur == 0) FA_STAGE(1, (t + 4) * 64)
      else          FA_STAGE(0, (t + 4) * 64)
    }
    // ---- AC: S[fn] = Qa . K^T (from LDS, swizzled) ----
    f32x4 S[4] = {};
#pragma unroll
    for (int fn = 0; fn < 4; ++fn)
#pragma unroll
      for (int kk = 0; kk < 2; ++kk) {
        const short8 kf = *(const short8*)((char*)Ks + cur * 8192 + (16 * fn + l15) * 128 + ((kk * 64 + 16 * l4) ^ srd));
        S[fn] = __builtin_amdgcn_mfma_f32_16x16x32_bf16(qa[kk], kf, S[fn], 0, 0, 0);
      }
    // ---- BD band: rows (3-w)*16 + 16*ftl + l15 of Rs ----
    {
      f32x4 T[5] = {};
#pragma unroll
      for (int ftl = 0; ftl < 5; ++ftl) {
        const int rrow = (3 - w) * 16 + 16 * ftl + l15;
#pragma unroll
        for (int kk = 0; kk < 2; ++kk) {
          const short8 rf = *(const short8*)((char*)Rs + cur * 16384 + rrow * 128 + ((kk * 64 + 16 * l4) ^ srd));
          T[ftl] = __builtin_amdgcn_mfma_f32_16x16x32_bf16(qb[kk], rf, T[ftl], 0, 0, 0);
        }
      }
#pragma unroll
      for (int ftl = 0; ftl < 5; ++ftl)
#pragma unroll
        for (int r = 0; r < 4; ++r)
          TP[w][4 * l4 + r][16 * ftl + l15] = __float2bfloat16(T[ftl][r]);
    }
    // ---- shift-add + mask ----
    const bool fullvalid = (j0 + 63) <= (512 + q0);
    float sv[4][4];
#pragma unroll
    for (int fn = 0; fn < 4; ++fn)
#pragma unroll
      for (int r = 0; r < 4; ++r) {
        const int il = 4 * l4 + r;
        const float tshift = __bfloat162float(TP[w][il][16 * fn + l15 + 15 - il]);
        const float s = S[fn][r] + tshift;
        const bool valid = fullvalid || (j0 + 16 * fn + l15 - 512 <= q0 + 16 * w + il);
        sv[fn][r] = valid ? s : -1e30f;
      }
    // ---- online softmax (row = 16-lane group) ----
#pragma unroll
    for (int r = 0; r < 4; ++r) {
      float m4 = fmaxf(fmaxf(sv[0][r], sv[1][r]), fmaxf(sv[2][r], sv[3][r]));
      m4 = fmaxf(m4, __shfl_xor(m4, 1));
      m4 = fmaxf(m4, __shfl_xor(m4, 2));
      m4 = fmaxf(m4, __shfl_xor(m4, 4));
      m4 = fmaxf(m4, __shfl_xor(m4, 8));
      const float mn = fmaxf(mrow[r], m4);
      const float alpha = expf(mrow[r] - mn);
      mrow[r] = mn;
      float ps = 0.f;
#pragma unroll
      for (int fn = 0; fn < 4; ++fn) {
        sv[fn][r] = expf(sv[fn][r] - mn);
        ps += sv[fn][r];
      }
      ps += __shfl_xor(ps, 1);
      ps += __shfl_xor(ps, 2);
      ps += __shfl_xor(ps, 4);
      ps += __shfl_xor(ps, 8);
      lrow[r] = lrow[r] * alpha + ps;
#pragma unroll
      for (int fd = 0; fd < 4; ++fd) accO[fd][r] *= alpha;
    }
    // ---- P -> LDS (transpose to A-frag, TP reused after Tl reads done) and PV ----
#pragma unroll
    for (int fn = 0; fn < 4; ++fn)
#pragma unroll
      for (int r = 0; r < 4; ++r)
        TP[w][4 * l4 + r][16 * fn + l15] = __float2bfloat16(sv[fn][r]);
    short8 pa[2];
    pa[0] = *(const short8*)&TP[w][l15][8 * l4];
    pa[1] = *(const short8*)&TP[w][l15][32 + 8 * l4];
#pragma unroll
    for (int fd = 0; fd < 4; ++fd)
#pragma unroll
      for (int kk = 0; kk < 2; ++kk) {
        const short8 vf = *(const short8*)((char*)Vs + cur * 8192 + (16 * fd + l15) * 128 + ((kk * 64 + 16 * l4) ^ srd));
        accO[fd] = __builtin_amdgcn_mfma_f32_16x16x32_bf16(pa[kk], vf, accO[fd], 0, 0, 0);
      }
    // ---- ensure prefetch landed + all waves done with cur before flipping ----
    asm volatile("s_waitcnt vmcnt(0)" ::: "memory");
    __syncthreads();
    cur ^= 1;
  }
#undef FA_STAGE
  // ---- store unnormalized partials ----
  const int cb = ck * 64 + bn;
  float* pob = po + (size_t)cb * 512 * 64;
#pragma unroll
  for (int fd = 0; fd < 4; ++fd)
#pragma unroll
    for (int r = 0; r < 4; ++r) {
      const int row = q0 + 16 * w + 4 * l4 + r;
      pob[(size_t)row * 64 + 16 * fd + l15] = accO[fd][r];
    }
  if (l15 == 0) {
#pragma unroll
    for (int r = 0; r < 4; ++r) {
      const int row = q0 + 16 * w + 4 * l4 + r;
      pm[(size_t)cb * 512 + row] = mrow[r];
      pl[(size_t)cb * 512 + row] = lrow[r];
    }
  }
}

// ================= merge 4 split-KV partials -> av bf16 =================
__global__ __launch_bounds__(256) void fmerge_kernel(
    const float* __restrict__ po, const float* __restrict__ pm,
    const float* __restrict__ pl, bf16* __restrict__ av)
{
  const long i = ((long)blockIdx.x * 256 + threadIdx.x) * 4;   // over 64*512*64
  const long bnq = i >> 6;                                     // bn*512 + q
  const int d4 = (int)(i & 63);
  const int bn = (int)(bnq >> 9), q = (int)(bnq & 511);
  const int b = bn >> 4, n = bn & 15;
  float mv[4], lv[4];
#pragma unroll
  for (int c = 0; c < 4; ++c) { mv[c] = pm[c * 32768 + bnq]; lv[c] = pl[c * 32768 + bnq]; }
  const float m = fmaxf(fmaxf(mv[0], mv[1]), fmaxf(mv[2], mv[3]));
  float wv[4], den = 0.f;
#pragma unroll
  for (int c = 0; c < 4; ++c) { wv[c] = expf(mv[c] - m); den += wv[c] * lv[c]; }
  const float inv = 1.f / den;
  float4 o = { 0.f, 0.f, 0.f, 0.f };
#pragma unroll
  for (int c = 0; c < 4; ++c) {
    const float4 oc = *(const float4*)(po + (size_t)c * 2097152 + bnq * 64 + d4);
    o.x += wv[c] * oc.x; o.y += wv[c] * oc.y; o.z += wv[c] * oc.z; o.w += wv[c] * oc.w;
  }
  bf16* dst = av + (size_t)(q * 4 + b) * 1024 + n * 64 + d4;
  dst[0] = __float2bfloat16(o.x * inv);
  dst[1] = __float2bfloat16(o.y * inv);
  dst[2] = __float2bfloat16(o.z * inv);
  dst[3] = __float2bfloat16(o.w * inv);
}

// ================= h = LayerNorm(h + x0 + x1), dual write fp32 h + bf16 cat(upper) =================
__global__ __launch_bounds__(256) void add_ln_kernel(
    float* __restrict__ h,
    const float* __restrict__ x0, const float* __restrict__ x1,
    const float* __restrict__ g, const float* __restrict__ bb, bf16* __restrict__ cat)
{
  float* hr = h + (long)blockIdx.x * DM;
  const long o = (long)blockIdx.x * DM;
  bf16* cr = cat + (long)(2048 + blockIdx.x) * DM;
  const int tid = threadIdx.x;
  __shared__ float red[256];
  float v0 = hr[tid]       + x0[o + tid]       + x1[o + tid];
  float v1 = hr[tid + 256] + x0[o + tid + 256] + x1[o + tid + 256];
  float v2 = hr[tid + 512] + x0[o + tid + 512] + x1[o + tid + 512];
  float v3 = hr[tid + 768] + x0[o + tid + 768] + x1[o + tid + 768];
  red[tid] = v0 + v1 + v2 + v3; __syncthreads();
  for (int off = 128; off; off >>= 1) { if (tid < off) red[tid] += red[tid + off]; __syncthreads(); }
  const float mean = red[0] * (1.f / DM); __syncthreads();
  const float d0 = v0 - mean, d1 = v1 - mean, d2 = v2 - mean, d3 = v3 - mean;
  red[tid] = d0 * d0 + d1 * d1 + d2 * d2 + d3 * d3; __syncthreads();
  for (int off = 128; off; off >>= 1) { if (tid < off) red[tid] += red[tid + off]; __syncthreads(); }
  const float inv = rsqrtf(red[0] * (1.f / DM) + 1e-5f);
  const float o0 = d0 * inv * g[tid]       + bb[tid];
  const float o1 = d1 * inv * g[tid + 256] + bb[tid + 256];
  const float o2 = d2 * inv * g[tid + 512] + bb[tid + 512];
  const float o3 = d3 * inv * g[tid + 768] + bb[tid + 768];
  hr[tid]       = o0;  cr[tid]       = __float2bfloat16(o0);
  hr[tid + 256] = o1;  cr[tid + 256] = __float2bfloat16(o1);
  hr[tid + 512] = o2;  cr[tid + 512] = __float2bfloat16(o2);
  hr[tid + 768] = o3;  cr[tid + 768] = __float2bfloat16(o3);
}

// ================= (q,b,d) -> (b,q,d) =================
__global__ __launch_bounds__(256) void out_kernel(const float* __restrict__ h, float* __restrict__ out)
{
  const int t = blockIdx.x, q = t >> 2, b = t & 3;
  const float* hr = h + (long)t * DM;
  float* orow = out + ((long)b * QLEN + q) * DM;
  for (int s = 0; s < 4; ++s) orow[threadIdx.x + 256 * s] = hr[threadIdx.x + 256 * s];
}

extern "C" void kernel_launch(void* const* d_in, const int* in_sizes, int n_in,
                              void* d_out, int out_size, void* d_ws, size_t ws_size,
                              hipStream_t stream)
{
  const int*   ids  = (const int*)d_in[0];
  const float* mems = (const float*)d_in[1];
  const float* e0 = (const float*)d_in[2]; const float* p0 = (const float*)d_in[3];
  const float* e1 = (const float*)d_in[4]; const float* p1 = (const float*)d_in[5];
  const float* e2 = (const float*)d_in[6]; const float* p2 = (const float*)d_in[7];
  const float* e3 = (const float*)d_in[8]; const float* p3 = (const float*)d_in[9];
  const float* qkvw = (const float*)d_in[10];
  const float* rnet = (const float*)d_in[11];
  const float* ow   = (const float*)d_in[12];
  const float* rwb  = (const float*)d_in[13];
  const float* rrb  = (const float*)d_in[14];
  const float* ln1g = (const float*)d_in[15];
  const float* ln1b = (const float*)d_in[16];
  const float* fw1  = (const float*)d_in[17];
  const float* fb1  = (const float*)d_in[18];
  const float* fw2  = (const float*)d_in[19];
  const float* fb2  = (const float*)d_in[20];
  const float* ln2g = (const float*)d_in[21];
  const float* ln2b = (const float*)d_in[22];
  float* out = (float*)d_out;

  // -------- workspace layout --------
  char* p = (char*)d_ws;
  float* h    = (float*)p;            p += (size_t)2048 * 1024 * 4;       // 8 MB
  bf16*  cat0 = (bf16*)p;             p += (size_t)5 * 4096 * 1024 * 2;   // 40 MB (cats[0..4])
  bf16*  pe   = (bf16*)p;             p += (size_t)1024 * 1024 * 2;       // 2 MB
  bf16*  rkb  = (bf16*)p;             p += (size_t)4 * 1024 * 1024 * 2;   // 8 MB (all layers, [p][1024])
  bf16*  rkn  = (bf16*)p;             p += (size_t)(4 * 16 * 1024 * 64 + 8192) * 2; // 8 MB + 16 KB guard
  bf16*  wh   = (bf16*)p;             p += (size_t)4096 * 3072 * 2;       // 24 MB
  bf16*  vt   = (bf16*)p;             p += (size_t)64 * 64 * 1024 * 2;    // 8 MB (j-blocked V^T)
  bf16*  kb   = (bf16*)p;             p += (size_t)64 * 1024 * 64 * 2;    // 8 MB (packed K)
  bf16*  qkvT = (bf16*)p;             p += (size_t)4 * 3072 * 1024 * 2;   // 24 MB
  bf16*  rnT  = (bf16*)p;             p += (size_t)4 * 1024 * 1024 * 2;   // 8 MB
  bf16*  oT   = (bf16*)p;             p += (size_t)4 * 1024 * 1024 * 2;   // 8 MB
  bf16*  f1T  = (bf16*)p;             p += (size_t)4 * 4096 * 1024 * 2;   // 32 MB
  bf16*  f2T  = (bf16*)p;             p += (size_t)4 * 4096 * 1024 * 2;   // 32 MB
  // 64 MB region A: mid (FFN) / partE (embed, 16 MB fp32)
  bf16*  mid  = (bf16*)p;
  float* partE= (float*)p;
  p += (size_t)4 * 16 * 512 * 1024 * 2;                                   // 64 MB
  // 64 MB region B: Aemb+projT (embed) / attn partials po/pm/pl / partP
  bf16*  Aemb = (bf16*)p;
  bf16*  projT= (bf16*)(p + (size_t)2048 * KEMB * 2);
  float* partP= (float*)p;
  float* po   = (float*)p;                                    // 4*64*512*64 fp32 = 32 MB
  float* pm   = (float*)(p + (size_t)32 * 1024 * 1024);       // 512 KB
  float* pl   = (float*)(p + (size_t)33 * 1024 * 1024);       // 512 KB
  p += (size_t)4 * 16 * 512 * 1024 * 2;                                   // 64 MB
  bf16*  av   = (bf16*)p;             p += (size_t)2048 * 1024 * 2;       // 4 MB

  // -------- upfront: embedding, pos-emb, mems conversion, ALL weight transposes --------
  embA_kernel<<<2048, 256, 0, stream>>>(ids, e0, e1, e2, e3, Aemb);
  projT_kernel<<<dim3(KEMB / 32, 32), 256, 0, stream>>>(p0, p1, p2, p3, projT);
  gemm_bf16<128, 64><<<dim3(16, 16, 2), 256, 0, stream>>>(
      Aemb, 0, 0, KEMB, projT, 0, 0, KEMB, partE, 0, 0, 1024,
      KEMB / 2, 32.f, nullptr, 0, 0, 0, 1, 2, 2097152);
  embsum_kernel<<<2048, 256, 0, stream>>>(partE, h, cat0);
  posemb_kernel<<<1024, 256, 0, stream>>>(pe);
  memsconv_kernel<<<8192, 256, 0, stream>>>(mems, cat0);

  wtrans_kernel<<<dim3(96, 32, 4), 256, 0, stream>>>(qkvw, qkvT, DM, 3072);
  wtrans_kernel<<<dim3(32, 32, 4), 256, 0, stream>>>(rnet, rnT, DM, DM);
  wtrans_kernel<<<dim3(32, 32, 4), 256, 0, stream>>>(ow, oT, DM, DM);
  wtrans_kernel<<<dim3(128, 32, 4), 256, 0, stream>>>(fw1, f1T, DM, DI);
  wtrans_kernel<<<dim3(32, 128, 4), 256, 0, stream>>>(fw2, f2T, DI, DM);

  // rk = pos_emb @ r_net_w for ALL layers (z = layer), then repack to [l][n][p][64]
  gemm_bf16<128, 128><<<dim3(8, 8, 4), 256, 0, stream>>>(
      pe, 0, 0, 1024, rnT, 1048576, 0, 1024, rkb, 1048576, 0, 1024,
      1024, 1.f, nullptr, 0, 0, 1, 1, 1, 0);
  rkpack_kernel<<<dim3(16, 64), 256, 0, stream>>>(rkb, rkn);

  for (int l = 0; l < NL; ++l) {
    bf16* catl = cat0 + (size_t)l * 4194304;
    // w_heads = cat @ qkv_w  -> wh (bf16, 4096 x 3072)
    gemm_bf16<128, 128><<<dim3(24, 32, 1), 256, 0, stream>>>(
        catl, 0, 0, 1024, qkvT + (size_t)l * 3145728, 0, 0, 1024, wh, 0, 0, 3072,
        1024, 1.f, nullptr, 0, 0, 1, 1, 1, 0);

    vt_kernel<<<dim3(16, 64), 256, 0, stream>>>(wh, vt, kb);

    // fused flash attention, split-KV x4 -> partials, then merge -> av (bf16)
    fattn_kernel<<<dim3(64, 8, 4), 256, 0, stream>>>(
        wh, kb, rkn + (size_t)l * 1048576, vt,
        rwb + l * NH * DH, rrb + l * NH * DH, po, pm, pl);
    fmerge_kernel<<<2048, 256, 0, stream>>>(po, pm, pl, av);

    // attn_out = av @ o_w (split-K x2, fp32 partials into partP), summed in add_ln
    gemm_bf16<128, 64><<<dim3(16, 16, 2), 256, 0, stream>>>(
        av, 0, 0, 1024, oT + (size_t)l * 1048576, 0, 0, 1024, partP, 0, 0, 1024,
        512, 1.f, nullptr, 0, 0, 0, 1, 2, 2097152);
    add_ln_kernel<<<2048, 256, 0, stream>>>(h, partP, partP + 2097152,
                                            ln1g + l * DM, ln1b + l * DM, catl);

    // FFN
    gemm_bf16<128, 128><<<dim3(32, 16, 1), 256, 0, stream>>>(
        catl + (size_t)2048 * 1024, 0, 0, 1024, f1T + (size_t)l * 4194304, 0, 0, 1024,
        mid, 0, 0, 4096, 1024, 1.f, fb1 + (size_t)l * DI, 0, 0, 1 | 4, 1, 1, 0);
    gemm_bf16<128, 64><<<dim3(16, 16, 2), 256, 0, stream>>>(
        mid, 0, 0, 4096, f2T + (size_t)l * 4194304, 0, 0, 4096, partP, 0, 0, 1024,
        2048, 1.f, fb2 + (size_t)l * DM, 0, 0, 0, 1, 2, 2097152);
    add_ln_kernel<<<2048, 256, 0, stream>>>(h, partP, partP + 2097152,
                                            ln2g + l * DM, ln2b + l * DM,
                                            cat0 + (size_t)(l + 1) * 4194304);
  }

  out_kernel<<<2048, 256, 0, stream>>>(h, out);
}

// Round 16
// 981.594 us; speedup vs baseline: 1.0151x; 1.0151x over previous
//
#include <hip/hip_runtime.h>
#include <hip/hip_bf16.h>

typedef __attribute__((ext_vector_type(8))) short short8;
typedef __attribute__((ext_vector_type(4))) float f32x4;
typedef __hip_bfloat16 bf16;

#define QLEN 512
#define MLEN 512
#define KLEN 1024
#define BSZ  4
#define DM   1024
#define NH   16
#define DH   64
#define DI   4096
#define NL   4
#define KEMB 1408   // 1024 + 256 + 64 + 16 = 1360, padded to 1408 (x32)

// direct global->LDS DMA, 16 B per lane (wave-uniform LDS base + lane*16)
__device__ __forceinline__ void gload16(const bf16* g, const void* l) {
  __builtin_amdgcn_global_load_lds(
      (const __attribute__((address_space(1))) void*)g,
      (__attribute__((address_space(3))) void*)l, 16, 0, 0);
}

__device__ __forceinline__ bf16 bits2bf(short s) { bf16 h; *(short*)&h = s; return h; }

// ================= adaptive embedding as GEMM: gather A rows (2048 x KEMB, bf16) =================
__global__ __launch_bounds__(256) void embA_kernel(
    const int* __restrict__ ids,
    const float* __restrict__ e0, const float* __restrict__ e1,
    const float* __restrict__ e2, const float* __restrict__ e3,
    bf16* __restrict__ Aemb)
{
  const int t = blockIdx.x;          // t = q*BSZ + b
  const int q = t >> 2, b = t & 3;
  const int id = ids[b * QLEN + q];
  const float* tab; int d, off, koff;
  if (id < 20000)       { tab = e0; d = 1024; off = 0;      koff = 0; }
  else if (id < 40000)  { tab = e1; d = 256;  off = 20000;  koff = 1024; }
  else if (id < 200000) { tab = e2; d = 64;   off = 40000;  koff = 1280; }
  else                  { tab = e3; d = 16;   off = 200000; koff = 1344; }
  bf16* row = Aemb + (long)t * KEMB;
  const float* tr = tab + (long)(id - off) * d;
  for (int k = threadIdx.x; k < KEMB; k += 256) {
    const int kk = k - koff;
    float v = 0.f;
    if (kk >= 0 && kk < d) v = tr[kk];
    row[k] = __float2bfloat16(v);
  }
}

// ================= concat proj^T: projT[n][k] (1024 x KEMB, bf16), zero-padded =================
__global__ __launch_bounds__(256) void projT_kernel(
    const float* __restrict__ p0, const float* __restrict__ p1,
    const float* __restrict__ p2, const float* __restrict__ p3,
    bf16* __restrict__ out)
{
  __shared__ float t[32][33];
  const int k0 = blockIdx.x * 32, n0 = blockIdx.y * 32;
  const int nx = threadIdx.x & 31, ky = threadIdx.x >> 5;
#pragma unroll
  for (int p = 0; p < 4; ++p) {
    const int k = k0 + ky + p * 8;
    float v = 0.f;
    if (k < 1024)       v = p0[(long)k * 1024 + n0 + nx];
    else if (k < 1280)  v = p1[(long)(k - 1024) * 1024 + n0 + nx];
    else if (k < 1344)  v = p2[(long)(k - 1280) * 1024 + n0 + nx];
    else if (k < 1360)  v = p3[(long)(k - 1344) * 1024 + n0 + nx];
    t[ky + p * 8][nx] = v;
  }
  __syncthreads();
#pragma unroll
  for (int p = 0; p < 4; ++p)
    out[(long)(n0 + ky + p * 8) * KEMB + k0 + nx] = __float2bfloat16(t[nx][ky + p * 8]);
}

// ================= sum 2 fp32 partials -> h fp32 + cat bf16 (upper) =================
__global__ __launch_bounds__(256) void embsum_kernel(const float* __restrict__ part,
                                                     float* __restrict__ h, bf16* __restrict__ cat)
{
  const long i = ((long)blockIdx.x * 256 + threadIdx.x) * 4;
  const float4 a = *(const float4*)(part + i);
  const float4 b = *(const float4*)(part + 2097152 + i);
  float4 s; s.x = a.x + b.x; s.y = a.y + b.y; s.z = a.z + b.z; s.w = a.w + b.w;
  *(float4*)(h + i) = s;
  bf16* cr = cat + (long)2048 * 1024 + i;
  cr[0] = __float2bfloat16(s.x); cr[1] = __float2bfloat16(s.y);
  cr[2] = __float2bfloat16(s.z); cr[3] = __float2bfloat16(s.w);
}

// ================= sinusoidal pos emb -> bf16 =================
__global__ __launch_bounds__(256) void posemb_kernel(bf16* __restrict__ pe)
{
  const int j = blockIdx.x;
  const float pos = (float)(KLEN - 1 - j);
  for (int i = threadIdx.x; i < DM / 2; i += 256) {
    const float freq = expf(-9.210340371976184f * ((float)(2 * i) / (float)DM));
    const float ang = pos * freq;
    pe[(long)j * DM + i]          = __float2bfloat16(sinf(ang));
    pe[(long)j * DM + DM / 2 + i] = __float2bfloat16(cosf(ang));
  }
}

// ================= fp32 (R x C) -> bf16 transposed (C x R), z = layer =================
__global__ __launch_bounds__(256) void wtrans_kernel(const float* __restrict__ in,
                                                     bf16* __restrict__ out, int R, int C)
{
  __shared__ float t[32][33];
  in  += (long)blockIdx.z * R * C;
  out += (long)blockIdx.z * R * C;
  const int c0 = blockIdx.x * 32, r0 = blockIdx.y * 32;
  const int cx = threadIdx.x & 31, ry = threadIdx.x >> 5;
#pragma unroll
  for (int p = 0; p < 4; ++p)
    t[ry + p * 8][cx] = in[(long)(r0 + ry + p * 8) * C + c0 + cx];
  __syncthreads();
#pragma unroll
  for (int p = 0; p < 4; ++p)
    out[(long)(c0 + ry + p * 8) * R + r0 + cx] = __float2bfloat16(t[cx][ry + p * 8]);
}

// ================= all mems (NL x 2048 x 1024 fp32) -> lower halves of cats[l] =================
__global__ __launch_bounds__(256) void memsconv_kernel(const float* __restrict__ mems,
                                                       bf16* __restrict__ cat0)
{
  const long i = ((long)blockIdx.x * 256 + threadIdx.x) * 4;   // over NL*2048*1024
  const long l = i >> 21, rem = i & ((1 << 21) - 1);
  const float4 v = *(const float4*)(mems + i);
  bf16* dst = cat0 + l * 4194304 + rem;
  dst[0] = __float2bfloat16(v.x); dst[1] = __float2bfloat16(v.y);
  dst[2] = __float2bfloat16(v.z); dst[3] = __float2bfloat16(v.w);
}

// ================= bf16 MFMA GEMM:  C = scale*(A @ B^T_supplied + colbias)  =================
// flags: 1 = bf16 out, 4 = relu, 8 = XCD-chunked block swizzle (requires
// gridDim.x*gridDim.y % 8 == 0, z == 1): keeps same-A-panel blocks on one XCD.
template<int BM, int BN>
__global__ __launch_bounds__(256) void gemm_bf16(
    const bf16* __restrict__ A, long aStrB, long aStrN, int lda,
    const bf16* __restrict__ B, long bStrB, long bStrN, int ldb,
    void* __restrict__ C, long cStrB, long cStrN, int ldc,
    int K, float scale, const float* __restrict__ bias, long biasStrB, long biasStrN,
    int flags, int zN, int zSplit, long cSplitStr)
{
  constexpr int RA = BM / 64, RB = BN / 64, FM = BM / 32, FN = BN / 32;
  __shared__ __align__(16) bf16 As[2][BM * 32];
  __shared__ __align__(16) bf16 Bs[2][BN * 32];
  const int zc = blockIdx.z % zSplit, zt = blockIdx.z / zSplit;
  const int zn = zt % zN, zb = zt / zN;
  A += (long)zb * aStrB + (long)zn * aStrN + (long)zc * K;
  B += (long)zb * bStrB + (long)zn * bStrN + (long)zc * K;
  int bx = blockIdx.x, by = blockIdx.y;
  if (flags & 8) {
    const int nwg = gridDim.x * gridDim.y;
    const int bid = by * gridDim.x + bx;
    const int qq = nwg >> 3;                      // nwg % 8 == 0 guaranteed by caller
    const int nb = (bid & 7) * qq + (bid >> 3);   // XCD (bid%8) gets contiguous range
    bx = nb % gridDim.x; by = nb / gridDim.x;
  }
  const int tid = threadIdx.x, lane = tid & 63;
  const int w = tid >> 6, wr = w >> 1, wc = w & 1;
  const int m0 = by * BM, n0 = bx * BN;
  const int l15 = lane & 15, l4 = lane >> 4;
  const int rowS = tid >> 2;
  const int cbS  = (tid & 3) * 16;
  const int swS  = cbS ^ (((rowS >> 1) & 3) << 4);
  const int wbase = w * 1024;
  const bf16* Ast = A + (size_t)(m0 + rowS) * lda + (swS >> 1);
  const bf16* Bst = B + (size_t)(n0 + rowS) * ldb + (swS >> 1);

#define STAGE_TILE(buf, kk)                                                       \
  {                                                                               \
    _Pragma("unroll")                                                             \
    for (int r = 0; r < RA; ++r)                                                  \
      gload16(Ast + (size_t)(r * 64) * lda + (kk), (char*)As[buf] + r * 4096 + wbase); \
    _Pragma("unroll")                                                             \
    for (int r = 0; r < RB; ++r)                                                  \
      gload16(Bst + (size_t)(r * 64) * ldb + (kk), (char*)Bs[buf] + r * 4096 + wbase); \
  }

  f32x4 acc[FM][FN] = {};
  STAGE_TILE(0, 0)
  asm volatile("s_waitcnt vmcnt(0)" ::: "memory");
  __syncthreads();
  int cur = 0;
  for (int k0 = 0; k0 < K; k0 += 32) {
    if (k0 + 32 < K) {
      if (cur == 0) STAGE_TILE(1, k0 + 32)
      else          STAGE_TILE(0, k0 + 32)
    }
    short8 af[FM], bfr[FN];
#pragma unroll
    for (int f = 0; f < FM; ++f) {
      const int row = wr * (BM / 2) + f * 16 + l15;
      af[f] = *(const short8*)((char*)As[cur] + row * 64 + ((16 * l4) ^ (((row >> 1) & 3) << 4)));
    }
#pragma unroll
    for (int f = 0; f < FN; ++f) {
      const int row = wc * (BN / 2) + f * 16 + l15;
      bfr[f] = *(const short8*)((char*)Bs[cur] + row * 64 + ((16 * l4) ^ (((row >> 1) & 3) << 4)));
    }
#pragma unroll
    for (int fm = 0; fm < FM; ++fm)
#pragma unroll
      for (int fn = 0; fn < FN; ++fn)
        acc[fm][fn] = __builtin_amdgcn_mfma_f32_16x16x32_bf16(af[fm], bfr[fn], acc[fm][fn], 0, 0, 0);
    asm volatile("s_waitcnt vmcnt(0)" ::: "memory");
    __syncthreads();
    cur ^= 1;
  }
#undef STAGE_TILE
  const int outbf = flags & 1, relu = flags & 4;
#pragma unroll
  for (int fm = 0; fm < FM; ++fm) {
#pragma unroll
    for (int fn = 0; fn < FN; ++fn) {
      const int col = n0 + wc * (BN / 2) + fn * 16 + l15;
      const int rw0 = m0 + wr * (BM / 2) + fm * 16 + l4 * 4;
      const float bv = (bias && zc == 0) ? bias[(size_t)zb * biasStrB + (size_t)zn * biasStrN + col] : 0.f;
#pragma unroll
      for (int r = 0; r < 4; ++r) {
        float v = (acc[fm][fn][r] + bv) * scale;
        if (relu) v = fmaxf(v, 0.f);
        const int row = rw0 + r;
        const size_t cOff = (size_t)zb * cStrB + (size_t)zn * cStrN + (size_t)zc * cSplitStr;
        if (outbf) {
          ((bf16*)C + cOff)[(size_t)row * ldc + col] = __float2bfloat16(v);
        } else {
          ((float*)C + cOff)[(size_t)row * ldc + col] = v;
        }
      }
    }
  }
}

// ================= V transpose (j-tile blocked) + K pack =================
__global__ __launch_bounds__(256) void vt_kernel(const bf16* __restrict__ wh,
                                                 bf16* __restrict__ vt, bf16* __restrict__ kb)
{
  const int bn = blockIdx.y, b = bn >> 4, n = bn & 15;
  const int j0 = blockIdx.x * 64;
  __shared__ bf16 t[64][72];
  const bf16* src = wh + (size_t)b * 3072 + 2048 + n * 64;
  const bf16* ksrc = wh + (size_t)b * 3072 + 1024 + n * 64;
  bf16* kdst = kb + (size_t)bn * 65536;
  const int tid = threadIdx.x;
#pragma unroll
  for (int r = 0; r < 16; ++r) {
    const int jl = r * 4 + (tid >> 6), d = tid & 63;
    t[jl][d] = src[(size_t)(j0 + jl) * 12288 + d];
    kdst[(size_t)(j0 + jl) * 64 + d] = ksrc[(size_t)(j0 + jl) * 12288 + d];
  }
  __syncthreads();
  bf16* dst = vt + (size_t)bn * 65536 + (size_t)j0 * 64;   // block [d][64]
#pragma unroll
  for (int r = 0; r < 16; ++r) {
    const int d = r * 4 + (tid >> 6), j = tid & 63;
    dst[(size_t)d * 64 + j] = t[j][d];
  }
}

// ================= rk repack: rkn[l][n][p][64] =================
__global__ __launch_bounds__(256) void rkpack_kernel(const bf16* __restrict__ rkb,
                                                     bf16* __restrict__ rkn)
{
  const int ln = blockIdx.y, l = ln >> 4, n = ln & 15;
  const int p0 = blockIdx.x * 64;
  const int d = threadIdx.x & 63, pr = threadIdx.x >> 6;
  const bf16* src = rkb + (size_t)l * 1048576 + n * 64 + d;
  bf16* dst = rkn + (size_t)ln * 65536 + d;
#pragma unroll
  for (int r = 0; r < 16; ++r) {
    const int p = p0 + r * 4 + pr;
    dst[(size_t)p * 64] = src[(size_t)p * 1024];
  }
}

// ================= fused flash attention, split-KV x4, LDS-staged K/V/rk (R14 config) =================
// grid (64 bn, 8 q-tiles, 4 ck): linear id % 8 == bn % 8 -> XCD L2 locality.
// Per j-tile, the WG stages K-tile (8 KB) + V-tile (8 KB) + rk band (128 rows,
// 16 KB — union of all 4 waves' bands) into LDS ONCE via global_load_lds —
// removes the 4x intra-WG L2 read redundancy. Single-buffered (3 WG/CU; the
// double-buffered variant was measured slower: 2 WG/CU cost > overlap gain).
__global__ __launch_bounds__(256) void fattn_kernel(
    const bf16* __restrict__ wh,     // 4096 x 3072 (row = 4*token + b) — Q only
    const bf16* __restrict__ kb,     // [bn][1024 j][64 d]
    const bf16* __restrict__ rkn_l,  // [16 n][1024 p][64 d] (this layer, 16 KB guard after)
    const bf16* __restrict__ vt,     // [bn][16 jt][64 d][64 jl]
    const float* __restrict__ rwb,   // 16 x 64 (this layer)
    const float* __restrict__ rrb,   // 16 x 64
    float* __restrict__ po, float* __restrict__ pm, float* __restrict__ pl)
{
  const int bn = blockIdx.x, b = bn >> 4, n = bn & 15;
  const int q0 = blockIdx.y * 64;
  const int ck = blockIdx.z;
  const int tid = threadIdx.x, w = tid >> 6, lane = tid & 63;
  const int l15 = lane & 15, l4 = lane >> 4;
  __shared__ __align__(16) bf16 Ks[64 * 64];    // 8 KB  [row j][128 B]
  __shared__ __align__(16) bf16 Vs[64 * 64];    // 8 KB  [row d][128 B]
  __shared__ __align__(16) bf16 Rs[128 * 64];   // 16 KB [row p-pstart][128 B]
  __shared__ bf16 Tl[4][16][84];                // wave-private shifted-BD band strips
  __shared__ bf16 Pl[4][16][72];                // wave-private P transpose staging

  // ---- load Q fragments, fold biases AND 0.125 scale (exact 2^-3) ----
  short8 qa[2], qb[2];
  {
    const bf16* qp = wh + (size_t)(2048 + b) * 3072 + (size_t)(q0 + 16 * w + l15) * 12288 + n * 64;
#pragma unroll
    for (int kk = 0; kk < 2; ++kk) {
      const short8 qv = *(const short8*)(qp + kk * 32 + 8 * l4);
      const float* wv = rwb + n * 64 + kk * 32 + 8 * l4;
      const float* rv = rrb + n * 64 + kk * 32 + 8 * l4;
      short8 a, c;
#pragma unroll
      for (int e = 0; e < 8; ++e) {
        const float q = __bfloat162float(bits2bf(qv[e]));
        const bf16 ab = __float2bfloat16((q + wv[e]) * 0.125f);
        const bf16 cb = __float2bfloat16((q + rv[e]) * 0.125f);
        a[e] = *(const short*)&ab;  c[e] = *(const short*)&cb;
      }
      qa[kk] = a; qb[kk] = c;
    }
  }

  const bf16* kbase = kb + (size_t)bn * 65536;                  // + j*64
  const bf16* rbase = rkn_l + (size_t)n * 65536;                // + p*64
  const bf16* vbase = vt + (size_t)bn * 65536;                  // + j0*64 + d*64 + jl
  const int ntiles = 9 + (q0 >> 6);

  // staging geometry: thread tid covers linear LDS bytes [tid*16, tid*16+16) per 4 KB slab
  const int stRow0 = tid >> 3;                  // row within 4 KB slab (32 rows/slab)
  const int stColb = (tid & 7) * 16;
  const int wbase = w * 1024;                   // wave-uniform LDS base within slab
  const int srd = (l15 & 7) << 4;               // read-side swizzle (== row&7 <<4 for all reads)

  f32x4 accO[4] = {};
  float mrow[4] = { -1e30f, -1e30f, -1e30f, -1e30f };
  float lrow[4] = { 0.f, 0.f, 0.f, 0.f };

  for (int t = ck; t < ntiles; t += 4) {
    const int j0 = t * 64;
    const int pstart = j0 - q0 + 448;           // Rs row 0 == global p = pstart (>= 0)
    // ---- stage K/V tiles + rk band into LDS (once per WG) ----
    __syncthreads();                            // previous tile fully consumed
    {
#pragma unroll
      for (int r = 0; r < 2; ++r) {             // K: 2 slabs of 4 KB
        const int row = r * 32 + stRow0;
        gload16(kbase + (size_t)(j0 + row) * 64 + ((stColb ^ ((row & 7) << 4)) >> 1),
                (char*)Ks + r * 4096 + wbase);
      }
#pragma unroll
      for (int r = 0; r < 2; ++r) {             // V: 2 slabs
        const int row = r * 32 + stRow0;
        gload16(vbase + (size_t)j0 * 64 + (size_t)row * 64 + ((stColb ^ ((row & 7) << 4)) >> 1),
                (char*)Vs + r * 4096 + wbase);
      }
#pragma unroll
      for (int r = 0; r < 4; ++r) {             // rk band: 4 slabs (128 rows)
        const int row = r * 32 + stRow0;
        gload16(rbase + (size_t)(pstart + row) * 64 + ((stColb ^ ((row & 7) << 4)) >> 1),
                (char*)Rs + r * 4096 + wbase);
      }
    }
    asm volatile("s_waitcnt vmcnt(0)" ::: "memory");
    __syncthreads();

    // ---- AC: S[fn] = Qa . K^T (from LDS, swizzled) ----
    f32x4 S[4] = {};
#pragma unroll
    for (int fn = 0; fn < 4; ++fn)
#pragma unroll
      for (int kk = 0; kk < 2; ++kk) {
        const short8 kf = *(const short8*)((char*)Ks + (16 * fn + l15) * 128 + ((kk * 64 + 16 * l4) ^ srd));
        S[fn] = __builtin_amdgcn_mfma_f32_16x16x32_bf16(qa[kk], kf, S[fn], 0, 0, 0);
      }
    // ---- BD band: rows (3-w)*16 + 16*ftl + l15 of Rs ----
    {
      f32x4 T[5] = {};
#pragma unroll
      for (int ftl = 0; ftl < 5; ++ftl) {
        const int rrow = (3 - w) * 16 + 16 * ftl + l15;
#pragma unroll
        for (int kk = 0; kk < 2; ++kk) {
          const short8 rf = *(const short8*)((char*)Rs + rrow * 128 + ((kk * 64 + 16 * l4) ^ srd));
          T[ftl] = __builtin_amdgcn_mfma_f32_16x16x32_bf16(qb[kk], rf, T[ftl], 0, 0, 0);
        }
      }
#pragma unroll
      for (int ftl = 0; ftl < 5; ++ftl)
#pragma unroll
        for (int r = 0; r < 4; ++r)
          Tl[w][4 * l4 + r][16 * ftl + l15] = __float2bfloat16(T[ftl][r]);
    }
    // ---- shift-add + mask ----
    const bool fullvalid = (j0 + 63) <= (512 + q0);
    float sv[4][4];
#pragma unroll
    for (int fn = 0; fn < 4; ++fn)
#pragma unroll
      for (int r = 0; r < 4; ++r) {
        const int il = 4 * l4 + r;
        const float tshift = __bfloat162float(Tl[w][il][16 * fn + l15 + 15 - il]);
        const float s = S[fn][r] + tshift;
        const bool valid = fullvalid || (j0 + 16 * fn + l15 - 512 <= q0 + 16 * w + il);
        sv[fn][r] = valid ? s : -1e30f;
      }
    // ---- online softmax (row = 16-lane group) ----
#pragma unroll
    for (int r = 0; r < 4; ++r) {
      float m4 = fmaxf(fmaxf(sv[0][r], sv[1][r]), fmaxf(sv[2][r], sv[3][r]));
      m4 = fmaxf(m4, __shfl_xor(m4, 1));
      m4 = fmaxf(m4, __shfl_xor(m4, 2));
      m4 = fmaxf(m4, __shfl_xor(m4, 4));
      m4 = fmaxf(m4, __shfl_xor(m4, 8));
      const float mn = fmaxf(mrow[r], m4);
      const float alpha = expf(mrow[r] - mn);
      mrow[r] = mn;
      float ps = 0.f;
#pragma unroll
      for (int fn = 0; fn < 4; ++fn) {
        sv[fn][r] = expf(sv[fn][r] - mn);
        ps += sv[fn][r];
      }
      ps += __shfl_xor(ps, 1);
      ps += __shfl_xor(ps, 2);
      ps += __shfl_xor(ps, 4);
      ps += __shfl_xor(ps, 8);
      lrow[r] = lrow[r] * alpha + ps;
#pragma unroll
      for (int fd = 0; fd < 4; ++fd) accO[fd][r] *= alpha;
    }
    // ---- P -> LDS (transpose to A-frag) and PV (V from LDS, swizzled) ----
#pragma unroll
    for (int fn = 0; fn < 4; ++fn)
#pragma unroll
      for (int r = 0; r < 4; ++r)
        Pl[w][4 * l4 + r][16 * fn + l15] = __float2bfloat16(sv[fn][r]);
    short8 pa[2];
    pa[0] = *(const short8*)&Pl[w][l15][8 * l4];
    pa[1] = *(const short8*)&Pl[w][l15][32 + 8 * l4];
#pragma unroll
    for (int fd = 0; fd < 4; ++fd)
#pragma unroll
      for (int kk = 0; kk < 2; ++kk) {
        const short8 vf = *(const short8*)((char*)Vs + (16 * fd + l15) * 128 + ((kk * 64 + 16 * l4) ^ srd));
        accO[fd] = __builtin_amdgcn_mfma_f32_16x16x32_bf16(pa[kk], vf, accO[fd], 0, 0, 0);
      }
  }
  // ---- store unnormalized partials ----
  const int cb = ck * 64 + bn;
  float* pob = po + (size_t)cb * 512 * 64;
#pragma unroll
  for (int fd = 0; fd < 4; ++fd)
#pragma unroll
    for (int r = 0; r < 4; ++r) {
      const int row = q0 + 16 * w + 4 * l4 + r;
      pob[(size_t)row * 64 + 16 * fd + l15] = accO[fd][r];
    }
  if (l15 == 0) {
#pragma unroll
    for (int r = 0; r < 4; ++r) {
      const int row = q0 + 16 * w + 4 * l4 + r;
      pm[(size_t)cb * 512 + row] = mrow[r];
      pl[(size_t)cb * 512 + row] = lrow[r];
    }
  }
}

// ================= merge 4 split-KV partials -> av bf16 =================
__global__ __launch_bounds__(256) void fmerge_kernel(
    const float* __restrict__ po, const float* __restrict__ pm,
    const float* __restrict__ pl, bf16* __restrict__ av)
{
  const long i = ((long)blockIdx.x * 256 + threadIdx.x) * 4;   // over 64*512*64
  const long bnq = i >> 6;                                     // bn*512 + q
  const int d4 = (int)(i & 63);
  const int bn = (int)(bnq >> 9), q = (int)(bnq & 511);
  const int b = bn >> 4, n = bn & 15;
  float mv[4], lv[4];
#pragma unroll
  for (int c = 0; c < 4; ++c) { mv[c] = pm[c * 32768 + bnq]; lv[c] = pl[c * 32768 + bnq]; }
  const float m = fmaxf(fmaxf(mv[0], mv[1]), fmaxf(mv[2], mv[3]));
  float wv[4], den = 0.f;
#pragma unroll
  for (int c = 0; c < 4; ++c) { wv[c] = expf(mv[c] - m); den += wv[c] * lv[c]; }
  const float inv = 1.f / den;
  float4 o = { 0.f, 0.f, 0.f, 0.f };
#pragma unroll
  for (int c = 0; c < 4; ++c) {
    const float4 oc = *(const float4*)(po + (size_t)c * 2097152 + bnq * 64 + d4);
    o.x += wv[c] * oc.x; o.y += wv[c] * oc.y; o.z += wv[c] * oc.z; o.w += wv[c] * oc.w;
  }
  bf16* dst = av + (size_t)(q * 4 + b) * 1024 + n * 64 + d4;
  dst[0] = __float2bfloat16(o.x * inv);
  dst[1] = __float2bfloat16(o.y * inv);
  dst[2] = __float2bfloat16(o.z * inv);
  dst[3] = __float2bfloat16(o.w * inv);
}

// ================= h = LayerNorm(h + x0 + x1), dual write fp32 h + bf16 cat(upper) =================
__global__ __launch_bounds__(256) void add_ln_kernel(
    float* __restrict__ h,
    const float* __restrict__ x0, const float* __restrict__ x1,
    const float* __restrict__ g, const float* __restrict__ bb, bf16* __restrict__ cat)
{
  float* hr = h + (long)blockIdx.x * DM;
  const long o = (long)blockIdx.x * DM;
  bf16* cr = cat + (long)(2048 + blockIdx.x) * DM;
  const int tid = threadIdx.x;
  __shared__ float red[256];
  float v0 = hr[tid]       + x0[o + tid]       + x1[o + tid];
  float v1 = hr[tid + 256] + x0[o + tid + 256] + x1[o + tid + 256];
  float v2 = hr[tid + 512] + x0[o + tid + 512] + x1[o + tid + 512];
  float v3 = hr[tid + 768] + x0[o + tid + 768] + x1[o + tid + 768];
  red[tid] = v0 + v1 + v2 + v3; __syncthreads();
  for (int off = 128; off; off >>= 1) { if (tid < off) red[tid] += red[tid + off]; __syncthreads(); }
  const float mean = red[0] * (1.f / DM); __syncthreads();
  const float d0 = v0 - mean, d1 = v1 - mean, d2 = v2 - mean, d3 = v3 - mean;
  red[tid] = d0 * d0 + d1 * d1 + d2 * d2 + d3 * d3; __syncthreads();
  for (int off = 128; off; off >>= 1) { if (tid < off) red[tid] += red[tid + off]; __syncthreads(); }
  const float inv = rsqrtf(red[0] * (1.f / DM) + 1e-5f);
  const float o0 = d0 * inv * g[tid]       + bb[tid];
  const float o1 = d1 * inv * g[tid + 256] + bb[tid + 256];
  const float o2 = d2 * inv * g[tid + 512] + bb[tid + 512];
  const float o3 = d3 * inv * g[tid + 768] + bb[tid + 768];
  hr[tid]       = o0;  cr[tid]       = __float2bfloat16(o0);
  hr[tid + 256] = o1;  cr[tid + 256] = __float2bfloat16(o1);
  hr[tid + 512] = o2;  cr[tid + 512] = __float2bfloat16(o2);
  hr[tid + 768] = o3;  cr[tid + 768] = __float2bfloat16(o3);
}

// ================= (q,b,d) -> (b,q,d) =================
__global__ __launch_bounds__(256) void out_kernel(const float* __restrict__ h, float* __restrict__ out)
{
  const int t = blockIdx.x, q = t >> 2, b = t & 3;
  const float* hr = h + (long)t * DM;
  float* orow = out + ((long)b * QLEN + q) * DM;
  for (int s = 0; s < 4; ++s) orow[threadIdx.x + 256 * s] = hr[threadIdx.x + 256 * s];
}

extern "C" void kernel_launch(void* const* d_in, const int* in_sizes, int n_in,
                              void* d_out, int out_size, void* d_ws, size_t ws_size,
                              hipStream_t stream)
{
  const int*   ids  = (const int*)d_in[0];
  const float* mems = (const float*)d_in[1];
  const float* e0 = (const float*)d_in[2]; const float* p0 = (const float*)d_in[3];
  const float* e1 = (const float*)d_in[4]; const float* p1 = (const float*)d_in[5];
  const float* e2 = (const float*)d_in[6]; const float* p2 = (const float*)d_in[7];
  const float* e3 = (const float*)d_in[8]; const float* p3 = (const float*)d_in[9];
  const float* qkvw = (const float*)d_in[10];
  const float* rnet = (const float*)d_in[11];
  const float* ow   = (const float*)d_in[12];
  const float* rwb  = (const float*)d_in[13];
  const float* rrb  = (const float*)d_in[14];
  const float* ln1g = (const float*)d_in[15];
  const float* ln1b = (const float*)d_in[16];
  const float* fw1  = (const float*)d_in[17];
  const float* fb1  = (const float*)d_in[18];
  const float* fw2  = (const float*)d_in[19];
  const float* fb2  = (const float*)d_in[20];
  const float* ln2g = (const float*)d_in[21];
  const float* ln2b = (const float*)d_in[22];
  float* out = (float*)d_out;

  // -------- workspace layout --------
  char* p = (char*)d_ws;
  float* h    = (float*)p;            p += (size_t)2048 * 1024 * 4;       // 8 MB
  bf16*  cat0 = (bf16*)p;             p += (size_t)5 * 4096 * 1024 * 2;   // 40 MB (cats[0..4])
  bf16*  pe   = (bf16*)p;             p += (size_t)1024 * 1024 * 2;       // 2 MB
  bf16*  rkb  = (bf16*)p;             p += (size_t)4 * 1024 * 1024 * 2;   // 8 MB (all layers, [p][1024])
  bf16*  rkn  = (bf16*)p;             p += (size_t)(4 * 16 * 1024 * 64 + 8192) * 2; // 8 MB + 16 KB guard
  bf16*  wh   = (bf16*)p;             p += (size_t)4096 * 3072 * 2;       // 24 MB
  bf16*  vt   = (bf16*)p;             p += (size_t)64 * 64 * 1024 * 2;    // 8 MB (j-blocked V^T)
  bf16*  kb   = (bf16*)p;             p += (size_t)64 * 1024 * 64 * 2;    // 8 MB (packed K)
  bf16*  qkvT = (bf16*)p;             p += (size_t)4 * 3072 * 1024 * 2;   // 24 MB
  bf16*  rnT  = (bf16*)p;             p += (size_t)4 * 1024 * 1024 * 2;   // 8 MB
  bf16*  oT   = (bf16*)p;             p += (size_t)4 * 1024 * 1024 * 2;   // 8 MB
  bf16*  f1T  = (bf16*)p;             p += (size_t)4 * 4096 * 1024 * 2;   // 32 MB
  bf16*  f2T  = (bf16*)p;             p += (size_t)4 * 4096 * 1024 * 2;   // 32 MB
  // 64 MB region A: mid (FFN) / partE (embed, 16 MB fp32)
  bf16*  mid  = (bf16*)p;
  float* partE= (float*)p;
  p += (size_t)4 * 16 * 512 * 1024 * 2;                                   // 64 MB
  // 64 MB region B: Aemb+projT (embed) / attn partials po/pm/pl / partP
  bf16*  Aemb = (bf16*)p;
  bf16*  projT= (bf16*)(p + (size_t)2048 * KEMB * 2);
  float* partP= (float*)p;
  float* po   = (float*)p;                                    // 4*64*512*64 fp32 = 32 MB
  float* pm   = (float*)(p + (size_t)32 * 1024 * 1024);       // 512 KB
  float* pl   = (float*)(p + (size_t)33 * 1024 * 1024);       // 512 KB
  p += (size_t)4 * 16 * 512 * 1024 * 2;                                   // 64 MB
  bf16*  av   = (bf16*)p;             p += (size_t)2048 * 1024 * 2;       // 4 MB

  // -------- upfront: embedding, pos-emb, mems conversion, ALL weight transposes --------
  embA_kernel<<<2048, 256, 0, stream>>>(ids, e0, e1, e2, e3, Aemb);
  projT_kernel<<<dim3(KEMB / 32, 32), 256, 0, stream>>>(p0, p1, p2, p3, projT);
  gemm_bf16<128, 64><<<dim3(16, 16, 2), 256, 0, stream>>>(
      Aemb, 0, 0, KEMB, projT, 0, 0, KEMB, partE, 0, 0, 1024,
      KEMB / 2, 32.f, nullptr, 0, 0, 0, 1, 2, 2097152);
  embsum_kernel<<<2048, 256, 0, stream>>>(partE, h, cat0);
  posemb_kernel<<<1024, 256, 0, stream>>>(pe);
  memsconv_kernel<<<8192, 256, 0, stream>>>(mems, cat0);

  wtrans_kernel<<<dim3(96, 32, 4), 256, 0, stream>>>(qkvw, qkvT, DM, 3072);
  wtrans_kernel<<<dim3(32, 32, 4), 256, 0, stream>>>(rnet, rnT, DM, DM);
  wtrans_kernel<<<dim3(32, 32, 4), 256, 0, stream>>>(ow, oT, DM, DM);
  wtrans_kernel<<<dim3(128, 32, 4), 256, 0, stream>>>(fw1, f1T, DM, DI);
  wtrans_kernel<<<dim3(32, 128, 4), 256, 0, stream>>>(fw2, f2T, DI, DM);

  // rk = pos_emb @ r_net_w for ALL layers (z = layer), then repack to [l][n][p][64]
  gemm_bf16<128, 128><<<dim3(8, 8, 4), 256, 0, stream>>>(
      pe, 0, 0, 1024, rnT, 1048576, 0, 1024, rkb, 1048576, 0, 1024,
      1024, 1.f, nullptr, 0, 0, 1, 1, 1, 0);
  rkpack_kernel<<<dim3(16, 64), 256, 0, stream>>>(rkb, rkn);

  for (int l = 0; l < NL; ++l) {
    bf16* catl = cat0 + (size_t)l * 4194304;
    // w_heads = cat @ qkv_w  -> wh (bf16, 4096 x 3072); XCD-chunked swizzle (768 % 8 == 0)
    gemm_bf16<128, 128><<<dim3(24, 32, 1), 256, 0, stream>>>(
        catl, 0, 0, 1024, qkvT + (size_t)l * 3145728, 0, 0, 1024, wh, 0, 0, 3072,
        1024, 1.f, nullptr, 0, 0, 1 | 8, 1, 1, 0);

    vt_kernel<<<dim3(16, 64), 256, 0, stream>>>(wh, vt, kb);

    // fused flash attention, split-KV x4 -> partials, then merge -> av (bf16)
    fattn_kernel<<<dim3(64, 8, 4), 256, 0, stream>>>(
        wh, kb, rkn + (size_t)l * 1048576, vt,
        rwb + l * NH * DH, rrb + l * NH * DH, po, pm, pl);
    fmerge_kernel<<<2048, 256, 0, stream>>>(po, pm, pl, av);

    // attn_out = av @ o_w (split-K x2, fp32 partials into partP), summed in add_ln
    gemm_bf16<128, 64><<<dim3(16, 16, 2), 256, 0, stream>>>(
        av, 0, 0, 1024, oT + (size_t)l * 1048576, 0, 0, 1024, partP, 0, 0, 1024,
        512, 1.f, nullptr, 0, 0, 0, 1, 2, 2097152);
    add_ln_kernel<<<2048, 256, 0, stream>>>(h, partP, partP + 2097152,
                                            ln1g + l * DM, ln1b + l * DM, catl);

    // FFN (ffn1 with XCD-chunked swizzle: 512 % 8 == 0)
    gemm_bf16<128, 128><<<dim3(32, 16, 1), 256, 0, stream>>>(
        catl + (size_t)2048 * 1024, 0, 0, 1024, f1T + (size_t)l * 4194304, 0, 0, 1024,
        mid, 0, 0, 4096, 1024, 1.f, fb1 + (size_t)l * DI, 0, 0, 1 | 4 | 8, 1, 1, 0);
    gemm_bf16<128, 64><<<dim3(16, 16, 2), 256, 0, stream>>>(
        mid, 0, 0, 4096, f2T + (size_t)l * 4194304, 0, 0, 4096, partP, 0, 0, 1024,
        2048, 1.f, fb2 + (size_t)l * DM, 0, 0, 0, 1, 2, 2097152);
    add_ln_kernel<<<2048, 256, 0, stream>>>(h, partP, partP + 2097152,
                                            ln2g + l * DM, ln2b + l * DM,
                                            cat0 + (size_t)(l + 1) * 4194304);
  }

  out_kernel<<<2048, 256, 0, stream>>>(h, out);
}

// Round 17
// 972.045 us; speedup vs baseline: 1.0251x; 1.0098x over previous
//
#include <hip/hip_runtime.h>
#include <hip/hip_bf16.h>

typedef __attribute__((ext_vector_type(8))) short short8;
typedef __attribute__((ext_vector_type(4))) float f32x4;
typedef __hip_bfloat16 bf16;

#define QLEN 512
#define MLEN 512
#define KLEN 1024
#define BSZ  4
#define DM   1024
#define NH   16
#define DH   64
#define DI   4096
#define NL   4
#define KEMB 1408   // 1024 + 256 + 64 + 16 = 1360, padded to 1408 (x32)
#define LOG2E 1.4426950408889634f

// direct global->LDS DMA, 16 B per lane (wave-uniform LDS base + lane*16)
__device__ __forceinline__ void gload16(const bf16* g, const void* l) {
  __builtin_amdgcn_global_load_lds(
      (const __attribute__((address_space(1))) void*)g,
      (__attribute__((address_space(3))) void*)l, 16, 0, 0);
}

__device__ __forceinline__ bf16 bits2bf(short s) { bf16 h; *(short*)&h = s; return h; }

// ================= adaptive embedding as GEMM: gather A rows (2048 x KEMB, bf16) =================
__global__ __launch_bounds__(256) void embA_kernel(
    const int* __restrict__ ids,
    const float* __restrict__ e0, const float* __restrict__ e1,
    const float* __restrict__ e2, const float* __restrict__ e3,
    bf16* __restrict__ Aemb)
{
  const int t = blockIdx.x;          // t = q*BSZ + b
  const int q = t >> 2, b = t & 3;
  const int id = ids[b * QLEN + q];
  const float* tab; int d, off, koff;
  if (id < 20000)       { tab = e0; d = 1024; off = 0;      koff = 0; }
  else if (id < 40000)  { tab = e1; d = 256;  off = 20000;  koff = 1024; }
  else if (id < 200000) { tab = e2; d = 64;   off = 40000;  koff = 1280; }
  else                  { tab = e3; d = 16;   off = 200000; koff = 1344; }
  bf16* row = Aemb + (long)t * KEMB;
  const float* tr = tab + (long)(id - off) * d;
  for (int k = threadIdx.x; k < KEMB; k += 256) {
    const int kk = k - koff;
    float v = 0.f;
    if (kk >= 0 && kk < d) v = tr[kk];
    row[k] = __float2bfloat16(v);
  }
}

// ================= concat proj^T: projT[n][k] (1024 x KEMB, bf16), zero-padded =================
__global__ __launch_bounds__(256) void projT_kernel(
    const float* __restrict__ p0, const float* __restrict__ p1,
    const float* __restrict__ p2, const float* __restrict__ p3,
    bf16* __restrict__ out)
{
  __shared__ float t[32][33];
  const int k0 = blockIdx.x * 32, n0 = blockIdx.y * 32;
  const int nx = threadIdx.x & 31, ky = threadIdx.x >> 5;
#pragma unroll
  for (int p = 0; p < 4; ++p) {
    const int k = k0 + ky + p * 8;
    float v = 0.f;
    if (k < 1024)       v = p0[(long)k * 1024 + n0 + nx];
    else if (k < 1280)  v = p1[(long)(k - 1024) * 1024 + n0 + nx];
    else if (k < 1344)  v = p2[(long)(k - 1280) * 1024 + n0 + nx];
    else if (k < 1360)  v = p3[(long)(k - 1344) * 1024 + n0 + nx];
    t[ky + p * 8][nx] = v;
  }
  __syncthreads();
#pragma unroll
  for (int p = 0; p < 4; ++p)
    out[(long)(n0 + ky + p * 8) * KEMB + k0 + nx] = __float2bfloat16(t[nx][ky + p * 8]);
}

// ================= sum 2 fp32 partials -> h fp32 + cat bf16 (upper) =================
__global__ __launch_bounds__(256) void embsum_kernel(const float* __restrict__ part,
                                                     float* __restrict__ h, bf16* __restrict__ cat)
{
  const long i = ((long)blockIdx.x * 256 + threadIdx.x) * 4;
  const float4 a = *(const float4*)(part + i);
  const float4 b = *(const float4*)(part + 2097152 + i);
  float4 s; s.x = a.x + b.x; s.y = a.y + b.y; s.z = a.z + b.z; s.w = a.w + b.w;
  *(float4*)(h + i) = s;
  bf16* cr = cat + (long)2048 * 1024 + i;
  cr[0] = __float2bfloat16(s.x); cr[1] = __float2bfloat16(s.y);
  cr[2] = __float2bfloat16(s.z); cr[3] = __float2bfloat16(s.w);
}

// ================= sinusoidal pos emb -> bf16 =================
__global__ __launch_bounds__(256) void posemb_kernel(bf16* __restrict__ pe)
{
  const int j = blockIdx.x;
  const float pos = (float)(KLEN - 1 - j);
  for (int i = threadIdx.x; i < DM / 2; i += 256) {
    const float freq = expf(-9.210340371976184f * ((float)(2 * i) / (float)DM));
    const float ang = pos * freq;
    pe[(long)j * DM + i]          = __float2bfloat16(sinf(ang));
    pe[(long)j * DM + DM / 2 + i] = __float2bfloat16(cosf(ang));
  }
}

// ================= fp32 (R x C) -> bf16 transposed (C x R), z = layer =================
__global__ __launch_bounds__(256) void wtrans_kernel(const float* __restrict__ in,
                                                     bf16* __restrict__ out, int R, int C)
{
  __shared__ float t[32][33];
  in  += (long)blockIdx.z * R * C;
  out += (long)blockIdx.z * R * C;
  const int c0 = blockIdx.x * 32, r0 = blockIdx.y * 32;
  const int cx = threadIdx.x & 31, ry = threadIdx.x >> 5;
#pragma unroll
  for (int p = 0; p < 4; ++p)
    t[ry + p * 8][cx] = in[(long)(r0 + ry + p * 8) * C + c0 + cx];
  __syncthreads();
#pragma unroll
  for (int p = 0; p < 4; ++p)
    out[(long)(c0 + ry + p * 8) * R + r0 + cx] = __float2bfloat16(t[cx][ry + p * 8]);
}

// ================= all mems (NL x 2048 x 1024 fp32) -> lower halves of cats[l] =================
__global__ __launch_bounds__(256) void memsconv_kernel(const float* __restrict__ mems,
                                                       bf16* __restrict__ cat0)
{
  const long i = ((long)blockIdx.x * 256 + threadIdx.x) * 4;   // over NL*2048*1024
  const long l = i >> 21, rem = i & ((1 << 21) - 1);
  const float4 v = *(const float4*)(mems + i);
  bf16* dst = cat0 + l * 4194304 + rem;
  dst[0] = __float2bfloat16(v.x); dst[1] = __float2bfloat16(v.y);
  dst[2] = __float2bfloat16(v.z); dst[3] = __float2bfloat16(v.w);
}

// ================= bf16 MFMA GEMM:  C = scale*(A @ B^T_supplied + colbias)  =================
// flags: 1 = bf16 out, 4 = relu, 8 = XCD-chunked block swizzle (nwg % 8 == 0, z == 1),
// 16 = K-pack fusion: blocks with cols in [1024,2048) write to aux[bn][j][64]
//      (packed K for fattn) instead of C.
template<int BM, int BN>
__global__ __launch_bounds__(256) void gemm_bf16(
    const bf16* __restrict__ A, long aStrB, long aStrN, int lda,
    const bf16* __restrict__ B, long bStrB, long bStrN, int ldb,
    void* __restrict__ C, long cStrB, long cStrN, int ldc,
    int K, float scale, const float* __restrict__ bias, long biasStrB, long biasStrN,
    int flags, int zN, int zSplit, long cSplitStr, bf16* __restrict__ aux)
{
  constexpr int RA = BM / 64, RB = BN / 64, FM = BM / 32, FN = BN / 32;
  __shared__ __align__(16) bf16 As[2][BM * 32];
  __shared__ __align__(16) bf16 Bs[2][BN * 32];
  const int zc = blockIdx.z % zSplit, zt = blockIdx.z / zSplit;
  const int zn = zt % zN, zb = zt / zN;
  A += (long)zb * aStrB + (long)zn * aStrN + (long)zc * K;
  B += (long)zb * bStrB + (long)zn * bStrN + (long)zc * K;
  int bx = blockIdx.x, by = blockIdx.y;
  if (flags & 8) {
    const int nwg = gridDim.x * gridDim.y;
    const int bid = by * gridDim.x + bx;
    const int qq = nwg >> 3;                      // nwg % 8 == 0 guaranteed by caller
    const int nb = (bid & 7) * qq + (bid >> 3);   // XCD (bid%8) gets contiguous range
    bx = nb % gridDim.x; by = nb / gridDim.x;
  }
  const int tid = threadIdx.x, lane = tid & 63;
  const int w = tid >> 6, wr = w >> 1, wc = w & 1;
  const int m0 = by * BM, n0 = bx * BN;
  const int l15 = lane & 15, l4 = lane >> 4;
  const int rowS = tid >> 2;
  const int cbS  = (tid & 3) * 16;
  const int swS  = cbS ^ (((rowS >> 1) & 3) << 4);
  const int wbase = w * 1024;
  const bf16* Ast = A + (size_t)(m0 + rowS) * lda + (swS >> 1);
  const bf16* Bst = B + (size_t)(n0 + rowS) * ldb + (swS >> 1);

#define STAGE_TILE(buf, kk)                                                       \
  {                                                                               \
    _Pragma("unroll")                                                             \
    for (int r = 0; r < RA; ++r)                                                  \
      gload16(Ast + (size_t)(r * 64) * lda + (kk), (char*)As[buf] + r * 4096 + wbase); \
    _Pragma("unroll")                                                             \
    for (int r = 0; r < RB; ++r)                                                  \
      gload16(Bst + (size_t)(r * 64) * ldb + (kk), (char*)Bs[buf] + r * 4096 + wbase); \
  }

  f32x4 acc[FM][FN] = {};
  STAGE_TILE(0, 0)
  asm volatile("s_waitcnt vmcnt(0)" ::: "memory");
  __syncthreads();
  int cur = 0;
  for (int k0 = 0; k0 < K; k0 += 32) {
    if (k0 + 32 < K) {
      if (cur == 0) STAGE_TILE(1, k0 + 32)
      else          STAGE_TILE(0, k0 + 32)
    }
    short8 af[FM], bfr[FN];
#pragma unroll
    for (int f = 0; f < FM; ++f) {
      const int row = wr * (BM / 2) + f * 16 + l15;
      af[f] = *(const short8*)((char*)As[cur] + row * 64 + ((16 * l4) ^ (((row >> 1) & 3) << 4)));
    }
#pragma unroll
    for (int f = 0; f < FN; ++f) {
      const int row = wc * (BN / 2) + f * 16 + l15;
      bfr[f] = *(const short8*)((char*)Bs[cur] + row * 64 + ((16 * l4) ^ (((row >> 1) & 3) << 4)));
    }
#pragma unroll
    for (int fm = 0; fm < FM; ++fm)
#pragma unroll
      for (int fn = 0; fn < FN; ++fn)
        acc[fm][fn] = __builtin_amdgcn_mfma_f32_16x16x32_bf16(af[fm], bfr[fn], acc[fm][fn], 0, 0, 0);
    asm volatile("s_waitcnt vmcnt(0)" ::: "memory");
    __syncthreads();
    cur ^= 1;
  }
#undef STAGE_TILE
  const int outbf = flags & 1, relu = flags & 4;
  const bool kpk = (flags & 16) && (n0 >= 1024) && (n0 < 2048);
#pragma unroll
  for (int fm = 0; fm < FM; ++fm) {
#pragma unroll
    for (int fn = 0; fn < FN; ++fn) {
      const int col = n0 + wc * (BN / 2) + fn * 16 + l15;
      const int rw0 = m0 + wr * (BM / 2) + fm * 16 + l4 * 4;
      const float bv = (bias && zc == 0) ? bias[(size_t)zb * biasStrB + (size_t)zn * biasStrN + col] : 0.f;
#pragma unroll
      for (int r = 0; r < 4; ++r) {
        float v = (acc[fm][fn][r] + bv) * scale;
        if (relu) v = fmaxf(v, 0.f);
        const int row = rw0 + r;
        if (kpk) {
          // packed K: aux[(row&3)*16 + (col-1024)/64][row>>2][col&63]
          const int bnn = ((row & 3) << 4) + ((col - 1024) >> 6);
          aux[(size_t)bnn * 65536 + (size_t)(row >> 2) * 64 + (col & 63)] = __float2bfloat16(v);
        } else {
          const size_t cOff = (size_t)zb * cStrB + (size_t)zn * cStrN + (size_t)zc * cSplitStr;
          if (outbf) {
            ((bf16*)C + cOff)[(size_t)row * ldc + col] = __float2bfloat16(v);
          } else {
            ((float*)C + cOff)[(size_t)row * ldc + col] = v;
          }
        }
      }
    }
  }
}

// ================= V transpose (j-tile blocked); K now packed by qkv GEMM epilogue =================
__global__ __launch_bounds__(256) void vt_kernel(const bf16* __restrict__ wh,
                                                 bf16* __restrict__ vt)
{
  const int bn = blockIdx.y, b = bn >> 4, n = bn & 15;
  const int j0 = blockIdx.x * 64;
  __shared__ bf16 t[64][72];
  const bf16* src = wh + (size_t)b * 3072 + 2048 + n * 64;
  const int tid = threadIdx.x;
#pragma unroll
  for (int r = 0; r < 16; ++r) {
    const int jl = r * 4 + (tid >> 6), d = tid & 63;
    t[jl][d] = src[(size_t)(j0 + jl) * 12288 + d];
  }
  __syncthreads();
  bf16* dst = vt + (size_t)bn * 65536 + (size_t)j0 * 64;   // block [d][64]
#pragma unroll
  for (int r = 0; r < 16; ++r) {
    const int d = r * 4 + (tid >> 6), j = tid & 63;
    dst[(size_t)d * 64 + j] = t[j][d];
  }
}

// ================= rk repack: rkn[l][n][p][64] =================
__global__ __launch_bounds__(256) void rkpack_kernel(const bf16* __restrict__ rkb,
                                                     bf16* __restrict__ rkn)
{
  const int ln = blockIdx.y, l = ln >> 4, n = ln & 15;
  const int p0 = blockIdx.x * 64;
  const int d = threadIdx.x & 63, pr = threadIdx.x >> 6;
  const bf16* src = rkb + (size_t)l * 1048576 + n * 64 + d;
  bf16* dst = rkn + (size_t)ln * 65536 + d;
#pragma unroll
  for (int r = 0; r < 16; ++r) {
    const int p = p0 + r * 4 + pr;
    dst[(size_t)p * 64] = src[(size_t)p * 1024];
  }
}

// ================= fused flash attention, split-KV x4, LDS-staged K/V/rk =================
// Base-2 softmax: log2(e) folded into Qa/Qb scale -> exp2 everywhere (pm in base-2 domain).
__global__ __launch_bounds__(256) void fattn_kernel(
    const bf16* __restrict__ wh,     // 4096 x 3072 (row = 4*token + b) — Q only
    const bf16* __restrict__ kb,     // [bn][1024 j][64 d]
    const bf16* __restrict__ rkn_l,  // [16 n][1024 p][64 d] (this layer, 16 KB guard after)
    const bf16* __restrict__ vt,     // [bn][16 jt][64 d][64 jl]
    const float* __restrict__ rwb,   // 16 x 64 (this layer)
    const float* __restrict__ rrb,   // 16 x 64
    float* __restrict__ po, float* __restrict__ pm, float* __restrict__ pl)
{
  const int bn = blockIdx.x, b = bn >> 4, n = bn & 15;
  const int q0 = blockIdx.y * 64;
  const int ck = blockIdx.z;
  const int tid = threadIdx.x, w = tid >> 6, lane = tid & 63;
  const int l15 = lane & 15, l4 = lane >> 4;
  __shared__ __align__(16) bf16 Ks[64 * 64];    // 8 KB  [row j][128 B]
  __shared__ __align__(16) bf16 Vs[64 * 64];    // 8 KB  [row d][128 B]
  __shared__ __align__(16) bf16 Rs[128 * 64];   // 16 KB [row p-pstart][128 B]
  __shared__ bf16 Tl[4][16][84];                // wave-private shifted-BD band strips
  __shared__ bf16 Pl[4][16][72];                // wave-private P transpose staging

  // ---- load Q fragments; fold biases AND 0.125*log2(e) scale (base-2 softmax domain) ----
  short8 qa[2], qb[2];
  {
    const bf16* qp = wh + (size_t)(2048 + b) * 3072 + (size_t)(q0 + 16 * w + l15) * 12288 + n * 64;
    const float sc2 = 0.125f * LOG2E;
#pragma unroll
    for (int kk = 0; kk < 2; ++kk) {
      const short8 qv = *(const short8*)(qp + kk * 32 + 8 * l4);
      const float* wv = rwb + n * 64 + kk * 32 + 8 * l4;
      const float* rv = rrb + n * 64 + kk * 32 + 8 * l4;
      short8 a, c;
#pragma unroll
      for (int e = 0; e < 8; ++e) {
        const float q = __bfloat162float(bits2bf(qv[e]));
        const bf16 ab = __float2bfloat16((q + wv[e]) * sc2);
        const bf16 cb = __float2bfloat16((q + rv[e]) * sc2);
        a[e] = *(const short*)&ab;  c[e] = *(const short*)&cb;
      }
      qa[kk] = a; qb[kk] = c;
    }
  }

  const bf16* kbase = kb + (size_t)bn * 65536;                  // + j*64
  const bf16* rbase = rkn_l + (size_t)n * 65536;                // + p*64
  const bf16* vbase = vt + (size_t)bn * 65536;                  // + j0*64 + d*64 + jl
  const int ntiles = 9 + (q0 >> 6);

  // staging geometry: thread tid covers linear LDS bytes [tid*16, tid*16+16) per 4 KB slab
  const int stRow0 = tid >> 3;                  // row within 4 KB slab (32 rows/slab)
  const int stColb = (tid & 7) * 16;
  const int wbase = w * 1024;                   // wave-uniform LDS base within slab
  const int srd = (l15 & 7) << 4;               // read-side swizzle (== row&7 <<4 for all reads)

  f32x4 accO[4] = {};
  float mrow[4] = { -1e30f, -1e30f, -1e30f, -1e30f };
  float lrow[4] = { 0.f, 0.f, 0.f, 0.f };

  for (int t = ck; t < ntiles; t += 4) {
    const int j0 = t * 64;
    const int pstart = j0 - q0 + 448;           // Rs row 0 == global p = pstart (>= 0)
    // ---- stage K/V tiles + rk band into LDS (once per WG) ----
    __syncthreads();                            // previous tile fully consumed
    {
#pragma unroll
      for (int r = 0; r < 2; ++r) {             // K: 2 slabs of 4 KB
        const int row = r * 32 + stRow0;
        gload16(kbase + (size_t)(j0 + row) * 64 + ((stColb ^ ((row & 7) << 4)) >> 1),
                (char*)Ks + r * 4096 + wbase);
      }
#pragma unroll
      for (int r = 0; r < 2; ++r) {             // V: 2 slabs
        const int row = r * 32 + stRow0;
        gload16(vbase + (size_t)j0 * 64 + (size_t)row * 64 + ((stColb ^ ((row & 7) << 4)) >> 1),
                (char*)Vs + r * 4096 + wbase);
      }
#pragma unroll
      for (int r = 0; r < 4; ++r) {             // rk band: 4 slabs (128 rows)
        const int row = r * 32 + stRow0;
        gload16(rbase + (size_t)(pstart + row) * 64 + ((stColb ^ ((row & 7) << 4)) >> 1),
                (char*)Rs + r * 4096 + wbase);
      }
    }
    asm volatile("s_waitcnt vmcnt(0)" ::: "memory");
    __syncthreads();

    // ---- AC: S[fn] = Qa . K^T (from LDS, swizzled) ----
    f32x4 S[4] = {};
#pragma unroll
    for (int fn = 0; fn < 4; ++fn)
#pragma unroll
      for (int kk = 0; kk < 2; ++kk) {
        const short8 kf = *(const short8*)((char*)Ks + (16 * fn + l15) * 128 + ((kk * 64 + 16 * l4) ^ srd));
        S[fn] = __builtin_amdgcn_mfma_f32_16x16x32_bf16(qa[kk], kf, S[fn], 0, 0, 0);
      }
    // ---- BD band: rows (3-w)*16 + 16*ftl + l15 of Rs ----
    {
      f32x4 T[5] = {};
#pragma unroll
      for (int ftl = 0; ftl < 5; ++ftl) {
        const int rrow = (3 - w) * 16 + 16 * ftl + l15;
#pragma unroll
        for (int kk = 0; kk < 2; ++kk) {
          const short8 rf = *(const short8*)((char*)Rs + rrow * 128 + ((kk * 64 + 16 * l4) ^ srd));
          T[ftl] = __builtin_amdgcn_mfma_f32_16x16x32_bf16(qb[kk], rf, T[ftl], 0, 0, 0);
        }
      }
#pragma unroll
      for (int ftl = 0; ftl < 5; ++ftl)
#pragma unroll
        for (int r = 0; r < 4; ++r)
          Tl[w][4 * l4 + r][16 * ftl + l15] = __float2bfloat16(T[ftl][r]);
    }
    // ---- shift-add + mask ----
    const bool fullvalid = (j0 + 63) <= (512 + q0);
    float sv[4][4];
#pragma unroll
    for (int fn = 0; fn < 4; ++fn)
#pragma unroll
      for (int r = 0; r < 4; ++r) {
        const int il = 4 * l4 + r;
        const float tshift = __bfloat162float(Tl[w][il][16 * fn + l15 + 15 - il]);
        const float s = S[fn][r] + tshift;
        const bool valid = fullvalid || (j0 + 16 * fn + l15 - 512 <= q0 + 16 * w + il);
        sv[fn][r] = valid ? s : -1e30f;
      }
    // ---- online softmax, base-2 (row = 16-lane group) ----
#pragma unroll
    for (int r = 0; r < 4; ++r) {
      float m4 = fmaxf(fmaxf(sv[0][r], sv[1][r]), fmaxf(sv[2][r], sv[3][r]));
      m4 = fmaxf(m4, __shfl_xor(m4, 1));
      m4 = fmaxf(m4, __shfl_xor(m4, 2));
      m4 = fmaxf(m4, __shfl_xor(m4, 4));
      m4 = fmaxf(m4, __shfl_xor(m4, 8));
      const float mn = fmaxf(mrow[r], m4);
      const float alpha = exp2f(mrow[r] - mn);
      mrow[r] = mn;
      float ps = 0.f;
#pragma unroll
      for (int fn = 0; fn < 4; ++fn) {
        sv[fn][r] = exp2f(sv[fn][r] - mn);
        ps += sv[fn][r];
      }
      ps += __shfl_xor(ps, 1);
      ps += __shfl_xor(ps, 2);
      ps += __shfl_xor(ps, 4);
      ps += __shfl_xor(ps, 8);
      lrow[r] = lrow[r] * alpha + ps;
#pragma unroll
      for (int fd = 0; fd < 4; ++fd) accO[fd][r] *= alpha;
    }
    // ---- P -> LDS (transpose to A-frag) and PV (V from LDS, swizzled) ----
#pragma unroll
    for (int fn = 0; fn < 4; ++fn)
#pragma unroll
      for (int r = 0; r < 4; ++r)
        Pl[w][4 * l4 + r][16 * fn + l15] = __float2bfloat16(sv[fn][r]);
    short8 pa[2];
    pa[0] = *(const short8*)&Pl[w][l15][8 * l4];
    pa[1] = *(const short8*)&Pl[w][l15][32 + 8 * l4];
#pragma unroll
    for (int fd = 0; fd < 4; ++fd)
#pragma unroll
      for (int kk = 0; kk < 2; ++kk) {
        const short8 vf = *(const short8*)((char*)Vs + (16 * fd + l15) * 128 + ((kk * 64 + 16 * l4) ^ srd));
        accO[fd] = __builtin_amdgcn_mfma_f32_16x16x32_bf16(pa[kk], vf, accO[fd], 0, 0, 0);
      }
  }
  // ---- store unnormalized partials (pm in base-2 domain) ----
  const int cb = ck * 64 + bn;
  float* pob = po + (size_t)cb * 512 * 64;
#pragma unroll
  for (int fd = 0; fd < 4; ++fd)
#pragma unroll
    for (int r = 0; r < 4; ++r) {
      const int row = q0 + 16 * w + 4 * l4 + r;
      pob[(size_t)row * 64 + 16 * fd + l15] = accO[fd][r];
    }
  if (l15 == 0) {
#pragma unroll
    for (int r = 0; r < 4; ++r) {
      const int row = q0 + 16 * w + 4 * l4 + r;
      pm[(size_t)cb * 512 + row] = mrow[r];
      pl[(size_t)cb * 512 + row] = lrow[r];
    }
  }
}

// ================= merge 4 split-KV partials -> av bf16 (base-2 weights) =================
__global__ __launch_bounds__(256) void fmerge_kernel(
    const float* __restrict__ po, const float* __restrict__ pm,
    const float* __restrict__ pl, bf16* __restrict__ av)
{
  const long i = ((long)blockIdx.x * 256 + threadIdx.x) * 4;   // over 64*512*64
  const long bnq = i >> 6;                                     // bn*512 + q
  const int d4 = (int)(i & 63);
  const int bn = (int)(bnq >> 9), q = (int)(bnq & 511);
  const int b = bn >> 4, n = bn & 15;
  float mv[4], lv[4];
#pragma unroll
  for (int c = 0; c < 4; ++c) { mv[c] = pm[c * 32768 + bnq]; lv[c] = pl[c * 32768 + bnq]; }
  const float m = fmaxf(fmaxf(mv[0], mv[1]), fmaxf(mv[2], mv[3]));
  float wv[4], den = 0.f;
#pragma unroll
  for (int c = 0; c < 4; ++c) { wv[c] = exp2f(mv[c] - m); den += wv[c] * lv[c]; }
  const float inv = 1.f / den;
  float4 o = { 0.f, 0.f, 0.f, 0.f };
#pragma unroll
  for (int c = 0; c < 4; ++c) {
    const float4 oc = *(const float4*)(po + (size_t)c * 2097152 + bnq * 64 + d4);
    o.x += wv[c] * oc.x; o.y += wv[c] * oc.y; o.z += wv[c] * oc.z; o.w += wv[c] * oc.w;
  }
  bf16* dst = av + (size_t)(q * 4 + b) * 1024 + n * 64 + d4;
  dst[0] = __float2bfloat16(o.x * inv);
  dst[1] = __float2bfloat16(o.y * inv);
  dst[2] = __float2bfloat16(o.z * inv);
  dst[3] = __float2bfloat16(o.w * inv);
}

// ================= h = LayerNorm(h + x0 + x1), dual write fp32 h + bf16 cat(upper) =================
__global__ __launch_bounds__(256) void add_ln_kernel(
    float* __restrict__ h,
    const float* __restrict__ x0, const float* __restrict__ x1,
    const float* __restrict__ g, const float* __restrict__ bb, bf16* __restrict__ cat)
{
  float* hr = h + (long)blockIdx.x * DM;
  const long o = (long)blockIdx.x * DM;
  bf16* cr = cat + (long)(2048 + blockIdx.x) * DM;
  const int tid = threadIdx.x;
  __shared__ float red[256];
  float v0 = hr[tid]       + x0[o + tid]       + x1[o + tid];
  float v1 = hr[tid + 256] + x0[o + tid + 256] + x1[o + tid + 256];
  float v2 = hr[tid + 512] + x0[o + tid + 512] + x1[o + tid + 512];
  float v3 = hr[tid + 768] + x0[o + tid + 768] + x1[o + tid + 768];
  red[tid] = v0 + v1 + v2 + v3; __syncthreads();
  for (int off = 128; off; off >>= 1) { if (tid < off) red[tid] += red[tid + off]; __syncthreads(); }
  const float mean = red[0] * (1.f / DM); __syncthreads();
  const float d0 = v0 - mean, d1 = v1 - mean, d2 = v2 - mean, d3 = v3 - mean;
  red[tid] = d0 * d0 + d1 * d1 + d2 * d2 + d3 * d3; __syncthreads();
  for (int off = 128; off; off >>= 1) { if (tid < off) red[tid] += red[tid + off]; __syncthreads(); }
  const float inv = rsqrtf(red[0] * (1.f / DM) + 1e-5f);
  const float o0 = d0 * inv * g[tid]       + bb[tid];
  const float o1 = d1 * inv * g[tid + 256] + bb[tid + 256];
  const float o2 = d2 * inv * g[tid + 512] + bb[tid + 512];
  const float o3 = d3 * inv * g[tid + 768] + bb[tid + 768];
  hr[tid]       = o0;  cr[tid]       = __float2bfloat16(o0);
  hr[tid + 256] = o1;  cr[tid + 256] = __float2bfloat16(o1);
  hr[tid + 512] = o2;  cr[tid + 512] = __float2bfloat16(o2);
  hr[tid + 768] = o3;  cr[tid + 768] = __float2bfloat16(o3);
}

// ================= (q,b,d) -> (b,q,d) =================
__global__ __launch_bounds__(256) void out_kernel(const float* __restrict__ h, float* __restrict__ out)
{
  const int t = blockIdx.x, q = t >> 2, b = t & 3;
  const float* hr = h + (long)t * DM;
  float* orow = out + ((long)b * QLEN + q) * DM;
  for (int s = 0; s < 4; ++s) orow[threadIdx.x + 256 * s] = hr[threadIdx.x + 256 * s];
}

extern "C" void kernel_launch(void* const* d_in, const int* in_sizes, int n_in,
                              void* d_out, int out_size, void* d_ws, size_t ws_size,
                              hipStream_t stream)
{
  const int*   ids  = (const int*)d_in[0];
  const float* mems = (const float*)d_in[1];
  const float* e0 = (const float*)d_in[2]; const float* p0 = (const float*)d_in[3];
  const float* e1 = (const float*)d_in[4]; const float* p1 = (const float*)d_in[5];
  const float* e2 = (const float*)d_in[6]; const float* p2 = (const float*)d_in[7];
  const float* e3 = (const float*)d_in[8]; const float* p3 = (const float*)d_in[9];
  const float* qkvw = (const float*)d_in[10];
  const float* rnet = (const float*)d_in[11];
  const float* ow   = (const float*)d_in[12];
  const float* rwb  = (const float*)d_in[13];
  const float* rrb  = (const float*)d_in[14];
  const float* ln1g = (const float*)d_in[15];
  const float* ln1b = (const float*)d_in[16];
  const float* fw1  = (const float*)d_in[17];
  const float* fb1  = (const float*)d_in[18];
  const float* fw2  = (const float*)d_in[19];
  const float* fb2  = (const float*)d_in[20];
  const float* ln2g = (const float*)d_in[21];
  const float* ln2b = (const float*)d_in[22];
  float* out = (float*)d_out;

  // -------- workspace layout --------
  char* p = (char*)d_ws;
  float* h    = (float*)p;            p += (size_t)2048 * 1024 * 4;       // 8 MB
  bf16*  cat0 = (bf16*)p;             p += (size_t)5 * 4096 * 1024 * 2;   // 40 MB (cats[0..4])
  bf16*  pe   = (bf16*)p;             p += (size_t)1024 * 1024 * 2;       // 2 MB
  bf16*  rkb  = (bf16*)p;             p += (size_t)4 * 1024 * 1024 * 2;   // 8 MB (all layers, [p][1024])
  bf16*  rkn  = (bf16*)p;             p += (size_t)(4 * 16 * 1024 * 64 + 8192) * 2; // 8 MB + 16 KB guard
  bf16*  wh   = (bf16*)p;             p += (size_t)4096 * 3072 * 2;       // 24 MB
  bf16*  vt   = (bf16*)p;             p += (size_t)64 * 64 * 1024 * 2;    // 8 MB (j-blocked V^T)
  bf16*  kb   = (bf16*)p;             p += (size_t)64 * 1024 * 64 * 2;    // 8 MB (packed K)
  bf16*  qkvT = (bf16*)p;             p += (size_t)4 * 3072 * 1024 * 2;   // 24 MB
  bf16*  rnT  = (bf16*)p;             p += (size_t)4 * 1024 * 1024 * 2;   // 8 MB
  bf16*  oT   = (bf16*)p;             p += (size_t)4 * 1024 * 1024 * 2;   // 8 MB
  bf16*  f1T  = (bf16*)p;             p += (size_t)4 * 4096 * 1024 * 2;   // 32 MB
  bf16*  f2T  = (bf16*)p;             p += (size_t)4 * 4096 * 1024 * 2;   // 32 MB
  // 64 MB region A: mid (FFN) / partE (embed, 16 MB fp32)
  bf16*  mid  = (bf16*)p;
  float* partE= (float*)p;
  p += (size_t)4 * 16 * 512 * 1024 * 2;                                   // 64 MB
  // 64 MB region B: Aemb+projT (embed) / attn partials po/pm/pl / partP
  bf16*  Aemb = (bf16*)p;
  bf16*  projT= (bf16*)(p + (size_t)2048 * KEMB * 2);
  float* partP= (float*)p;
  float* po   = (float*)p;                                    // 4*64*512*64 fp32 = 32 MB
  float* pm   = (float*)(p + (size_t)32 * 1024 * 1024);       // 512 KB
  float* pl   = (float*)(p + (size_t)33 * 1024 * 1024);       // 512 KB
  p += (size_t)4 * 16 * 512 * 1024 * 2;                                   // 64 MB
  bf16*  av   = (bf16*)p;             p += (size_t)2048 * 1024 * 2;       // 4 MB

  // -------- upfront: embedding, pos-emb, mems conversion, ALL weight transposes --------
  embA_kernel<<<2048, 256, 0, stream>>>(ids, e0, e1, e2, e3, Aemb);
  projT_kernel<<<dim3(KEMB / 32, 32), 256, 0, stream>>>(p0, p1, p2, p3, projT);
  gemm_bf16<128, 64><<<dim3(16, 16, 2), 256, 0, stream>>>(
      Aemb, 0, 0, KEMB, projT, 0, 0, KEMB, partE, 0, 0, 1024,
      KEMB / 2, 32.f, nullptr, 0, 0, 0, 1, 2, 2097152, nullptr);
  embsum_kernel<<<2048, 256, 0, stream>>>(partE, h, cat0);
  posemb_kernel<<<1024, 256, 0, stream>>>(pe);
  memsconv_kernel<<<8192, 256, 0, stream>>>(mems, cat0);

  wtrans_kernel<<<dim3(96, 32, 4), 256, 0, stream>>>(qkvw, qkvT, DM, 3072);
  wtrans_kernel<<<dim3(32, 32, 4), 256, 0, stream>>>(rnet, rnT, DM, DM);
  wtrans_kernel<<<dim3(32, 32, 4), 256, 0, stream>>>(ow, oT, DM, DM);
  wtrans_kernel<<<dim3(128, 32, 4), 256, 0, stream>>>(fw1, f1T, DM, DI);
  wtrans_kernel<<<dim3(32, 128, 4), 256, 0, stream>>>(fw2, f2T, DI, DM);

  // rk = pos_emb @ r_net_w for ALL layers (z = layer), then repack to [l][n][p][64]
  gemm_bf16<128, 128><<<dim3(8, 8, 4), 256, 0, stream>>>(
      pe, 0, 0, 1024, rnT, 1048576, 0, 1024, rkb, 1048576, 0, 1024,
      1024, 1.f, nullptr, 0, 0, 1, 1, 1, 0, nullptr);
  rkpack_kernel<<<dim3(16, 64), 256, 0, stream>>>(rkb, rkn);

  for (int l = 0; l < NL; ++l) {
    bf16* catl = cat0 + (size_t)l * 4194304;
    // w_heads = cat @ qkv_w -> wh (Q/V cols) + kb (K cols packed, flag 16); XCD swizzle
    gemm_bf16<128, 128><<<dim3(24, 32, 1), 256, 0, stream>>>(
        catl, 0, 0, 1024, qkvT + (size_t)l * 3145728, 0, 0, 1024, wh, 0, 0, 3072,
        1024, 1.f, nullptr, 0, 0, 1 | 8 | 16, 1, 1, 0, kb);

    vt_kernel<<<dim3(16, 64), 256, 0, stream>>>(wh, vt);

    // fused flash attention, split-KV x4 -> partials, then merge -> av (bf16)
    fattn_kernel<<<dim3(64, 8, 4), 256, 0, stream>>>(
        wh, kb, rkn + (size_t)l * 1048576, vt,
        rwb + l * NH * DH, rrb + l * NH * DH, po, pm, pl);
    fmerge_kernel<<<2048, 256, 0, stream>>>(po, pm, pl, av);

    // attn_out = av @ o_w (split-K x2, fp32 partials into partP), summed in add_ln
    gemm_bf16<128, 64><<<dim3(16, 16, 2), 256, 0, stream>>>(
        av, 0, 0, 1024, oT + (size_t)l * 1048576, 0, 0, 1024, partP, 0, 0, 1024,
        512, 1.f, nullptr, 0, 0, 0, 1, 2, 2097152, nullptr);
    add_ln_kernel<<<2048, 256, 0, stream>>>(h, partP, partP + 2097152,
                                            ln1g + l * DM, ln1b + l * DM, catl);

    // FFN (ffn1 with XCD-chunked swizzle: 512 % 8 == 0)
    gemm_bf16<128, 128><<<dim3(32, 16, 1), 256, 0, stream>>>(
        catl + (size_t)2048 * 1024, 0, 0, 1024, f1T + (size_t)l * 4194304, 0, 0, 1024,
        mid, 0, 0, 4096, 1024, 1.f, fb1 + (size_t)l * DI, 0, 0, 1 | 4 | 8, 1, 1, 0, nullptr);
    gemm_bf16<128, 64><<<dim3(16, 16, 2), 256, 0, stream>>>(
        mid, 0, 0, 4096, f2T + (size_t)l * 4194304, 0, 0, 4096, partP, 0, 0, 1024,
        2048, 1.f, fb2 + (size_t)l * DM, 0, 0, 0, 1, 2, 2097152, nullptr);
    add_ln_kernel<<<2048, 256, 0, stream>>>(h, partP, partP + 2097152,
                                            ln2g + l * DM, ln2b + l * DM,
                                            cat0 + (size_t)(l + 1) * 4194304);
  }

  out_kernel<<<2048, 256, 0, stream>>>(h, out);
}

// Round 18
// 955.641 us; speedup vs baseline: 1.0427x; 1.0172x over previous
//
#include <hip/hip_runtime.h>
#include <hip/hip_bf16.h>

typedef __attribute__((ext_vector_type(8))) short short8;
typedef __attribute__((ext_vector_type(4))) float f32x4;
typedef __hip_bfloat16 bf16;

#define QLEN 512
#define MLEN 512
#define KLEN 1024
#define BSZ  4
#define DM   1024
#define NH   16
#define DH   64
#define DI   4096
#define NL   4
#define KEMB 1408   // 1024 + 256 + 64 + 16 = 1360, padded to 1408 (x32)
#define LOG2E 1.4426950408889634f

// direct global->LDS DMA, 16 B per lane (wave-uniform LDS base + lane*16)
__device__ __forceinline__ void gload16(const bf16* g, const void* l) {
  __builtin_amdgcn_global_load_lds(
      (const __attribute__((address_space(1))) void*)g,
      (__attribute__((address_space(3))) void*)l, 16, 0, 0);
}

__device__ __forceinline__ bf16 bits2bf(short s) { bf16 h; *(short*)&h = s; return h; }

// ================= adaptive embedding as GEMM: gather A rows (2048 x KEMB, bf16) =================
__global__ __launch_bounds__(256) void embA_kernel(
    const int* __restrict__ ids,
    const float* __restrict__ e0, const float* __restrict__ e1,
    const float* __restrict__ e2, const float* __restrict__ e3,
    bf16* __restrict__ Aemb)
{
  const int t = blockIdx.x;          // t = q*BSZ + b
  const int q = t >> 2, b = t & 3;
  const int id = ids[b * QLEN + q];
  const float* tab; int d, off, koff;
  if (id < 20000)       { tab = e0; d = 1024; off = 0;      koff = 0; }
  else if (id < 40000)  { tab = e1; d = 256;  off = 20000;  koff = 1024; }
  else if (id < 200000) { tab = e2; d = 64;   off = 40000;  koff = 1280; }
  else                  { tab = e3; d = 16;   off = 200000; koff = 1344; }
  bf16* row = Aemb + (long)t * KEMB;
  const float* tr = tab + (long)(id - off) * d;
  for (int k = threadIdx.x; k < KEMB; k += 256) {
    const int kk = k - koff;
    float v = 0.f;
    if (kk >= 0 && kk < d) v = tr[kk];
    row[k] = __float2bfloat16(v);
  }
}

// ================= concat proj^T: projT[n][k] (1024 x KEMB, bf16), zero-padded =================
__global__ __launch_bounds__(256) void projT_kernel(
    const float* __restrict__ p0, const float* __restrict__ p1,
    const float* __restrict__ p2, const float* __restrict__ p3,
    bf16* __restrict__ out)
{
  __shared__ float t[32][33];
  const int k0 = blockIdx.x * 32, n0 = blockIdx.y * 32;
  const int nx = threadIdx.x & 31, ky = threadIdx.x >> 5;
#pragma unroll
  for (int p = 0; p < 4; ++p) {
    const int k = k0 + ky + p * 8;
    float v = 0.f;
    if (k < 1024)       v = p0[(long)k * 1024 + n0 + nx];
    else if (k < 1280)  v = p1[(long)(k - 1024) * 1024 + n0 + nx];
    else if (k < 1344)  v = p2[(long)(k - 1280) * 1024 + n0 + nx];
    else if (k < 1360)  v = p3[(long)(k - 1344) * 1024 + n0 + nx];
    t[ky + p * 8][nx] = v;
  }
  __syncthreads();
#pragma unroll
  for (int p = 0; p < 4; ++p)
    out[(long)(n0 + ky + p * 8) * KEMB + k0 + nx] = __float2bfloat16(t[nx][ky + p * 8]);
}

// ================= sum 2 fp32 partials -> h fp32 + cat bf16 (upper) =================
__global__ __launch_bounds__(256) void embsum_kernel(const float* __restrict__ part,
                                                     float* __restrict__ h, bf16* __restrict__ cat)
{
  const long i = ((long)blockIdx.x * 256 + threadIdx.x) * 4;
  const float4 a = *(const float4*)(part + i);
  const float4 b = *(const float4*)(part + 2097152 + i);
  float4 s; s.x = a.x + b.x; s.y = a.y + b.y; s.z = a.z + b.z; s.w = a.w + b.w;
  *(float4*)(h + i) = s;
  bf16* cr = cat + (long)2048 * 1024 + i;
  cr[0] = __float2bfloat16(s.x); cr[1] = __float2bfloat16(s.y);
  cr[2] = __float2bfloat16(s.z); cr[3] = __float2bfloat16(s.w);
}

// ================= sinusoidal pos emb -> bf16 =================
__global__ __launch_bounds__(256) void posemb_kernel(bf16* __restrict__ pe)
{
  const int j = blockIdx.x;
  const float pos = (float)(KLEN - 1 - j);
  for (int i = threadIdx.x; i < DM / 2; i += 256) {
    const float freq = expf(-9.210340371976184f * ((float)(2 * i) / (float)DM));
    const float ang = pos * freq;
    pe[(long)j * DM + i]          = __float2bfloat16(sinf(ang));
    pe[(long)j * DM + DM / 2 + i] = __float2bfloat16(cosf(ang));
  }
}

// ================= fp32 (R x C) -> bf16 transposed (C x R), z = layer =================
__global__ __launch_bounds__(256) void wtrans_kernel(const float* __restrict__ in,
                                                     bf16* __restrict__ out, int R, int C)
{
  __shared__ float t[32][33];
  in  += (long)blockIdx.z * R * C;
  out += (long)blockIdx.z * R * C;
  const int c0 = blockIdx.x * 32, r0 = blockIdx.y * 32;
  const int cx = threadIdx.x & 31, ry = threadIdx.x >> 5;
#pragma unroll
  for (int p = 0; p < 4; ++p)
    t[ry + p * 8][cx] = in[(long)(r0 + ry + p * 8) * C + c0 + cx];
  __syncthreads();
#pragma unroll
  for (int p = 0; p < 4; ++p)
    out[(long)(c0 + ry + p * 8) * R + r0 + cx] = __float2bfloat16(t[cx][ry + p * 8]);
}

// ================= all mems (NL x 2048 x 1024 fp32) -> lower halves of cats[l] =================
__global__ __launch_bounds__(256) void memsconv_kernel(const float* __restrict__ mems,
                                                       bf16* __restrict__ cat0)
{
  const long i = ((long)blockIdx.x * 256 + threadIdx.x) * 4;   // over NL*2048*1024
  const long l = i >> 21, rem = i & ((1 << 21) - 1);
  const float4 v = *(const float4*)(mems + i);
  bf16* dst = cat0 + l * 4194304 + rem;
  dst[0] = __float2bfloat16(v.x); dst[1] = __float2bfloat16(v.y);
  dst[2] = __float2bfloat16(v.z); dst[3] = __float2bfloat16(v.w);
}

// ================= bf16 MFMA GEMM:  C = scale*(A @ B^T_supplied + colbias)  =================
// flags: 1 = bf16 out, 4 = relu, 8 = XCD-chunked block swizzle (nwg % 8 == 0, z == 1),
// 16 = K-pack fusion: blocks with cols in [1024,2048) write to aux[bn][j][64]
//      (packed K for fattn) instead of C.
template<int BM, int BN>
__global__ __launch_bounds__(256) void gemm_bf16(
    const bf16* __restrict__ A, long aStrB, long aStrN, int lda,
    const bf16* __restrict__ B, long bStrB, long bStrN, int ldb,
    void* __restrict__ C, long cStrB, long cStrN, int ldc,
    int K, float scale, const float* __restrict__ bias, long biasStrB, long biasStrN,
    int flags, int zN, int zSplit, long cSplitStr, bf16* __restrict__ aux)
{
  constexpr int RA = BM / 64, RB = BN / 64, FM = BM / 32, FN = BN / 32;
  __shared__ __align__(16) bf16 As[2][BM * 32];
  __shared__ __align__(16) bf16 Bs[2][BN * 32];
  const int zc = blockIdx.z % zSplit, zt = blockIdx.z / zSplit;
  const int zn = zt % zN, zb = zt / zN;
  A += (long)zb * aStrB + (long)zn * aStrN + (long)zc * K;
  B += (long)zb * bStrB + (long)zn * bStrN + (long)zc * K;
  int bx = blockIdx.x, by = blockIdx.y;
  if (flags & 8) {
    const int nwg = gridDim.x * gridDim.y;
    const int bid = by * gridDim.x + bx;
    const int qq = nwg >> 3;                      // nwg % 8 == 0 guaranteed by caller
    const int nb = (bid & 7) * qq + (bid >> 3);   // XCD (bid%8) gets contiguous range
    bx = nb % gridDim.x; by = nb / gridDim.x;
  }
  const int tid = threadIdx.x, lane = tid & 63;
  const int w = tid >> 6, wr = w >> 1, wc = w & 1;
  const int m0 = by * BM, n0 = bx * BN;
  const int l15 = lane & 15, l4 = lane >> 4;
  const int rowS = tid >> 2;
  const int cbS  = (tid & 3) * 16;
  const int swS  = cbS ^ (((rowS >> 1) & 3) << 4);
  const int wbase = w * 1024;
  const bf16* Ast = A + (size_t)(m0 + rowS) * lda + (swS >> 1);
  const bf16* Bst = B + (size_t)(n0 + rowS) * ldb + (swS >> 1);

#define STAGE_TILE(buf, kk)                                                       \
  {                                                                               \
    _Pragma("unroll")                                                             \
    for (int r = 0; r < RA; ++r)                                                  \
      gload16(Ast + (size_t)(r * 64) * lda + (kk), (char*)As[buf] + r * 4096 + wbase); \
    _Pragma("unroll")                                                             \
    for (int r = 0; r < RB; ++r)                                                  \
      gload16(Bst + (size_t)(r * 64) * ldb + (kk), (char*)Bs[buf] + r * 4096 + wbase); \
  }

  f32x4 acc[FM][FN] = {};
  STAGE_TILE(0, 0)
  asm volatile("s_waitcnt vmcnt(0)" ::: "memory");
  __syncthreads();
  int cur = 0;
  for (int k0 = 0; k0 < K; k0 += 32) {
    if (k0 + 32 < K) {
      if (cur == 0) STAGE_TILE(1, k0 + 32)
      else          STAGE_TILE(0, k0 + 32)
    }
    short8 af[FM], bfr[FN];
#pragma unroll
    for (int f = 0; f < FM; ++f) {
      const int row = wr * (BM / 2) + f * 16 + l15;
      af[f] = *(const short8*)((char*)As[cur] + row * 64 + ((16 * l4) ^ (((row >> 1) & 3) << 4)));
    }
#pragma unroll
    for (int f = 0; f < FN; ++f) {
      const int row = wc * (BN / 2) + f * 16 + l15;
      bfr[f] = *(const short8*)((char*)Bs[cur] + row * 64 + ((16 * l4) ^ (((row >> 1) & 3) << 4)));
    }
#pragma unroll
    for (int fm = 0; fm < FM; ++fm)
#pragma unroll
      for (int fn = 0; fn < FN; ++fn)
        acc[fm][fn] = __builtin_amdgcn_mfma_f32_16x16x32_bf16(af[fm], bfr[fn], acc[fm][fn], 0, 0, 0);
    asm volatile("s_waitcnt vmcnt(0)" ::: "memory");
    __syncthreads();
    cur ^= 1;
  }
#undef STAGE_TILE
  const int outbf = flags & 1, relu = flags & 4;
  const bool kpk = (flags & 16) && (n0 >= 1024) && (n0 < 2048);
#pragma unroll
  for (int fm = 0; fm < FM; ++fm) {
#pragma unroll
    for (int fn = 0; fn < FN; ++fn) {
      const int col = n0 + wc * (BN / 2) + fn * 16 + l15;
      const int rw0 = m0 + wr * (BM / 2) + fm * 16 + l4 * 4;
      const float bv = (bias && zc == 0) ? bias[(size_t)zb * biasStrB + (size_t)zn * biasStrN + col] : 0.f;
#pragma unroll
      for (int r = 0; r < 4; ++r) {
        float v = (acc[fm][fn][r] + bv) * scale;
        if (relu) v = fmaxf(v, 0.f);
        const int row = rw0 + r;
        if (kpk) {
          // packed K: aux[(row&3)*16 + (col-1024)/64][row>>2][col&63]
          const int bnn = ((row & 3) << 4) + ((col - 1024) >> 6);
          aux[(size_t)bnn * 65536 + (size_t)(row >> 2) * 64 + (col & 63)] = __float2bfloat16(v);
        } else {
          const size_t cOff = (size_t)zb * cStrB + (size_t)zn * cStrN + (size_t)zc * cSplitStr;
          if (outbf) {
            ((bf16*)C + cOff)[(size_t)row * ldc + col] = __float2bfloat16(v);
          } else {
            ((float*)C + cOff)[(size_t)row * ldc + col] = v;
          }
        }
      }
    }
  }
}

// ================= V transpose (j-tile blocked); K packed by qkv GEMM epilogue =================
__global__ __launch_bounds__(256) void vt_kernel(const bf16* __restrict__ wh,
                                                 bf16* __restrict__ vt)
{
  const int bn = blockIdx.y, b = bn >> 4, n = bn & 15;
  const int j0 = blockIdx.x * 64;
  __shared__ bf16 t[64][72];
  const bf16* src = wh + (size_t)b * 3072 + 2048 + n * 64;
  const int tid = threadIdx.x;
#pragma unroll
  for (int r = 0; r < 16; ++r) {
    const int jl = r * 4 + (tid >> 6), d = tid & 63;
    t[jl][d] = src[(size_t)(j0 + jl) * 12288 + d];
  }
  __syncthreads();
  bf16* dst = vt + (size_t)bn * 65536 + (size_t)j0 * 64;   // block [d][64]
#pragma unroll
  for (int r = 0; r < 16; ++r) {
    const int d = r * 4 + (tid >> 6), j = tid & 63;
    dst[(size_t)d * 64 + j] = t[j][d];
  }
}

// ================= rk repack: rkn[l][n][p][64] =================
__global__ __launch_bounds__(256) void rkpack_kernel(const bf16* __restrict__ rkb,
                                                     bf16* __restrict__ rkn)
{
  const int ln = blockIdx.y, l = ln >> 4, n = ln & 15;
  const int p0 = blockIdx.x * 64;
  const int d = threadIdx.x & 63, pr = threadIdx.x >> 6;
  const bf16* src = rkb + (size_t)l * 1048576 + n * 64 + d;
  bf16* dst = rkn + (size_t)ln * 65536 + d;
#pragma unroll
  for (int r = 0; r < 16; ++r) {
    const int p = p0 + r * 4 + pr;
    dst[(size_t)p * 64] = src[(size_t)p * 1024];
  }
}

// ================= fused flash attention, split-KV x4, LDS-staged K/V/rk =================
// Base-2 softmax: log2(e) folded into Qa/Qb scale -> exp2 everywhere (pm in base-2 domain).
__global__ __launch_bounds__(256) void fattn_kernel(
    const bf16* __restrict__ wh,     // 4096 x 3072 (row = 4*token + b) — Q only
    const bf16* __restrict__ kb,     // [bn][1024 j][64 d]
    const bf16* __restrict__ rkn_l,  // [16 n][1024 p][64 d] (this layer, 16 KB guard after)
    const bf16* __restrict__ vt,     // [bn][16 jt][64 d][64 jl]
    const float* __restrict__ rwb,   // 16 x 64 (this layer)
    const float* __restrict__ rrb,   // 16 x 64
    float* __restrict__ po, float* __restrict__ pm, float* __restrict__ pl)
{
  const int bn = blockIdx.x, b = bn >> 4, n = bn & 15;
  const int q0 = blockIdx.y * 64;
  const int ck = blockIdx.z;
  const int tid = threadIdx.x, w = tid >> 6, lane = tid & 63;
  const int l15 = lane & 15, l4 = lane >> 4;
  __shared__ __align__(16) bf16 Ks[64 * 64];    // 8 KB  [row j][128 B]
  __shared__ __align__(16) bf16 Vs[64 * 64];    // 8 KB  [row d][128 B]
  __shared__ __align__(16) bf16 Rs[128 * 64];   // 16 KB [row p-pstart][128 B]
  __shared__ bf16 Tl[4][16][84];                // wave-private shifted-BD band strips
  __shared__ bf16 Pl[4][16][72];                // wave-private P transpose staging

  // ---- load Q fragments; fold biases AND 0.125*log2(e) scale (base-2 softmax domain) ----
  short8 qa[2], qb[2];
  {
    const bf16* qp = wh + (size_t)(2048 + b) * 3072 + (size_t)(q0 + 16 * w + l15) * 12288 + n * 64;
    const float sc2 = 0.125f * LOG2E;
#pragma unroll
    for (int kk = 0; kk < 2; ++kk) {
      const short8 qv = *(const short8*)(qp + kk * 32 + 8 * l4);
      const float* wv = rwb + n * 64 + kk * 32 + 8 * l4;
      const float* rv = rrb + n * 64 + kk * 32 + 8 * l4;
      short8 a, c;
#pragma unroll
      for (int e = 0; e < 8; ++e) {
        const float q = __bfloat162float(bits2bf(qv[e]));
        const bf16 ab = __float2bfloat16((q + wv[e]) * sc2);
        const bf16 cb = __float2bfloat16((q + rv[e]) * sc2);
        a[e] = *(const short*)&ab;  c[e] = *(const short*)&cb;
      }
      qa[kk] = a; qb[kk] = c;
    }
  }

  const bf16* kbase = kb + (size_t)bn * 65536;                  // + j*64
  const bf16* rbase = rkn_l + (size_t)n * 65536;                // + p*64
  const bf16* vbase = vt + (size_t)bn * 65536;                  // + j0*64 + d*64 + jl
  const int ntiles = 9 + (q0 >> 6);

  // staging geometry: thread tid covers linear LDS bytes [tid*16, tid*16+16) per 4 KB slab
  const int stRow0 = tid >> 3;                  // row within 4 KB slab (32 rows/slab)
  const int stColb = (tid & 7) * 16;
  const int wbase = w * 1024;                   // wave-uniform LDS base within slab
  const int srd = (l15 & 7) << 4;               // read-side swizzle (== row&7 <<4 for all reads)

  f32x4 accO[4] = {};
  float mrow[4] = { -1e30f, -1e30f, -1e30f, -1e30f };
  float lrow[4] = { 0.f, 0.f, 0.f, 0.f };

  for (int t = ck; t < ntiles; t += 4) {
    const int j0 = t * 64;
    const int pstart = j0 - q0 + 448;           // Rs row 0 == global p = pstart (>= 0)
    // ---- stage K/V tiles + rk band into LDS (once per WG) ----
    __syncthreads();                            // previous tile fully consumed
    {
#pragma unroll
      for (int r = 0; r < 2; ++r) {             // K: 2 slabs of 4 KB
        const int row = r * 32 + stRow0;
        gload16(kbase + (size_t)(j0 + row) * 64 + ((stColb ^ ((row & 7) << 4)) >> 1),
                (char*)Ks + r * 4096 + wbase);
      }
#pragma unroll
      for (int r = 0; r < 2; ++r) {             // V: 2 slabs
        const int row = r * 32 + stRow0;
        gload16(vbase + (size_t)j0 * 64 + (size_t)row * 64 + ((stColb ^ ((row & 7) << 4)) >> 1),
                (char*)Vs + r * 4096 + wbase);
      }
#pragma unroll
      for (int r = 0; r < 4; ++r) {             // rk band: 4 slabs (128 rows)
        const int row = r * 32 + stRow0;
        gload16(rbase + (size_t)(pstart + row) * 64 + ((stColb ^ ((row & 7) << 4)) >> 1),
                (char*)Rs + r * 4096 + wbase);
      }
    }
    asm volatile("s_waitcnt vmcnt(0)" ::: "memory");
    __syncthreads();

    // ---- AC: S[fn] = Qa . K^T (from LDS, swizzled) ----
    f32x4 S[4] = {};
#pragma unroll
    for (int fn = 0; fn < 4; ++fn)
#pragma unroll
      for (int kk = 0; kk < 2; ++kk) {
        const short8 kf = *(const short8*)((char*)Ks + (16 * fn + l15) * 128 + ((kk * 64 + 16 * l4) ^ srd));
        S[fn] = __builtin_amdgcn_mfma_f32_16x16x32_bf16(qa[kk], kf, S[fn], 0, 0, 0);
      }
    // ---- BD band: rows (3-w)*16 + 16*ftl + l15 of Rs ----
    {
      f32x4 T[5] = {};
#pragma unroll
      for (int ftl = 0; ftl < 5; ++ftl) {
        const int rrow = (3 - w) * 16 + 16 * ftl + l15;
#pragma unroll
        for (int kk = 0; kk < 2; ++kk) {
          const short8 rf = *(const short8*)((char*)Rs + rrow * 128 + ((kk * 64 + 16 * l4) ^ srd));
          T[ftl] = __builtin_amdgcn_mfma_f32_16x16x32_bf16(qb[kk], rf, T[ftl], 0, 0, 0);
        }
      }
#pragma unroll
      for (int ftl = 0; ftl < 5; ++ftl)
#pragma unroll
        for (int r = 0; r < 4; ++r)
          Tl[w][4 * l4 + r][16 * ftl + l15] = __float2bfloat16(T[ftl][r]);
    }
    // ---- shift-add + mask ----
    const bool fullvalid = (j0 + 63) <= (512 + q0);
    float sv[4][4];
#pragma unroll
    for (int fn = 0; fn < 4; ++fn)
#pragma unroll
      for (int r = 0; r < 4; ++r) {
        const int il = 4 * l4 + r;
        const float tshift = __bfloat162float(Tl[w][il][16 * fn + l15 + 15 - il]);
        const float s = S[fn][r] + tshift;
        const bool valid = fullvalid || (j0 + 16 * fn + l15 - 512 <= q0 + 16 * w + il);
        sv[fn][r] = valid ? s : -1e30f;
      }
    // ---- online softmax, base-2 (row = 16-lane group) ----
#pragma unroll
    for (int r = 0; r < 4; ++r) {
      float m4 = fmaxf(fmaxf(sv[0][r], sv[1][r]), fmaxf(sv[2][r], sv[3][r]));
      m4 = fmaxf(m4, __shfl_xor(m4, 1));
      m4 = fmaxf(m4, __shfl_xor(m4, 2));
      m4 = fmaxf(m4, __shfl_xor(m4, 4));
      m4 = fmaxf(m4, __shfl_xor(m4, 8));
      const float mn = fmaxf(mrow[r], m4);
      const float alpha = exp2f(mrow[r] - mn);
      mrow[r] = mn;
      float ps = 0.f;
#pragma unroll
      for (int fn = 0; fn < 4; ++fn) {
        sv[fn][r] = exp2f(sv[fn][r] - mn);
        ps += sv[fn][r];
      }
      ps += __shfl_xor(ps, 1);
      ps += __shfl_xor(ps, 2);
      ps += __shfl_xor(ps, 4);
      ps += __shfl_xor(ps, 8);
      lrow[r] = lrow[r] * alpha + ps;
#pragma unroll
      for (int fd = 0; fd < 4; ++fd) accO[fd][r] *= alpha;
    }
    // ---- P -> LDS (transpose to A-frag) and PV (V from LDS, swizzled) ----
#pragma unroll
    for (int fn = 0; fn < 4; ++fn)
#pragma unroll
      for (int r = 0; r < 4; ++r)
        Pl[w][4 * l4 + r][16 * fn + l15] = __float2bfloat16(sv[fn][r]);
    short8 pa[2];
    pa[0] = *(const short8*)&Pl[w][l15][8 * l4];
    pa[1] = *(const short8*)&Pl[w][l15][32 + 8 * l4];
#pragma unroll
    for (int fd = 0; fd < 4; ++fd)
#pragma unroll
      for (int kk = 0; kk < 2; ++kk) {
        const short8 vf = *(const short8*)((char*)Vs + (16 * fd + l15) * 128 + ((kk * 64 + 16 * l4) ^ srd));
        accO[fd] = __builtin_amdgcn_mfma_f32_16x16x32_bf16(pa[kk], vf, accO[fd], 0, 0, 0);
      }
  }
  // ---- store unnormalized partials (pm in base-2 domain) ----
  const int cb = ck * 64 + bn;
  float* pob = po + (size_t)cb * 512 * 64;
#pragma unroll
  for (int fd = 0; fd < 4; ++fd)
#pragma unroll
    for (int r = 0; r < 4; ++r) {
      const int row = q0 + 16 * w + 4 * l4 + r;
      pob[(size_t)row * 64 + 16 * fd + l15] = accO[fd][r];
    }
  if (l15 == 0) {
#pragma unroll
    for (int r = 0; r < 4; ++r) {
      const int row = q0 + 16 * w + 4 * l4 + r;
      pm[(size_t)cb * 512 + row] = mrow[r];
      pl[(size_t)cb * 512 + row] = lrow[r];
    }
  }
}

// ================= merge 4 split-KV partials -> av bf16 (base-2 weights) =================
__global__ __launch_bounds__(256) void fmerge_kernel(
    const float* __restrict__ po, const float* __restrict__ pm,
    const float* __restrict__ pl, bf16* __restrict__ av)
{
  const long i = ((long)blockIdx.x * 256 + threadIdx.x) * 4;   // over 64*512*64
  const long bnq = i >> 6;                                     // bn*512 + q
  const int d4 = (int)(i & 63);
  const int bn = (int)(bnq >> 9), q = (int)(bnq & 511);
  const int b = bn >> 4, n = bn & 15;
  float mv[4], lv[4];
#pragma unroll
  for (int c = 0; c < 4; ++c) { mv[c] = pm[c * 32768 + bnq]; lv[c] = pl[c * 32768 + bnq]; }
  const float m = fmaxf(fmaxf(mv[0], mv[1]), fmaxf(mv[2], mv[3]));
  float wv[4], den = 0.f;
#pragma unroll
  for (int c = 0; c < 4; ++c) { wv[c] = exp2f(mv[c] - m); den += wv[c] * lv[c]; }
  const float inv = 1.f / den;
  float4 o = { 0.f, 0.f, 0.f, 0.f };
#pragma unroll
  for (int c = 0; c < 4; ++c) {
    const float4 oc = *(const float4*)(po + (size_t)c * 2097152 + bnq * 64 + d4);
    o.x += wv[c] * oc.x; o.y += wv[c] * oc.y; o.z += wv[c] * oc.z; o.w += wv[c] * oc.w;
  }
  bf16* dst = av + (size_t)(q * 4 + b) * 1024 + n * 64 + d4;
  dst[0] = __float2bfloat16(o.x * inv);
  dst[1] = __float2bfloat16(o.y * inv);
  dst[2] = __float2bfloat16(o.z * inv);
  dst[3] = __float2bfloat16(o.w * inv);
}

// ================= h = LayerNorm(h + x0 + x1), bf16 addends (split-K partials) =================
__global__ __launch_bounds__(256) void add_ln_kernel(
    float* __restrict__ h,
    const bf16* __restrict__ x0, const bf16* __restrict__ x1,
    const float* __restrict__ g, const float* __restrict__ bb, bf16* __restrict__ cat)
{
  float* hr = h + (long)blockIdx.x * DM;
  const long o = (long)blockIdx.x * DM;
  bf16* cr = cat + (long)(2048 + blockIdx.x) * DM;
  const int tid = threadIdx.x;
  __shared__ float red[256];
  float v0 = hr[tid]       + __bfloat162float(x0[o + tid])       + __bfloat162float(x1[o + tid]);
  float v1 = hr[tid + 256] + __bfloat162float(x0[o + tid + 256]) + __bfloat162float(x1[o + tid + 256]);
  float v2 = hr[tid + 512] + __bfloat162float(x0[o + tid + 512]) + __bfloat162float(x1[o + tid + 512]);
  float v3 = hr[tid + 768] + __bfloat162float(x0[o + tid + 768]) + __bfloat162float(x1[o + tid + 768]);
  red[tid] = v0 + v1 + v2 + v3; __syncthreads();
  for (int off = 128; off; off >>= 1) { if (tid < off) red[tid] += red[tid + off]; __syncthreads(); }
  const float mean = red[0] * (1.f / DM); __syncthreads();
  const float d0 = v0 - mean, d1 = v1 - mean, d2 = v2 - mean, d3 = v3 - mean;
  red[tid] = d0 * d0 + d1 * d1 + d2 * d2 + d3 * d3; __syncthreads();
  for (int off = 128; off; off >>= 1) { if (tid < off) red[tid] += red[tid + off]; __syncthreads(); }
  const float inv = rsqrtf(red[0] * (1.f / DM) + 1e-5f);
  const float o0 = d0 * inv * g[tid]       + bb[tid];
  const float o1 = d1 * inv * g[tid + 256] + bb[tid + 256];
  const float o2 = d2 * inv * g[tid + 512] + bb[tid + 512];
  const float o3 = d3 * inv * g[tid + 768] + bb[tid + 768];
  hr[tid]       = o0;  cr[tid]       = __float2bfloat16(o0);
  hr[tid + 256] = o1;  cr[tid + 256] = __float2bfloat16(o1);
  hr[tid + 512] = o2;  cr[tid + 512] = __float2bfloat16(o2);
  hr[tid + 768] = o3;  cr[tid + 768] = __float2bfloat16(o3);
}

// ================= (q,b,d) -> (b,q,d) =================
__global__ __launch_bounds__(256) void out_kernel(const float* __restrict__ h, float* __restrict__ out)
{
  const int t = blockIdx.x, q = t >> 2, b = t & 3;
  const float* hr = h + (long)t * DM;
  float* orow = out + ((long)b * QLEN + q) * DM;
  for (int s = 0; s < 4; ++s) orow[threadIdx.x + 256 * s] = hr[threadIdx.x + 256 * s];
}

extern "C" void kernel_launch(void* const* d_in, const int* in_sizes, int n_in,
                              void* d_out, int out_size, void* d_ws, size_t ws_size,
                              hipStream_t stream)
{
  const int*   ids  = (const int*)d_in[0];
  const float* mems = (const float*)d_in[1];
  const float* e0 = (const float*)d_in[2]; const float* p0 = (const float*)d_in[3];
  const float* e1 = (const float*)d_in[4]; const float* p1 = (const float*)d_in[5];
  const float* e2 = (const float*)d_in[6]; const float* p2 = (const float*)d_in[7];
  const float* e3 = (const float*)d_in[8]; const float* p3 = (const float*)d_in[9];
  const float* qkvw = (const float*)d_in[10];
  const float* rnet = (const float*)d_in[11];
  const float* ow   = (const float*)d_in[12];
  const float* rwb  = (const float*)d_in[13];
  const float* rrb  = (const float*)d_in[14];
  const float* ln1g = (const float*)d_in[15];
  const float* ln1b = (const float*)d_in[16];
  const float* fw1  = (const float*)d_in[17];
  const float* fb1  = (const float*)d_in[18];
  const float* fw2  = (const float*)d_in[19];
  const float* fb2  = (const float*)d_in[20];
  const float* ln2g = (const float*)d_in[21];
  const float* ln2b = (const float*)d_in[22];
  float* out = (float*)d_out;

  // -------- workspace layout --------
  char* p = (char*)d_ws;
  float* h    = (float*)p;            p += (size_t)2048 * 1024 * 4;       // 8 MB
  bf16*  cat0 = (bf16*)p;             p += (size_t)5 * 4096 * 1024 * 2;   // 40 MB (cats[0..4])
  bf16*  pe   = (bf16*)p;             p += (size_t)1024 * 1024 * 2;       // 2 MB
  bf16*  rkb  = (bf16*)p;             p += (size_t)4 * 1024 * 1024 * 2;   // 8 MB (all layers, [p][1024])
  bf16*  rkn  = (bf16*)p;             p += (size_t)(4 * 16 * 1024 * 64 + 8192) * 2; // 8 MB + 16 KB guard
  bf16*  wh   = (bf16*)p;             p += (size_t)4096 * 3072 * 2;       // 24 MB
  bf16*  vt   = (bf16*)p;             p += (size_t)64 * 64 * 1024 * 2;    // 8 MB (j-blocked V^T)
  bf16*  kb   = (bf16*)p;             p += (size_t)64 * 1024 * 64 * 2;    // 8 MB (packed K)
  bf16*  qkvT = (bf16*)p;             p += (size_t)4 * 3072 * 1024 * 2;   // 24 MB
  bf16*  rnT  = (bf16*)p;             p += (size_t)4 * 1024 * 1024 * 2;   // 8 MB
  bf16*  oT   = (bf16*)p;             p += (size_t)4 * 1024 * 1024 * 2;   // 8 MB
  bf16*  f1T  = (bf16*)p;             p += (size_t)4 * 4096 * 1024 * 2;   // 32 MB
  bf16*  f2T  = (bf16*)p;             p += (size_t)4 * 4096 * 1024 * 2;   // 32 MB
  // 64 MB region A: mid (FFN) / partE (embed, 16 MB fp32)
  bf16*  mid  = (bf16*)p;
  float* partE= (float*)p;
  p += (size_t)4 * 16 * 512 * 1024 * 2;                                   // 64 MB
  // 64 MB region B: Aemb+projT (embed) / attn partials po/pm/pl / partPb (bf16 split-K partials)
  bf16*  Aemb = (bf16*)p;
  bf16*  projT= (bf16*)(p + (size_t)2048 * KEMB * 2);
  bf16*  partPb = (bf16*)p;                                   // 2 x 2048x1024 bf16 = 8 MB
  float* po   = (float*)p;                                    // 4*64*512*64 fp32 = 32 MB
  float* pm   = (float*)(p + (size_t)32 * 1024 * 1024);       // 512 KB
  float* pl   = (float*)(p + (size_t)33 * 1024 * 1024);       // 512 KB
  p += (size_t)4 * 16 * 512 * 1024 * 2;                                   // 64 MB
  bf16*  av   = (bf16*)p;             p += (size_t)2048 * 1024 * 2;       // 4 MB

  // NOTE: partPb (proj/ffn2 partials) and po/pm/pl (attn partials) share region B
  // but are used in disjoint phases: attn partials are consumed by fmerge BEFORE
  // the proj GEMM writes partPb; ffn2 partials are consumed before next layer's attn.

  // -------- upfront: embedding, pos-emb, mems conversion, ALL weight transposes --------
  embA_kernel<<<2048, 256, 0, stream>>>(ids, e0, e1, e2, e3, Aemb);
  projT_kernel<<<dim3(KEMB / 32, 32), 256, 0, stream>>>(p0, p1, p2, p3, projT);
  gemm_bf16<128, 64><<<dim3(16, 16, 2), 256, 0, stream>>>(
      Aemb, 0, 0, KEMB, projT, 0, 0, KEMB, partE, 0, 0, 1024,
      KEMB / 2, 32.f, nullptr, 0, 0, 0, 1, 2, 2097152, nullptr);
  embsum_kernel<<<2048, 256, 0, stream>>>(partE, h, cat0);
  posemb_kernel<<<1024, 256, 0, stream>>>(pe);
  memsconv_kernel<<<8192, 256, 0, stream>>>(mems, cat0);

  wtrans_kernel<<<dim3(96, 32, 4), 256, 0, stream>>>(qkvw, qkvT, DM, 3072);
  wtrans_kernel<<<dim3(32, 32, 4), 256, 0, stream>>>(rnet, rnT, DM, DM);
  wtrans_kernel<<<dim3(32, 32, 4), 256, 0, stream>>>(ow, oT, DM, DM);
  wtrans_kernel<<<dim3(128, 32, 4), 256, 0, stream>>>(fw1, f1T, DM, DI);
  wtrans_kernel<<<dim3(32, 128, 4), 256, 0, stream>>>(fw2, f2T, DI, DM);

  // rk = pos_emb @ r_net_w for ALL layers (z = layer), then repack to [l][n][p][64]
  gemm_bf16<128, 128><<<dim3(8, 8, 4), 256, 0, stream>>>(
      pe, 0, 0, 1024, rnT, 1048576, 0, 1024, rkb, 1048576, 0, 1024,
      1024, 1.f, nullptr, 0, 0, 1, 1, 1, 0, nullptr);
  rkpack_kernel<<<dim3(16, 64), 256, 0, stream>>>(rkb, rkn);

  for (int l = 0; l < NL; ++l) {
    bf16* catl = cat0 + (size_t)l * 4194304;
    // w_heads = cat @ qkv_w -> wh (Q/V cols) + kb (K cols packed, flag 16); XCD swizzle
    gemm_bf16<128, 128><<<dim3(24, 32, 1), 256, 0, stream>>>(
        catl, 0, 0, 1024, qkvT + (size_t)l * 3145728, 0, 0, 1024, wh, 0, 0, 3072,
        1024, 1.f, nullptr, 0, 0, 1 | 8 | 16, 1, 1, 0, kb);

    vt_kernel<<<dim3(16, 64), 256, 0, stream>>>(wh, vt);

    // fused flash attention, split-KV x4 -> partials, then merge -> av (bf16)
    fattn_kernel<<<dim3(64, 8, 4), 256, 0, stream>>>(
        wh, kb, rkn + (size_t)l * 1048576, vt,
        rwb + l * NH * DH, rrb + l * NH * DH, po, pm, pl);
    fmerge_kernel<<<2048, 256, 0, stream>>>(po, pm, pl, av);

    // attn_out = av @ o_w (split-K x2, bf16 partials into partPb), summed in add_ln
    gemm_bf16<128, 64><<<dim3(16, 16, 2), 256, 0, stream>>>(
        av, 0, 0, 1024, oT + (size_t)l * 1048576, 0, 0, 1024, partPb, 0, 0, 1024,
        512, 1.f, nullptr, 0, 0, 1, 1, 2, 2097152, nullptr);
    add_ln_kernel<<<2048, 256, 0, stream>>>(h, partPb, partPb + 2097152,
                                            ln1g + l * DM, ln1b + l * DM, catl);

    // FFN (ffn1 with XCD-chunked swizzle: 512 % 8 == 0)
    gemm_bf16<128, 128><<<dim3(32, 16, 1), 256, 0, stream>>>(
        catl + (size_t)2048 * 1024, 0, 0, 1024, f1T + (size_t)l * 4194304, 0, 0, 1024,
        mid, 0, 0, 4096, 1024, 1.f, fb1 + (size_t)l * DI, 0, 0, 1 | 4 | 8, 1, 1, 0, nullptr);
    gemm_bf16<128, 64><<<dim3(16, 16, 2), 256, 0, stream>>>(
        mid, 0, 0, 4096, f2T + (size_t)l * 4194304, 0, 0, 4096, partPb, 0, 0, 1024,
        2048, 1.f, fb2 + (size_t)l * DM, 0, 0, 1, 1, 2, 2097152, nullptr);
    add_ln_kernel<<<2048, 256, 0, stream>>>(h, partPb, partPb + 2097152,
                                            ln2g + l * DM, ln2b + l * DM,
                                            cat0 + (size_t)(l + 1) * 4194304);
  }

  out_kernel<<<2048, 256, 0, stream>>>(h, out);
}

// Round 19
// 947.883 us; speedup vs baseline: 1.0512x; 1.0082x over previous
//
#include <hip/hip_runtime.h>
#include <hip/hip_bf16.h>

typedef __attribute__((ext_vector_type(8))) short short8;
typedef __attribute__((ext_vector_type(4))) float f32x4;
typedef __hip_bfloat16 bf16;

#define QLEN 512
#define MLEN 512
#define KLEN 1024
#define BSZ  4
#define DM   1024
#define NH   16
#define DH   64
#define DI   4096
#define NL   4
#define KEMB 1408   // 1024 + 256 + 64 + 16 = 1360, padded to 1408 (x32)
#define LOG2E 1.4426950408889634f

// direct global->LDS DMA, 16 B per lane (wave-uniform LDS base + lane*16)
__device__ __forceinline__ void gload16(const bf16* g, const void* l) {
  __builtin_amdgcn_global_load_lds(
      (const __attribute__((address_space(1))) void*)g,
      (__attribute__((address_space(3))) void*)l, 16, 0, 0);
}

__device__ __forceinline__ bf16 bits2bf(short s) { bf16 h; *(short*)&h = s; return h; }

// ================= adaptive embedding as GEMM: gather A rows (2048 x KEMB, bf16) =================
__global__ __launch_bounds__(256) void embA_kernel(
    const int* __restrict__ ids,
    const float* __restrict__ e0, const float* __restrict__ e1,
    const float* __restrict__ e2, const float* __restrict__ e3,
    bf16* __restrict__ Aemb)
{
  const int t = blockIdx.x;          // t = q*BSZ + b
  const int q = t >> 2, b = t & 3;
  const int id = ids[b * QLEN + q];
  const float* tab; int d, off, koff;
  if (id < 20000)       { tab = e0; d = 1024; off = 0;      koff = 0; }
  else if (id < 40000)  { tab = e1; d = 256;  off = 20000;  koff = 1024; }
  else if (id < 200000) { tab = e2; d = 64;   off = 40000;  koff = 1280; }
  else                  { tab = e3; d = 16;   off = 200000; koff = 1344; }
  bf16* row = Aemb + (long)t * KEMB;
  const float* tr = tab + (long)(id - off) * d;
  for (int k = threadIdx.x; k < KEMB; k += 256) {
    const int kk = k - koff;
    float v = 0.f;
    if (kk >= 0 && kk < d) v = tr[kk];
    row[k] = __float2bfloat16(v);
  }
}

// ================= concat proj^T: projT[n][k] (1024 x KEMB, bf16), zero-padded =================
__global__ __launch_bounds__(256) void projT_kernel(
    const float* __restrict__ p0, const float* __restrict__ p1,
    const float* __restrict__ p2, const float* __restrict__ p3,
    bf16* __restrict__ out)
{
  __shared__ float t[32][33];
  const int k0 = blockIdx.x * 32, n0 = blockIdx.y * 32;
  const int nx = threadIdx.x & 31, ky = threadIdx.x >> 5;
#pragma unroll
  for (int p = 0; p < 4; ++p) {
    const int k = k0 + ky + p * 8;
    float v = 0.f;
    if (k < 1024)       v = p0[(long)k * 1024 + n0 + nx];
    else if (k < 1280)  v = p1[(long)(k - 1024) * 1024 + n0 + nx];
    else if (k < 1344)  v = p2[(long)(k - 1280) * 1024 + n0 + nx];
    else if (k < 1360)  v = p3[(long)(k - 1344) * 1024 + n0 + nx];
    t[ky + p * 8][nx] = v;
  }
  __syncthreads();
#pragma unroll
  for (int p = 0; p < 4; ++p)
    out[(long)(n0 + ky + p * 8) * KEMB + k0 + nx] = __float2bfloat16(t[nx][ky + p * 8]);
}

// ================= sum 2 fp32 partials -> cat bf16 (upper; residual stream) =================
__global__ __launch_bounds__(256) void embsum_kernel(const float* __restrict__ part,
                                                     bf16* __restrict__ cat)
{
  const long i = ((long)blockIdx.x * 256 + threadIdx.x) * 4;
  const float4 a = *(const float4*)(part + i);
  const float4 b = *(const float4*)(part + 2097152 + i);
  bf16* cr = cat + (long)2048 * 1024 + i;
  cr[0] = __float2bfloat16(a.x + b.x); cr[1] = __float2bfloat16(a.y + b.y);
  cr[2] = __float2bfloat16(a.z + b.z); cr[3] = __float2bfloat16(a.w + b.w);
}

// ================= sinusoidal pos emb -> bf16 =================
__global__ __launch_bounds__(256) void posemb_kernel(bf16* __restrict__ pe)
{
  const int j = blockIdx.x;
  const float pos = (float)(KLEN - 1 - j);
  for (int i = threadIdx.x; i < DM / 2; i += 256) {
    const float freq = expf(-9.210340371976184f * ((float)(2 * i) / (float)DM));
    const float ang = pos * freq;
    pe[(long)j * DM + i]          = __float2bfloat16(sinf(ang));
    pe[(long)j * DM + DM / 2 + i] = __float2bfloat16(cosf(ang));
  }
}

// ================= fp32 (R x C) -> bf16 transposed (C x R), z = layer =================
__global__ __launch_bounds__(256) void wtrans_kernel(const float* __restrict__ in,
                                                     bf16* __restrict__ out, int R, int C)
{
  __shared__ float t[32][33];
  in  += (long)blockIdx.z * R * C;
  out += (long)blockIdx.z * R * C;
  const int c0 = blockIdx.x * 32, r0 = blockIdx.y * 32;
  const int cx = threadIdx.x & 31, ry = threadIdx.x >> 5;
#pragma unroll
  for (int p = 0; p < 4; ++p)
    t[ry + p * 8][cx] = in[(long)(r0 + ry + p * 8) * C + c0 + cx];
  __syncthreads();
#pragma unroll
  for (int p = 0; p < 4; ++p)
    out[(long)(c0 + ry + p * 8) * R + r0 + cx] = __float2bfloat16(t[cx][ry + p * 8]);
}

// ================= all mems (NL x 2048 x 1024 fp32) -> lower halves of cats[l] =================
__global__ __launch_bounds__(256) void memsconv_kernel(const float* __restrict__ mems,
                                                       bf16* __restrict__ cat0)
{
  const long i = ((long)blockIdx.x * 256 + threadIdx.x) * 4;   // over NL*2048*1024
  const long l = i >> 21, rem = i & ((1 << 21) - 1);
  const float4 v = *(const float4*)(mems + i);
  bf16* dst = cat0 + l * 4194304 + rem;
  dst[0] = __float2bfloat16(v.x); dst[1] = __float2bfloat16(v.y);
  dst[2] = __float2bfloat16(v.z); dst[3] = __float2bfloat16(v.w);
}

// ================= bf16 MFMA GEMM:  C = scale*(A @ B^T_supplied + colbias)  =================
// flags: 1 = bf16 out, 4 = relu, 8 = XCD-chunked block swizzle (nwg % 8 == 0, z == 1),
// 16 = K-pack fusion: blocks with cols in [1024,2048) write to aux[bn][j][64]
//      (packed K for fattn) instead of C.
template<int BM, int BN>
__global__ __launch_bounds__(256) void gemm_bf16(
    const bf16* __restrict__ A, long aStrB, long aStrN, int lda,
    const bf16* __restrict__ B, long bStrB, long bStrN, int ldb,
    void* __restrict__ C, long cStrB, long cStrN, int ldc,
    int K, float scale, const float* __restrict__ bias, long biasStrB, long biasStrN,
    int flags, int zN, int zSplit, long cSplitStr, bf16* __restrict__ aux)
{
  constexpr int RA = BM / 64, RB = BN / 64, FM = BM / 32, FN = BN / 32;
  __shared__ __align__(16) bf16 As[2][BM * 32];
  __shared__ __align__(16) bf16 Bs[2][BN * 32];
  const int zc = blockIdx.z % zSplit, zt = blockIdx.z / zSplit;
  const int zn = zt % zN, zb = zt / zN;
  A += (long)zb * aStrB + (long)zn * aStrN + (long)zc * K;
  B += (long)zb * bStrB + (long)zn * bStrN + (long)zc * K;
  int bx = blockIdx.x, by = blockIdx.y;
  if (flags & 8) {
    const int nwg = gridDim.x * gridDim.y;
    const int bid = by * gridDim.x + bx;
    const int qq = nwg >> 3;                      // nwg % 8 == 0 guaranteed by caller
    const int nb = (bid & 7) * qq + (bid >> 3);   // XCD (bid%8) gets contiguous range
    bx = nb % gridDim.x; by = nb / gridDim.x;
  }
  const int tid = threadIdx.x, lane = tid & 63;
  const int w = tid >> 6, wr = w >> 1, wc = w & 1;
  const int m0 = by * BM, n0 = bx * BN;
  const int l15 = lane & 15, l4 = lane >> 4;
  const int rowS = tid >> 2;
  const int cbS  = (tid & 3) * 16;
  const int swS  = cbS ^ (((rowS >> 1) & 3) << 4);
  const int wbase = w * 1024;
  const bf16* Ast = A + (size_t)(m0 + rowS) * lda + (swS >> 1);
  const bf16* Bst = B + (size_t)(n0 + rowS) * ldb + (swS >> 1);

#define STAGE_TILE(buf, kk)                                                       \
  {                                                                               \
    _Pragma("unroll")                                                             \
    for (int r = 0; r < RA; ++r)                                                  \
      gload16(Ast + (size_t)(r * 64) * lda + (kk), (char*)As[buf] + r * 4096 + wbase); \
    _Pragma("unroll")                                                             \
    for (int r = 0; r < RB; ++r)                                                  \
      gload16(Bst + (size_t)(r * 64) * ldb + (kk), (char*)Bs[buf] + r * 4096 + wbase); \
  }

  f32x4 acc[FM][FN] = {};
  STAGE_TILE(0, 0)
  asm volatile("s_waitcnt vmcnt(0)" ::: "memory");
  __syncthreads();
  int cur = 0;
  for (int k0 = 0; k0 < K; k0 += 32) {
    if (k0 + 32 < K) {
      if (cur == 0) STAGE_TILE(1, k0 + 32)
      else          STAGE_TILE(0, k0 + 32)
    }
    short8 af[FM], bfr[FN];
#pragma unroll
    for (int f = 0; f < FM; ++f) {
      const int row = wr * (BM / 2) + f * 16 + l15;
      af[f] = *(const short8*)((char*)As[cur] + row * 64 + ((16 * l4) ^ (((row >> 1) & 3) << 4)));
    }
#pragma unroll
    for (int f = 0; f < FN; ++f) {
      const int row = wc * (BN / 2) + f * 16 + l15;
      bfr[f] = *(const short8*)((char*)Bs[cur] + row * 64 + ((16 * l4) ^ (((row >> 1) & 3) << 4)));
    }
#pragma unroll
    for (int fm = 0; fm < FM; ++fm)
#pragma unroll
      for (int fn = 0; fn < FN; ++fn)
        acc[fm][fn] = __builtin_amdgcn_mfma_f32_16x16x32_bf16(af[fm], bfr[fn], acc[fm][fn], 0, 0, 0);
    asm volatile("s_waitcnt vmcnt(0)" ::: "memory");
    __syncthreads();
    cur ^= 1;
  }
#undef STAGE_TILE
  const int outbf = flags & 1, relu = flags & 4;
  const bool kpk = (flags & 16) && (n0 >= 1024) && (n0 < 2048);
#pragma unroll
  for (int fm = 0; fm < FM; ++fm) {
#pragma unroll
    for (int fn = 0; fn < FN; ++fn) {
      const int col = n0 + wc * (BN / 2) + fn * 16 + l15;
      const int rw0 = m0 + wr * (BM / 2) + fm * 16 + l4 * 4;
      const float bv = (bias && zc == 0) ? bias[(size_t)zb * biasStrB + (size_t)zn * biasStrN + col] : 0.f;
#pragma unroll
      for (int r = 0; r < 4; ++r) {
        float v = (acc[fm][fn][r] + bv) * scale;
        if (relu) v = fmaxf(v, 0.f);
        const int row = rw0 + r;
        if (kpk) {
          // packed K: aux[(row&3)*16 + (col-1024)/64][row>>2][col&63]
          const int bnn = ((row & 3) << 4) + ((col - 1024) >> 6);
          aux[(size_t)bnn * 65536 + (size_t)(row >> 2) * 64 + (col & 63)] = __float2bfloat16(v);
        } else {
          const size_t cOff = (size_t)zb * cStrB + (size_t)zn * cStrN + (size_t)zc * cSplitStr;
          if (outbf) {
            ((bf16*)C + cOff)[(size_t)row * ldc + col] = __float2bfloat16(v);
          } else {
            ((float*)C + cOff)[(size_t)row * ldc + col] = v;
          }
        }
      }
    }
  }
}

// ================= V transpose (j-tile blocked); K packed by qkv GEMM epilogue =================
__global__ __launch_bounds__(256) void vt_kernel(const bf16* __restrict__ wh,
                                                 bf16* __restrict__ vt)
{
  const int bn = blockIdx.y, b = bn >> 4, n = bn & 15;
  const int j0 = blockIdx.x * 64;
  __shared__ bf16 t[64][72];
  const bf16* src = wh + (size_t)b * 3072 + 2048 + n * 64;
  const int tid = threadIdx.x;
#pragma unroll
  for (int r = 0; r < 16; ++r) {
    const int jl = r * 4 + (tid >> 6), d = tid & 63;
    t[jl][d] = src[(size_t)(j0 + jl) * 12288 + d];
  }
  __syncthreads();
  bf16* dst = vt + (size_t)bn * 65536 + (size_t)j0 * 64;   // block [d][64]
#pragma unroll
  for (int r = 0; r < 16; ++r) {
    const int d = r * 4 + (tid >> 6), j = tid & 63;
    dst[(size_t)d * 64 + j] = t[j][d];
  }
}

// ================= rk repack: rkn[l][n][p][64] =================
__global__ __launch_bounds__(256) void rkpack_kernel(const bf16* __restrict__ rkb,
                                                     bf16* __restrict__ rkn)
{
  const int ln = blockIdx.y, l = ln >> 4, n = ln & 15;
  const int p0 = blockIdx.x * 64;
  const int d = threadIdx.x & 63, pr = threadIdx.x >> 6;
  const bf16* src = rkb + (size_t)l * 1048576 + n * 64 + d;
  bf16* dst = rkn + (size_t)ln * 65536 + d;
#pragma unroll
  for (int r = 0; r < 16; ++r) {
    const int p = p0 + r * 4 + pr;
    dst[(size_t)p * 64] = src[(size_t)p * 1024];
  }
}

// ================= fused flash attention, split-KV x4, LDS-staged K/V/rk =================
// Base-2 softmax: log2(e) folded into Qa/Qb scale -> exp2 everywhere (pm in base-2 domain).
__global__ __launch_bounds__(256) void fattn_kernel(
    const bf16* __restrict__ wh,     // 4096 x 3072 (row = 4*token + b) — Q only
    const bf16* __restrict__ kb,     // [bn][1024 j][64 d]
    const bf16* __restrict__ rkn_l,  // [16 n][1024 p][64 d] (this layer, 16 KB guard after)
    const bf16* __restrict__ vt,     // [bn][16 jt][64 d][64 jl]
    const float* __restrict__ rwb,   // 16 x 64 (this layer)
    const float* __restrict__ rrb,   // 16 x 64
    float* __restrict__ po, float* __restrict__ pm, float* __restrict__ pl)
{
  const int bn = blockIdx.x, b = bn >> 4, n = bn & 15;
  const int q0 = blockIdx.y * 64;
  const int ck = blockIdx.z;
  const int tid = threadIdx.x, w = tid >> 6, lane = tid & 63;
  const int l15 = lane & 15, l4 = lane >> 4;
  __shared__ __align__(16) bf16 Ks[64 * 64];    // 8 KB  [row j][128 B]
  __shared__ __align__(16) bf16 Vs[64 * 64];    // 8 KB  [row d][128 B]
  __shared__ __align__(16) bf16 Rs[128 * 64];   // 16 KB [row p-pstart][128 B]
  __shared__ bf16 Tl[4][16][84];                // wave-private shifted-BD band strips
  __shared__ bf16 Pl[4][16][72];                // wave-private P transpose staging

  // ---- load Q fragments; fold biases AND 0.125*log2(e) scale (base-2 softmax domain) ----
  short8 qa[2], qb[2];
  {
    const bf16* qp = wh + (size_t)(2048 + b) * 3072 + (size_t)(q0 + 16 * w + l15) * 12288 + n * 64;
    const float sc2 = 0.125f * LOG2E;
#pragma unroll
    for (int kk = 0; kk < 2; ++kk) {
      const short8 qv = *(const short8*)(qp + kk * 32 + 8 * l4);
      const float* wv = rwb + n * 64 + kk * 32 + 8 * l4;
      const float* rv = rrb + n * 64 + kk * 32 + 8 * l4;
      short8 a, c;
#pragma unroll
      for (int e = 0; e < 8; ++e) {
        const float q = __bfloat162float(bits2bf(qv[e]));
        const bf16 ab = __float2bfloat16((q + wv[e]) * sc2);
        const bf16 cb = __float2bfloat16((q + rv[e]) * sc2);
        a[e] = *(const short*)&ab;  c[e] = *(const short*)&cb;
      }
      qa[kk] = a; qb[kk] = c;
    }
  }

  const bf16* kbase = kb + (size_t)bn * 65536;                  // + j*64
  const bf16* rbase = rkn_l + (size_t)n * 65536;                // + p*64
  const bf16* vbase = vt + (size_t)bn * 65536;                  // + j0*64 + d*64 + jl
  const int ntiles = 9 + (q0 >> 6);

  // staging geometry: thread tid covers linear LDS bytes [tid*16, tid*16+16) per 4 KB slab
  const int stRow0 = tid >> 3;                  // row within 4 KB slab (32 rows/slab)
  const int stColb = (tid & 7) * 16;
  const int wbase = w * 1024;                   // wave-uniform LDS base within slab
  const int srd = (l15 & 7) << 4;               // read-side swizzle (== row&7 <<4 for all reads)

  f32x4 accO[4] = {};
  float mrow[4] = { -1e30f, -1e30f, -1e30f, -1e30f };
  float lrow[4] = { 0.f, 0.f, 0.f, 0.f };

  for (int t = ck; t < ntiles; t += 4) {
    const int j0 = t * 64;
    const int pstart = j0 - q0 + 448;           // Rs row 0 == global p = pstart (>= 0)
    // ---- stage K/V tiles + rk band into LDS (once per WG) ----
    __syncthreads();                            // previous tile fully consumed
    {
#pragma unroll
      for (int r = 0; r < 2; ++r) {             // K: 2 slabs of 4 KB
        const int row = r * 32 + stRow0;
        gload16(kbase + (size_t)(j0 + row) * 64 + ((stColb ^ ((row & 7) << 4)) >> 1),
                (char*)Ks + r * 4096 + wbase);
      }
#pragma unroll
      for (int r = 0; r < 2; ++r) {             // V: 2 slabs
        const int row = r * 32 + stRow0;
        gload16(vbase + (size_t)j0 * 64 + (size_t)row * 64 + ((stColb ^ ((row & 7) << 4)) >> 1),
                (char*)Vs + r * 4096 + wbase);
      }
#pragma unroll
      for (int r = 0; r < 4; ++r) {             // rk band: 4 slabs (128 rows)
        const int row = r * 32 + stRow0;
        gload16(rbase + (size_t)(pstart + row) * 64 + ((stColb ^ ((row & 7) << 4)) >> 1),
                (char*)Rs + r * 4096 + wbase);
      }
    }
    asm volatile("s_waitcnt vmcnt(0)" ::: "memory");
    __syncthreads();

    // ---- AC: S[fn] = Qa . K^T (from LDS, swizzled) ----
    f32x4 S[4] = {};
#pragma unroll
    for (int fn = 0; fn < 4; ++fn)
#pragma unroll
      for (int kk = 0; kk < 2; ++kk) {
        const short8 kf = *(const short8*)((char*)Ks + (16 * fn + l15) * 128 + ((kk * 64 + 16 * l4) ^ srd));
        S[fn] = __builtin_amdgcn_mfma_f32_16x16x32_bf16(qa[kk], kf, S[fn], 0, 0, 0);
      }
    // ---- BD band: rows (3-w)*16 + 16*ftl + l15 of Rs ----
    {
      f32x4 T[5] = {};
#pragma unroll
      for (int ftl = 0; ftl < 5; ++ftl) {
        const int rrow = (3 - w) * 16 + 16 * ftl + l15;
#pragma unroll
        for (int kk = 0; kk < 2; ++kk) {
          const short8 rf = *(const short8*)((char*)Rs + rrow * 128 + ((kk * 64 + 16 * l4) ^ srd));
          T[ftl] = __builtin_amdgcn_mfma_f32_16x16x32_bf16(qb[kk], rf, T[ftl], 0, 0, 0);
        }
      }
#pragma unroll
      for (int ftl = 0; ftl < 5; ++ftl)
#pragma unroll
        for (int r = 0; r < 4; ++r)
          Tl[w][4 * l4 + r][16 * ftl + l15] = __float2bfloat16(T[ftl][r]);
    }
    // ---- shift-add + mask ----
    const bool fullvalid = (j0 + 63) <= (512 + q0);
    float sv[4][4];
#pragma unroll
    for (int fn = 0; fn < 4; ++fn)
#pragma unroll
      for (int r = 0; r < 4; ++r) {
        const int il = 4 * l4 + r;
        const float tshift = __bfloat162float(Tl[w][il][16 * fn + l15 + 15 - il]);
        const float s = S[fn][r] + tshift;
        const bool valid = fullvalid || (j0 + 16 * fn + l15 - 512 <= q0 + 16 * w + il);
        sv[fn][r] = valid ? s : -1e30f;
      }
    // ---- online softmax, base-2 (row = 16-lane group) ----
#pragma unroll
    for (int r = 0; r < 4; ++r) {
      float m4 = fmaxf(fmaxf(sv[0][r], sv[1][r]), fmaxf(sv[2][r], sv[3][r]));
      m4 = fmaxf(m4, __shfl_xor(m4, 1));
      m4 = fmaxf(m4, __shfl_xor(m4, 2));
      m4 = fmaxf(m4, __shfl_xor(m4, 4));
      m4 = fmaxf(m4, __shfl_xor(m4, 8));
      const float mn = fmaxf(mrow[r], m4);
      const float alpha = exp2f(mrow[r] - mn);
      mrow[r] = mn;
      float ps = 0.f;
#pragma unroll
      for (int fn = 0; fn < 4; ++fn) {
        sv[fn][r] = exp2f(sv[fn][r] - mn);
        ps += sv[fn][r];
      }
      ps += __shfl_xor(ps, 1);
      ps += __shfl_xor(ps, 2);
      ps += __shfl_xor(ps, 4);
      ps += __shfl_xor(ps, 8);
      lrow[r] = lrow[r] * alpha + ps;
#pragma unroll
      for (int fd = 0; fd < 4; ++fd) accO[fd][r] *= alpha;
    }
    // ---- P -> LDS (transpose to A-frag) and PV (V from LDS, swizzled) ----
#pragma unroll
    for (int fn = 0; fn < 4; ++fn)
#pragma unroll
      for (int r = 0; r < 4; ++r)
        Pl[w][4 * l4 + r][16 * fn + l15] = __float2bfloat16(sv[fn][r]);
    short8 pa[2];
    pa[0] = *(const short8*)&Pl[w][l15][8 * l4];
    pa[1] = *(const short8*)&Pl[w][l15][32 + 8 * l4];
#pragma unroll
    for (int fd = 0; fd < 4; ++fd)
#pragma unroll
      for (int kk = 0; kk < 2; ++kk) {
        const short8 vf = *(const short8*)((char*)Vs + (16 * fd + l15) * 128 + ((kk * 64 + 16 * l4) ^ srd));
        accO[fd] = __builtin_amdgcn_mfma_f32_16x16x32_bf16(pa[kk], vf, accO[fd], 0, 0, 0);
      }
  }
  // ---- store unnormalized partials (pm in base-2 domain) ----
  const int cb = ck * 64 + bn;
  float* pob = po + (size_t)cb * 512 * 64;
#pragma unroll
  for (int fd = 0; fd < 4; ++fd)
#pragma unroll
    for (int r = 0; r < 4; ++r) {
      const int row = q0 + 16 * w + 4 * l4 + r;
      pob[(size_t)row * 64 + 16 * fd + l15] = accO[fd][r];
    }
  if (l15 == 0) {
#pragma unroll
    for (int r = 0; r < 4; ++r) {
      const int row = q0 + 16 * w + 4 * l4 + r;
      pm[(size_t)cb * 512 + row] = mrow[r];
      pl[(size_t)cb * 512 + row] = lrow[r];
    }
  }
}

// ================= merge 4 split-KV partials -> av bf16 (base-2 weights) =================
__global__ __launch_bounds__(256) void fmerge_kernel(
    const float* __restrict__ po, const float* __restrict__ pm,
    const float* __restrict__ pl, bf16* __restrict__ av)
{
  const long i = ((long)blockIdx.x * 256 + threadIdx.x) * 4;   // over 64*512*64
  const long bnq = i >> 6;                                     // bn*512 + q
  const int d4 = (int)(i & 63);
  const int bn = (int)(bnq >> 9), q = (int)(bnq & 511);
  const int b = bn >> 4, n = bn & 15;
  float mv[4], lv[4];
#pragma unroll
  for (int c = 0; c < 4; ++c) { mv[c] = pm[c * 32768 + bnq]; lv[c] = pl[c * 32768 + bnq]; }
  const float m = fmaxf(fmaxf(mv[0], mv[1]), fmaxf(mv[2], mv[3]));
  float wv[4], den = 0.f;
#pragma unroll
  for (int c = 0; c < 4; ++c) { wv[c] = exp2f(mv[c] - m); den += wv[c] * lv[c]; }
  const float inv = 1.f / den;
  float4 o = { 0.f, 0.f, 0.f, 0.f };
#pragma unroll
  for (int c = 0; c < 4; ++c) {
    const float4 oc = *(const float4*)(po + (size_t)c * 2097152 + bnq * 64 + d4);
    o.x += wv[c] * oc.x; o.y += wv[c] * oc.y; o.z += wv[c] * oc.z; o.w += wv[c] * oc.w;
  }
  bf16* dst = av + (size_t)(q * 4 + b) * 1024 + n * 64 + d4;
  dst[0] = __float2bfloat16(o.x * inv);
  dst[1] = __float2bfloat16(o.y * inv);
  dst[2] = __float2bfloat16(o.z * inv);
  dst[3] = __float2bfloat16(o.w * inv);
}

// ================= cat_out = bf16(LN(hin + x0 + x1)); residual stream lives in bf16 =================
__global__ __launch_bounds__(256) void add_ln_kernel(
    const bf16* __restrict__ hin,
    const bf16* __restrict__ x0, const bf16* __restrict__ x1,
    const float* __restrict__ g, const float* __restrict__ bb, bf16* __restrict__ cat_out)
{
  const long o = (long)blockIdx.x * DM;
  const int tid = threadIdx.x;
  __shared__ float red[256];
  float v0 = __bfloat162float(hin[o + tid])       + __bfloat162float(x0[o + tid])       + __bfloat162float(x1[o + tid]);
  float v1 = __bfloat162float(hin[o + tid + 256]) + __bfloat162float(x0[o + tid + 256]) + __bfloat162float(x1[o + tid + 256]);
  float v2 = __bfloat162float(hin[o + tid + 512]) + __bfloat162float(x0[o + tid + 512]) + __bfloat162float(x1[o + tid + 512]);
  float v3 = __bfloat162float(hin[o + tid + 768]) + __bfloat162float(x0[o + tid + 768]) + __bfloat162float(x1[o + tid + 768]);
  red[tid] = v0 + v1 + v2 + v3; __syncthreads();
  for (int off = 128; off; off >>= 1) { if (tid < off) red[tid] += red[tid + off]; __syncthreads(); }
  const float mean = red[0] * (1.f / DM); __syncthreads();
  const float d0 = v0 - mean, d1 = v1 - mean, d2 = v2 - mean, d3 = v3 - mean;
  red[tid] = d0 * d0 + d1 * d1 + d2 * d2 + d3 * d3; __syncthreads();
  for (int off = 128; off; off >>= 1) { if (tid < off) red[tid] += red[tid + off]; __syncthreads(); }
  const float inv = rsqrtf(red[0] * (1.f / DM) + 1e-5f);
  cat_out[o + tid]       = __float2bfloat16(d0 * inv * g[tid]       + bb[tid]);
  cat_out[o + tid + 256] = __float2bfloat16(d1 * inv * g[tid + 256] + bb[tid + 256]);
  cat_out[o + tid + 512] = __float2bfloat16(d2 * inv * g[tid + 512] + bb[tid + 512]);
  cat_out[o + tid + 768] = __float2bfloat16(d3 * inv * g[tid + 768] + bb[tid + 768]);
}

// ================= (q,b,d) bf16 -> (b,q,d) fp32 =================
__global__ __launch_bounds__(256) void out_kernel(const bf16* __restrict__ hb, float* __restrict__ out)
{
  const int t = blockIdx.x, q = t >> 2, b = t & 3;
  const bf16* hr = hb + (long)t * DM;
  float* orow = out + ((long)b * QLEN + q) * DM;
  for (int s = 0; s < 4; ++s)
    orow[threadIdx.x + 256 * s] = __bfloat162float(hr[threadIdx.x + 256 * s]);
}

extern "C" void kernel_launch(void* const* d_in, const int* in_sizes, int n_in,
                              void* d_out, int out_size, void* d_ws, size_t ws_size,
                              hipStream_t stream)
{
  const int*   ids  = (const int*)d_in[0];
  const float* mems = (const float*)d_in[1];
  const float* e0 = (const float*)d_in[2]; const float* p0 = (const float*)d_in[3];
  const float* e1 = (const float*)d_in[4]; const float* p1 = (const float*)d_in[5];
  const float* e2 = (const float*)d_in[6]; const float* p2 = (const float*)d_in[7];
  const float* e3 = (const float*)d_in[8]; const float* p3 = (const float*)d_in[9];
  const float* qkvw = (const float*)d_in[10];
  const float* rnet = (const float*)d_in[11];
  const float* ow   = (const float*)d_in[12];
  const float* rwb  = (const float*)d_in[13];
  const float* rrb  = (const float*)d_in[14];
  const float* ln1g = (const float*)d_in[15];
  const float* ln1b = (const float*)d_in[16];
  const float* fw1  = (const float*)d_in[17];
  const float* fb1  = (const float*)d_in[18];
  const float* fw2  = (const float*)d_in[19];
  const float* fb2  = (const float*)d_in[20];
  const float* ln2g = (const float*)d_in[21];
  const float* ln2b = (const float*)d_in[22];
  float* out = (float*)d_out;

  // -------- workspace layout --------
  char* p = (char*)d_ws;
  p += (size_t)2048 * 1024 * 4;                                           // 8 MB (reserved; was fp32 h)
  bf16*  cat0 = (bf16*)p;             p += (size_t)5 * 4096 * 1024 * 2;   // 40 MB (cats[0..4]; upper = residual)
  bf16*  pe   = (bf16*)p;             p += (size_t)1024 * 1024 * 2;       // 2 MB
  bf16*  rkb  = (bf16*)p;             p += (size_t)4 * 1024 * 1024 * 2;   // 8 MB (all layers, [p][1024])
  bf16*  rkn  = (bf16*)p;             p += (size_t)(4 * 16 * 1024 * 64 + 8192) * 2; // 8 MB + 16 KB guard
  bf16*  wh   = (bf16*)p;             p += (size_t)4096 * 3072 * 2;       // 24 MB
  bf16*  vt   = (bf16*)p;             p += (size_t)64 * 64 * 1024 * 2;    // 8 MB (j-blocked V^T)
  bf16*  kb   = (bf16*)p;             p += (size_t)64 * 1024 * 64 * 2;    // 8 MB (packed K)
  bf16*  qkvT = (bf16*)p;             p += (size_t)4 * 3072 * 1024 * 2;   // 24 MB
  bf16*  rnT  = (bf16*)p;             p += (size_t)4 * 1024 * 1024 * 2;   // 8 MB
  bf16*  oT   = (bf16*)p;             p += (size_t)4 * 1024 * 1024 * 2;   // 8 MB
  bf16*  f1T  = (bf16*)p;             p += (size_t)4 * 4096 * 1024 * 2;   // 32 MB
  bf16*  f2T  = (bf16*)p;             p += (size_t)4 * 4096 * 1024 * 2;   // 32 MB
  // 64 MB region A: mid (FFN) / partE (embed, 16 MB fp32)
  bf16*  mid  = (bf16*)p;
  float* partE= (float*)p;
  p += (size_t)4 * 16 * 512 * 1024 * 2;                                   // 64 MB
  // 64 MB region B: Aemb+projT (embed) / attn partials po/pm/pl / partPb (bf16 split-K partials)
  bf16*  Aemb = (bf16*)p;
  bf16*  projT= (bf16*)(p + (size_t)2048 * KEMB * 2);
  bf16*  partPb = (bf16*)p;                                   // 2 x 2048x1024 bf16 = 8 MB
  float* po   = (float*)p;                                    // 4*64*512*64 fp32 = 32 MB
  float* pm   = (float*)(p + (size_t)32 * 1024 * 1024);       // 512 KB
  float* pl   = (float*)(p + (size_t)33 * 1024 * 1024);       // 512 KB
  p += (size_t)4 * 16 * 512 * 1024 * 2;                                   // 64 MB
  bf16*  av   = (bf16*)p;             p += (size_t)2048 * 1024 * 2;       // 4 MB

  // NOTE: partPb (proj/ffn2 partials) and po/pm/pl (attn partials) share region B
  // but are used in disjoint phases. The residual stream lives in the bf16 upper
  // halves of cats[l]: attn add_ln updates catl-upper in place; FFN add_ln writes
  // cat(l+1)-upper; out_kernel reads cat4-upper.

  // -------- upfront: embedding, pos-emb, mems conversion, ALL weight transposes --------
  embA_kernel<<<2048, 256, 0, stream>>>(ids, e0, e1, e2, e3, Aemb);
  projT_kernel<<<dim3(KEMB / 32, 32), 256, 0, stream>>>(p0, p1, p2, p3, projT);
  gemm_bf16<128, 64><<<dim3(16, 16, 2), 256, 0, stream>>>(
      Aemb, 0, 0, KEMB, projT, 0, 0, KEMB, partE, 0, 0, 1024,
      KEMB / 2, 32.f, nullptr, 0, 0, 0, 1, 2, 2097152, nullptr);
  embsum_kernel<<<2048, 256, 0, stream>>>(partE, cat0);
  posemb_kernel<<<1024, 256, 0, stream>>>(pe);
  memsconv_kernel<<<8192, 256, 0, stream>>>(mems, cat0);

  wtrans_kernel<<<dim3(96, 32, 4), 256, 0, stream>>>(qkvw, qkvT, DM, 3072);
  wtrans_kernel<<<dim3(32, 32, 4), 256, 0, stream>>>(rnet, rnT, DM, DM);
  wtrans_kernel<<<dim3(32, 32, 4), 256, 0, stream>>>(ow, oT, DM, DM);
  wtrans_kernel<<<dim3(128, 32, 4), 256, 0, stream>>>(fw1, f1T, DM, DI);
  wtrans_kernel<<<dim3(32, 128, 4), 256, 0, stream>>>(fw2, f2T, DI, DM);

  // rk = pos_emb @ r_net_w for ALL layers (z = layer), then repack to [l][n][p][64]
  gemm_bf16<128, 128><<<dim3(8, 8, 4), 256, 0, stream>>>(
      pe, 0, 0, 1024, rnT, 1048576, 0, 1024, rkb, 1048576, 0, 1024,
      1024, 1.f, nullptr, 0, 0, 1, 1, 1, 0, nullptr);
  rkpack_kernel<<<dim3(16, 64), 256, 0, stream>>>(rkb, rkn);

  for (int l = 0; l < NL; ++l) {
    bf16* catl = cat0 + (size_t)l * 4194304;
    bf16* resl = catl + (size_t)2048 * 1024;     // residual stream (cat upper)
    // w_heads = cat @ qkv_w -> wh (Q/V cols) + kb (K cols packed, flag 16); XCD swizzle
    gemm_bf16<128, 128><<<dim3(24, 32, 1), 256, 0, stream>>>(
        catl, 0, 0, 1024, qkvT + (size_t)l * 3145728, 0, 0, 1024, wh, 0, 0, 3072,
        1024, 1.f, nullptr, 0, 0, 1 | 8 | 16, 1, 1, 0, kb);

    vt_kernel<<<dim3(16, 64), 256, 0, stream>>>(wh, vt);

    // fused flash attention, split-KV x4 -> partials, then merge -> av (bf16)
    fattn_kernel<<<dim3(64, 8, 4), 256, 0, stream>>>(
        wh, kb, rkn + (size_t)l * 1048576, vt,
        rwb + l * NH * DH, rrb + l * NH * DH, po, pm, pl);
    fmerge_kernel<<<2048, 256, 0, stream>>>(po, pm, pl, av);

    // attn_out = av @ o_w (split-K x2, bf16 partials into partPb), summed in add_ln
    gemm_bf16<128, 64><<<dim3(16, 16, 2), 256, 0, stream>>>(
        av, 0, 0, 1024, oT + (size_t)l * 1048576, 0, 0, 1024, partPb, 0, 0, 1024,
        512, 1.f, nullptr, 0, 0, 1, 1, 2, 2097152, nullptr);
    add_ln_kernel<<<2048, 256, 0, stream>>>(resl, partPb, partPb + 2097152,
                                            ln1g + l * DM, ln1b + l * DM, resl);

    // FFN (ffn1 with XCD-chunked swizzle: 512 % 8 == 0)
    gemm_bf16<128, 128><<<dim3(32, 16, 1), 256, 0, stream>>>(
        resl, 0, 0, 1024, f1T + (size_t)l * 4194304, 0, 0, 1024,
        mid, 0, 0, 4096, 1024, 1.f, fb1 + (size_t)l * DI, 0, 0, 1 | 4 | 8, 1, 1, 0, nullptr);
    gemm_bf16<128, 64><<<dim3(16, 16, 2), 256, 0, stream>>>(
        mid, 0, 0, 4096, f2T + (size_t)l * 4194304, 0, 0, 4096, partPb, 0, 0, 1024,
        2048, 1.f, fb2 + (size_t)l * DM, 0, 0, 1, 1, 2, 2097152, nullptr);
    add_ln_kernel<<<2048, 256, 0, stream>>>(resl, partPb, partPb + 2097152,
                                            ln2g + l * DM, ln2b + l * DM,
                                            cat0 + (size_t)(l + 1) * 4194304 + (size_t)2048 * 1024);
  }

  out_kernel<<<2048, 256, 0, stream>>>(cat0 + (size_t)4 * 4194304 + (size_t)2048 * 1024, out);
}

// Round 20
// 940.245 us; speedup vs baseline: 1.0598x; 1.0081x over previous
//
#include <hip/hip_runtime.h>
#include <hip/hip_bf16.h>

typedef __attribute__((ext_vector_type(8))) short short8;
typedef __attribute__((ext_vector_type(4))) float f32x4;
typedef __hip_bfloat16 bf16;

#define QLEN 512
#define MLEN 512
#define KLEN 1024
#define BSZ  4
#define DM   1024
#define NH   16
#define DH   64
#define DI   4096
#define NL   4
#define KEMB 1408   // 1024 + 256 + 64 + 16 = 1360, padded to 1408 (x32)
#define LOG2E 1.4426950408889634f

// direct global->LDS DMA, 16 B per lane (wave-uniform LDS base + lane*16)
__device__ __forceinline__ void gload16(const bf16* g, const void* l) {
  __builtin_amdgcn_global_load_lds(
      (const __attribute__((address_space(1))) void*)g,
      (__attribute__((address_space(3))) void*)l, 16, 0, 0);
}

__device__ __forceinline__ bf16 bits2bf(short s) { bf16 h; *(short*)&h = s; return h; }

// ================= adaptive embedding as GEMM: gather A rows (2048 x KEMB, bf16) =================
__global__ __launch_bounds__(256) void embA_kernel(
    const int* __restrict__ ids,
    const float* __restrict__ e0, const float* __restrict__ e1,
    const float* __restrict__ e2, const float* __restrict__ e3,
    bf16* __restrict__ Aemb)
{
  const int t = blockIdx.x;          // t = q*BSZ + b
  const int q = t >> 2, b = t & 3;
  const int id = ids[b * QLEN + q];
  const float* tab; int d, off, koff;
  if (id < 20000)       { tab = e0; d = 1024; off = 0;      koff = 0; }
  else if (id < 40000)  { tab = e1; d = 256;  off = 20000;  koff = 1024; }
  else if (id < 200000) { tab = e2; d = 64;   off = 40000;  koff = 1280; }
  else                  { tab = e3; d = 16;   off = 200000; koff = 1344; }
  bf16* row = Aemb + (long)t * KEMB;
  const float* tr = tab + (long)(id - off) * d;
  for (int k = threadIdx.x; k < KEMB; k += 256) {
    const int kk = k - koff;
    float v = 0.f;
    if (kk >= 0 && kk < d) v = tr[kk];
    row[k] = __float2bfloat16(v);
  }
}

// ================= concat proj^T: projT[n][k] (1024 x KEMB, bf16), zero-padded =================
__global__ __launch_bounds__(256) void projT_kernel(
    const float* __restrict__ p0, const float* __restrict__ p1,
    const float* __restrict__ p2, const float* __restrict__ p3,
    bf16* __restrict__ out)
{
  __shared__ float t[32][33];
  const int k0 = blockIdx.x * 32, n0 = blockIdx.y * 32;
  const int nx = threadIdx.x & 31, ky = threadIdx.x >> 5;
#pragma unroll
  for (int p = 0; p < 4; ++p) {
    const int k = k0 + ky + p * 8;
    float v = 0.f;
    if (k < 1024)       v = p0[(long)k * 1024 + n0 + nx];
    else if (k < 1280)  v = p1[(long)(k - 1024) * 1024 + n0 + nx];
    else if (k < 1344)  v = p2[(long)(k - 1280) * 1024 + n0 + nx];
    else if (k < 1360)  v = p3[(long)(k - 1344) * 1024 + n0 + nx];
    t[ky + p * 8][nx] = v;
  }
  __syncthreads();
#pragma unroll
  for (int p = 0; p < 4; ++p)
    out[(long)(n0 + ky + p * 8) * KEMB + k0 + nx] = __float2bfloat16(t[nx][ky + p * 8]);
}

// ================= sum 2 fp32 partials -> cat bf16 (upper; residual stream) =================
__global__ __launch_bounds__(256) void embsum_kernel(const float* __restrict__ part,
                                                     bf16* __restrict__ cat)
{
  const long i = ((long)blockIdx.x * 256 + threadIdx.x) * 4;
  const float4 a = *(const float4*)(part + i);
  const float4 b = *(const float4*)(part + 2097152 + i);
  bf16* cr = cat + (long)2048 * 1024 + i;
  cr[0] = __float2bfloat16(a.x + b.x); cr[1] = __float2bfloat16(a.y + b.y);
  cr[2] = __float2bfloat16(a.z + b.z); cr[3] = __float2bfloat16(a.w + b.w);
}

// ================= sinusoidal pos emb -> bf16 =================
__global__ __launch_bounds__(256) void posemb_kernel(bf16* __restrict__ pe)
{
  const int j = blockIdx.x;
  const float pos = (float)(KLEN - 1 - j);
  for (int i = threadIdx.x; i < DM / 2; i += 256) {
    const float freq = expf(-9.210340371976184f * ((float)(2 * i) / (float)DM));
    const float ang = pos * freq;
    pe[(long)j * DM + i]          = __float2bfloat16(sinf(ang));
    pe[(long)j * DM + DM / 2 + i] = __float2bfloat16(cosf(ang));
  }
}

// ================= fp32 (R x C) -> bf16 transposed (C x R), z = layer =================
__global__ __launch_bounds__(256) void wtrans_kernel(const float* __restrict__ in,
                                                     bf16* __restrict__ out, int R, int C)
{
  __shared__ float t[32][33];
  in  += (long)blockIdx.z * R * C;
  out += (long)blockIdx.z * R * C;
  const int c0 = blockIdx.x * 32, r0 = blockIdx.y * 32;
  const int cx = threadIdx.x & 31, ry = threadIdx.x >> 5;
#pragma unroll
  for (int p = 0; p < 4; ++p)
    t[ry + p * 8][cx] = in[(long)(r0 + ry + p * 8) * C + c0 + cx];
  __syncthreads();
#pragma unroll
  for (int p = 0; p < 4; ++p)
    out[(long)(c0 + ry + p * 8) * R + r0 + cx] = __float2bfloat16(t[cx][ry + p * 8]);
}

// ================= all mems (NL x 2048 x 1024 fp32) -> lower halves of cats[l] =================
__global__ __launch_bounds__(256) void memsconv_kernel(const float* __restrict__ mems,
                                                       bf16* __restrict__ cat0)
{
  const long i = ((long)blockIdx.x * 256 + threadIdx.x) * 4;   // over NL*2048*1024
  const long l = i >> 21, rem = i & ((1 << 21) - 1);
  const float4 v = *(const float4*)(mems + i);
  bf16* dst = cat0 + l * 4194304 + rem;
  dst[0] = __float2bfloat16(v.x); dst[1] = __float2bfloat16(v.y);
  dst[2] = __float2bfloat16(v.z); dst[3] = __float2bfloat16(v.w);
}

// ================= bf16 MFMA GEMM:  C = scale*(A @ B^T_supplied + colbias)  =================
// flags: 1 = bf16 out, 4 = relu, 8 = XCD-chunked block swizzle (nwg % 8 == 0, z == 1),
// 16 = K-pack fusion: blocks with cols in [1024,2048) write to aux[bn][j][64]
//      (packed K for fattn) instead of C.
template<int BM, int BN>
__global__ __launch_bounds__(256) void gemm_bf16(
    const bf16* __restrict__ A, long aStrB, long aStrN, int lda,
    const bf16* __restrict__ B, long bStrB, long bStrN, int ldb,
    void* __restrict__ C, long cStrB, long cStrN, int ldc,
    int K, float scale, const float* __restrict__ bias, long biasStrB, long biasStrN,
    int flags, int zN, int zSplit, long cSplitStr, bf16* __restrict__ aux)
{
  constexpr int RA = BM / 64, RB = BN / 64, FM = BM / 32, FN = BN / 32;
  __shared__ __align__(16) bf16 As[2][BM * 32];
  __shared__ __align__(16) bf16 Bs[2][BN * 32];
  const int zc = blockIdx.z % zSplit, zt = blockIdx.z / zSplit;
  const int zn = zt % zN, zb = zt / zN;
  A += (long)zb * aStrB + (long)zn * aStrN + (long)zc * K;
  B += (long)zb * bStrB + (long)zn * bStrN + (long)zc * K;
  int bx = blockIdx.x, by = blockIdx.y;
  if (flags & 8) {
    const int nwg = gridDim.x * gridDim.y;
    const int bid = by * gridDim.x + bx;
    const int qq = nwg >> 3;                      // nwg % 8 == 0 guaranteed by caller
    const int nb = (bid & 7) * qq + (bid >> 3);   // XCD (bid%8) gets contiguous range
    bx = nb % gridDim.x; by = nb / gridDim.x;
  }
  const int tid = threadIdx.x, lane = tid & 63;
  const int w = tid >> 6, wr = w >> 1, wc = w & 1;
  const int m0 = by * BM, n0 = bx * BN;
  const int l15 = lane & 15, l4 = lane >> 4;
  const int rowS = tid >> 2;
  const int cbS  = (tid & 3) * 16;
  const int swS  = cbS ^ (((rowS >> 1) & 3) << 4);
  const int wbase = w * 1024;
  const bf16* Ast = A + (size_t)(m0 + rowS) * lda + (swS >> 1);
  const bf16* Bst = B + (size_t)(n0 + rowS) * ldb + (swS >> 1);

#define STAGE_TILE(buf, kk)                                                       \
  {                                                                               \
    _Pragma("unroll")                                                             \
    for (int r = 0; r < RA; ++r)                                                  \
      gload16(Ast + (size_t)(r * 64) * lda + (kk), (char*)As[buf] + r * 4096 + wbase); \
    _Pragma("unroll")                                                             \
    for (int r = 0; r < RB; ++r)                                                  \
      gload16(Bst + (size_t)(r * 64) * ldb + (kk), (char*)Bs[buf] + r * 4096 + wbase); \
  }

  f32x4 acc[FM][FN] = {};
  STAGE_TILE(0, 0)
  asm volatile("s_waitcnt vmcnt(0)" ::: "memory");
  __syncthreads();
  int cur = 0;
  for (int k0 = 0; k0 < K; k0 += 32) {
    if (k0 + 32 < K) {
      if (cur == 0) STAGE_TILE(1, k0 + 32)
      else          STAGE_TILE(0, k0 + 32)
    }
    short8 af[FM], bfr[FN];
#pragma unroll
    for (int f = 0; f < FM; ++f) {
      const int row = wr * (BM / 2) + f * 16 + l15;
      af[f] = *(const short8*)((char*)As[cur] + row * 64 + ((16 * l4) ^ (((row >> 1) & 3) << 4)));
    }
#pragma unroll
    for (int f = 0; f < FN; ++f) {
      const int row = wc * (BN / 2) + f * 16 + l15;
      bfr[f] = *(const short8*)((char*)Bs[cur] + row * 64 + ((16 * l4) ^ (((row >> 1) & 3) << 4)));
    }
#pragma unroll
    for (int fm = 0; fm < FM; ++fm)
#pragma unroll
      for (int fn = 0; fn < FN; ++fn)
        acc[fm][fn] = __builtin_amdgcn_mfma_f32_16x16x32_bf16(af[fm], bfr[fn], acc[fm][fn], 0, 0, 0);
    asm volatile("s_waitcnt vmcnt(0)" ::: "memory");
    __syncthreads();
    cur ^= 1;
  }
#undef STAGE_TILE
  const int outbf = flags & 1, relu = flags & 4;
  const bool kpk = (flags & 16) && (n0 >= 1024) && (n0 < 2048);
#pragma unroll
  for (int fm = 0; fm < FM; ++fm) {
#pragma unroll
    for (int fn = 0; fn < FN; ++fn) {
      const int col = n0 + wc * (BN / 2) + fn * 16 + l15;
      const int rw0 = m0 + wr * (BM / 2) + fm * 16 + l4 * 4;
      const float bv = (bias && zc == 0) ? bias[(size_t)zb * biasStrB + (size_t)zn * biasStrN + col] : 0.f;
#pragma unroll
      for (int r = 0; r < 4; ++r) {
        float v = (acc[fm][fn][r] + bv) * scale;
        if (relu) v = fmaxf(v, 0.f);
        const int row = rw0 + r;
        if (kpk) {
          // packed K: aux[(row&3)*16 + (col-1024)/64][row>>2][col&63]
          const int bnn = ((row & 3) << 4) + ((col - 1024) >> 6);
          aux[(size_t)bnn * 65536 + (size_t)(row >> 2) * 64 + (col & 63)] = __float2bfloat16(v);
        } else {
          const size_t cOff = (size_t)zb * cStrB + (size_t)zn * cStrN + (size_t)zc * cSplitStr;
          if (outbf) {
            ((bf16*)C + cOff)[(size_t)row * ldc + col] = __float2bfloat16(v);
          } else {
            ((float*)C + cOff)[(size_t)row * ldc + col] = v;
          }
        }
      }
    }
  }
}

// ================= V transpose (j-tile blocked); K packed by qkv GEMM epilogue =================
__global__ __launch_bounds__(256) void vt_kernel(const bf16* __restrict__ wh,
                                                 bf16* __restrict__ vt)
{
  const int bn = blockIdx.y, b = bn >> 4, n = bn & 15;
  const int j0 = blockIdx.x * 64;
  __shared__ bf16 t[64][72];
  const bf16* src = wh + (size_t)b * 3072 + 2048 + n * 64;
  const int tid = threadIdx.x;
#pragma unroll
  for (int r = 0; r < 16; ++r) {
    const int jl = r * 4 + (tid >> 6), d = tid & 63;
    t[jl][d] = src[(size_t)(j0 + jl) * 12288 + d];
  }
  __syncthreads();
  bf16* dst = vt + (size_t)bn * 65536 + (size_t)j0 * 64;   // block [d][64]
#pragma unroll
  for (int r = 0; r < 16; ++r) {
    const int d = r * 4 + (tid >> 6), j = tid & 63;
    dst[(size_t)d * 64 + j] = t[j][d];
  }
}

// ================= rk repack: rkn[l][n][p][64] =================
__global__ __launch_bounds__(256) void rkpack_kernel(const bf16* __restrict__ rkb,
                                                     bf16* __restrict__ rkn)
{
  const int ln = blockIdx.y, l = ln >> 4, n = ln & 15;
  const int p0 = blockIdx.x * 64;
  const int d = threadIdx.x & 63, pr = threadIdx.x >> 6;
  const bf16* src = rkb + (size_t)l * 1048576 + n * 64 + d;
  bf16* dst = rkn + (size_t)ln * 65536 + d;
#pragma unroll
  for (int r = 0; r < 16; ++r) {
    const int p = p0 + r * 4 + pr;
    dst[(size_t)p * 64] = src[(size_t)p * 1024];
  }
}

// ================= fused flash attention, split-KV x2, LDS-staged K/V/rk =================
// Base-2 softmax: log2(e) folded into Qa/Qb scale -> exp2 everywhere (pm in base-2 domain).
// Split-KV x2 (was x4): residency is 3 WG/CU = 768 slots, so 1024 WGs x 2x-work has the
// same compute makespan as 2048 x 1x, but halves po/pm/pl partial traffic.
__global__ __launch_bounds__(256) void fattn_kernel(
    const bf16* __restrict__ wh,     // 4096 x 3072 (row = 4*token + b) — Q only
    const bf16* __restrict__ kb,     // [bn][1024 j][64 d]
    const bf16* __restrict__ rkn_l,  // [16 n][1024 p][64 d] (this layer, 16 KB guard after)
    const bf16* __restrict__ vt,     // [bn][16 jt][64 d][64 jl]
    const float* __restrict__ rwb,   // 16 x 64 (this layer)
    const float* __restrict__ rrb,   // 16 x 64
    float* __restrict__ po, float* __restrict__ pm, float* __restrict__ pl)
{
  const int bn = blockIdx.x, b = bn >> 4, n = bn & 15;
  const int q0 = blockIdx.y * 64;
  const int ck = blockIdx.z;
  const int tid = threadIdx.x, w = tid >> 6, lane = tid & 63;
  const int l15 = lane & 15, l4 = lane >> 4;
  __shared__ __align__(16) bf16 Ks[64 * 64];    // 8 KB  [row j][128 B]
  __shared__ __align__(16) bf16 Vs[64 * 64];    // 8 KB  [row d][128 B]
  __shared__ __align__(16) bf16 Rs[128 * 64];   // 16 KB [row p-pstart][128 B]
  __shared__ bf16 Tl[4][16][84];                // wave-private shifted-BD band strips
  __shared__ bf16 Pl[4][16][72];                // wave-private P transpose staging

  // ---- load Q fragments; fold biases AND 0.125*log2(e) scale (base-2 softmax domain) ----
  short8 qa[2], qb[2];
  {
    const bf16* qp = wh + (size_t)(2048 + b) * 3072 + (size_t)(q0 + 16 * w + l15) * 12288 + n * 64;
    const float sc2 = 0.125f * LOG2E;
#pragma unroll
    for (int kk = 0; kk < 2; ++kk) {
      const short8 qv = *(const short8*)(qp + kk * 32 + 8 * l4);
      const float* wv = rwb + n * 64 + kk * 32 + 8 * l4;
      const float* rv = rrb + n * 64 + kk * 32 + 8 * l4;
      short8 a, c;
#pragma unroll
      for (int e = 0; e < 8; ++e) {
        const float q = __bfloat162float(bits2bf(qv[e]));
        const bf16 ab = __float2bfloat16((q + wv[e]) * sc2);
        const bf16 cb = __float2bfloat16((q + rv[e]) * sc2);
        a[e] = *(const short*)&ab;  c[e] = *(const short*)&cb;
      }
      qa[kk] = a; qb[kk] = c;
    }
  }

  const bf16* kbase = kb + (size_t)bn * 65536;                  // + j*64
  const bf16* rbase = rkn_l + (size_t)n * 65536;                // + p*64
  const bf16* vbase = vt + (size_t)bn * 65536;                  // + j0*64 + d*64 + jl
  const int ntiles = 9 + (q0 >> 6);

  // staging geometry: thread tid covers linear LDS bytes [tid*16, tid*16+16) per 4 KB slab
  const int stRow0 = tid >> 3;                  // row within 4 KB slab (32 rows/slab)
  const int stColb = (tid & 7) * 16;
  const int wbase = w * 1024;                   // wave-uniform LDS base within slab
  const int srd = (l15 & 7) << 4;               // read-side swizzle (== row&7 <<4 for all reads)

  f32x4 accO[4] = {};
  float mrow[4] = { -1e30f, -1e30f, -1e30f, -1e30f };
  float lrow[4] = { 0.f, 0.f, 0.f, 0.f };

  for (int t = ck; t < ntiles; t += 2) {
    const int j0 = t * 64;
    const int pstart = j0 - q0 + 448;           // Rs row 0 == global p = pstart (>= 0)
    // ---- stage K/V tiles + rk band into LDS (once per WG) ----
    __syncthreads();                            // previous tile fully consumed
    {
#pragma unroll
      for (int r = 0; r < 2; ++r) {             // K: 2 slabs of 4 KB
        const int row = r * 32 + stRow0;
        gload16(kbase + (size_t)(j0 + row) * 64 + ((stColb ^ ((row & 7) << 4)) >> 1),
                (char*)Ks + r * 4096 + wbase);
      }
#pragma unroll
      for (int r = 0; r < 2; ++r) {             // V: 2 slabs
        const int row = r * 32 + stRow0;
        gload16(vbase + (size_t)j0 * 64 + (size_t)row * 64 + ((stColb ^ ((row & 7) << 4)) >> 1),
                (char*)Vs + r * 4096 + wbase);
      }
#pragma unroll
      for (int r = 0; r < 4; ++r) {             // rk band: 4 slabs (128 rows)
        const int row = r * 32 + stRow0;
        gload16(rbase + (size_t)(pstart + row) * 64 + ((stColb ^ ((row & 7) << 4)) >> 1),
                (char*)Rs + r * 4096 + wbase);
      }
    }
    asm volatile("s_waitcnt vmcnt(0)" ::: "memory");
    __syncthreads();

    // ---- AC: S[fn] = Qa . K^T (from LDS, swizzled) ----
    f32x4 S[4] = {};
#pragma unroll
    for (int fn = 0; fn < 4; ++fn)
#pragma unroll
      for (int kk = 0; kk < 2; ++kk) {
        const short8 kf = *(const short8*)((char*)Ks + (16 * fn + l15) * 128 + ((kk * 64 + 16 * l4) ^ srd));
        S[fn] = __builtin_amdgcn_mfma_f32_16x16x32_bf16(qa[kk], kf, S[fn], 0, 0, 0);
      }
    // ---- BD band: rows (3-w)*16 + 16*ftl + l15 of Rs ----
    {
      f32x4 T[5] = {};
#pragma unroll
      for (int ftl = 0; ftl < 5; ++ftl) {
        const int rrow = (3 - w) * 16 + 16 * ftl + l15;
#pragma unroll
        for (int kk = 0; kk < 2; ++kk) {
          const short8 rf = *(const short8*)((char*)Rs + rrow * 128 + ((kk * 64 + 16 * l4) ^ srd));
          T[ftl] = __builtin_amdgcn_mfma_f32_16x16x32_bf16(qb[kk], rf, T[ftl], 0, 0, 0);
        }
      }
#pragma unroll
      for (int ftl = 0; ftl < 5; ++ftl)
#pragma unroll
        for (int r = 0; r < 4; ++r)
          Tl[w][4 * l4 + r][16 * ftl + l15] = __float2bfloat16(T[ftl][r]);
    }
    // ---- shift-add + mask ----
    const bool fullvalid = (j0 + 63) <= (512 + q0);
    float sv[4][4];
#pragma unroll
    for (int fn = 0; fn < 4; ++fn)
#pragma unroll
      for (int r = 0; r < 4; ++r) {
        const int il = 4 * l4 + r;
        const float tshift = __bfloat162float(Tl[w][il][16 * fn + l15 + 15 - il]);
        const float s = S[fn][r] + tshift;
        const bool valid = fullvalid || (j0 + 16 * fn + l15 - 512 <= q0 + 16 * w + il);
        sv[fn][r] = valid ? s : -1e30f;
      }
    // ---- online softmax, base-2 (row = 16-lane group) ----
#pragma unroll
    for (int r = 0; r < 4; ++r) {
      float m4 = fmaxf(fmaxf(sv[0][r], sv[1][r]), fmaxf(sv[2][r], sv[3][r]));
      m4 = fmaxf(m4, __shfl_xor(m4, 1));
      m4 = fmaxf(m4, __shfl_xor(m4, 2));
      m4 = fmaxf(m4, __shfl_xor(m4, 4));
      m4 = fmaxf(m4, __shfl_xor(m4, 8));
      const float mn = fmaxf(mrow[r], m4);
      const float alpha = exp2f(mrow[r] - mn);
      mrow[r] = mn;
      float ps = 0.f;
#pragma unroll
      for (int fn = 0; fn < 4; ++fn) {
        sv[fn][r] = exp2f(sv[fn][r] - mn);
        ps += sv[fn][r];
      }
      ps += __shfl_xor(ps, 1);
      ps += __shfl_xor(ps, 2);
      ps += __shfl_xor(ps, 4);
      ps += __shfl_xor(ps, 8);
      lrow[r] = lrow[r] * alpha + ps;
#pragma unroll
      for (int fd = 0; fd < 4; ++fd) accO[fd][r] *= alpha;
    }
    // ---- P -> LDS (transpose to A-frag) and PV (V from LDS, swizzled) ----
#pragma unroll
    for (int fn = 0; fn < 4; ++fn)
#pragma unroll
      for (int r = 0; r < 4; ++r)
        Pl[w][4 * l4 + r][16 * fn + l15] = __float2bfloat16(sv[fn][r]);
    short8 pa[2];
    pa[0] = *(const short8*)&Pl[w][l15][8 * l4];
    pa[1] = *(const short8*)&Pl[w][l15][32 + 8 * l4];
#pragma unroll
    for (int fd = 0; fd < 4; ++fd)
#pragma unroll
      for (int kk = 0; kk < 2; ++kk) {
        const short8 vf = *(const short8*)((char*)Vs + (16 * fd + l15) * 128 + ((kk * 64 + 16 * l4) ^ srd));
        accO[fd] = __builtin_amdgcn_mfma_f32_16x16x32_bf16(pa[kk], vf, accO[fd], 0, 0, 0);
      }
  }
  // ---- store unnormalized partials (pm in base-2 domain) ----
  const int cb = ck * 64 + bn;
  float* pob = po + (size_t)cb * 512 * 64;
#pragma unroll
  for (int fd = 0; fd < 4; ++fd)
#pragma unroll
    for (int r = 0; r < 4; ++r) {
      const int row = q0 + 16 * w + 4 * l4 + r;
      pob[(size_t)row * 64 + 16 * fd + l15] = accO[fd][r];
    }
  if (l15 == 0) {
#pragma unroll
    for (int r = 0; r < 4; ++r) {
      const int row = q0 + 16 * w + 4 * l4 + r;
      pm[(size_t)cb * 512 + row] = mrow[r];
      pl[(size_t)cb * 512 + row] = lrow[r];
    }
  }
}

// ================= merge 2 split-KV partials -> av bf16 (base-2 weights) =================
__global__ __launch_bounds__(256) void fmerge_kernel(
    const float* __restrict__ po, const float* __restrict__ pm,
    const float* __restrict__ pl, bf16* __restrict__ av)
{
  const long i = ((long)blockIdx.x * 256 + threadIdx.x) * 4;   // over 64*512*64
  const long bnq = i >> 6;                                     // bn*512 + q
  const int d4 = (int)(i & 63);
  const int bn = (int)(bnq >> 9), q = (int)(bnq & 511);
  const int b = bn >> 4, n = bn & 15;
  float mv[2], lv[2];
#pragma unroll
  for (int c = 0; c < 2; ++c) { mv[c] = pm[c * 32768 + bnq]; lv[c] = pl[c * 32768 + bnq]; }
  const float m = fmaxf(mv[0], mv[1]);
  float wv[2], den = 0.f;
#pragma unroll
  for (int c = 0; c < 2; ++c) { wv[c] = exp2f(mv[c] - m); den += wv[c] * lv[c]; }
  const float inv = 1.f / den;
  float4 o = { 0.f, 0.f, 0.f, 0.f };
#pragma unroll
  for (int c = 0; c < 2; ++c) {
    const float4 oc = *(const float4*)(po + (size_t)c * 2097152 + bnq * 64 + d4);
    o.x += wv[c] * oc.x; o.y += wv[c] * oc.y; o.z += wv[c] * oc.z; o.w += wv[c] * oc.w;
  }
  bf16* dst = av + (size_t)(q * 4 + b) * 1024 + n * 64 + d4;
  dst[0] = __float2bfloat16(o.x * inv);
  dst[1] = __float2bfloat16(o.y * inv);
  dst[2] = __float2bfloat16(o.z * inv);
  dst[3] = __float2bfloat16(o.w * inv);
}

// ================= cat_out = bf16(LN(hin + x0 + x1)); residual stream lives in bf16 =================
__global__ __launch_bounds__(256) void add_ln_kernel(
    const bf16* __restrict__ hin,
    const bf16* __restrict__ x0, const bf16* __restrict__ x1,
    const float* __restrict__ g, const float* __restrict__ bb, bf16* __restrict__ cat_out)
{
  const long o = (long)blockIdx.x * DM;
  const int tid = threadIdx.x;
  __shared__ float red[256];
  float v0 = __bfloat162float(hin[o + tid])       + __bfloat162float(x0[o + tid])       + __bfloat162float(x1[o + tid]);
  float v1 = __bfloat162float(hin[o + tid + 256]) + __bfloat162float(x0[o + tid + 256]) + __bfloat162float(x1[o + tid + 256]);
  float v2 = __bfloat162float(hin[o + tid + 512]) + __bfloat162float(x0[o + tid + 512]) + __bfloat162float(x1[o + tid + 512]);
  float v3 = __bfloat162float(hin[o + tid + 768]) + __bfloat162float(x0[o + tid + 768]) + __bfloat162float(x1[o + tid + 768]);
  red[tid] = v0 + v1 + v2 + v3; __syncthreads();
  for (int off = 128; off; off >>= 1) { if (tid < off) red[tid] += red[tid + off]; __syncthreads(); }
  const float mean = red[0] * (1.f / DM); __syncthreads();
  const float d0 = v0 - mean, d1 = v1 - mean, d2 = v2 - mean, d3 = v3 - mean;
  red[tid] = d0 * d0 + d1 * d1 + d2 * d2 + d3 * d3; __syncthreads();
  for (int off = 128; off; off >>= 1) { if (tid < off) red[tid] += red[tid + off]; __syncthreads(); }
  const float inv = rsqrtf(red[0] * (1.f / DM) + 1e-5f);
  cat_out[o + tid]       = __float2bfloat16(d0 * inv * g[tid]       + bb[tid]);
  cat_out[o + tid + 256] = __float2bfloat16(d1 * inv * g[tid + 256] + bb[tid + 256]);
  cat_out[o + tid + 512] = __float2bfloat16(d2 * inv * g[tid + 512] + bb[tid + 512]);
  cat_out[o + tid + 768] = __float2bfloat16(d3 * inv * g[tid + 768] + bb[tid + 768]);
}

// ================= (q,b,d) bf16 -> (b,q,d) fp32 =================
__global__ __launch_bounds__(256) void out_kernel(const bf16* __restrict__ hb, float* __restrict__ out)
{
  const int t = blockIdx.x, q = t >> 2, b = t & 3;
  const bf16* hr = hb + (long)t * DM;
  float* orow = out + ((long)b * QLEN + q) * DM;
  for (int s = 0; s < 4; ++s)
    orow[threadIdx.x + 256 * s] = __bfloat162float(hr[threadIdx.x + 256 * s]);
}

extern "C" void kernel_launch(void* const* d_in, const int* in_sizes, int n_in,
                              void* d_out, int out_size, void* d_ws, size_t ws_size,
                              hipStream_t stream)
{
  const int*   ids  = (const int*)d_in[0];
  const float* mems = (const float*)d_in[1];
  const float* e0 = (const float*)d_in[2]; const float* p0 = (const float*)d_in[3];
  const float* e1 = (const float*)d_in[4]; const float* p1 = (const float*)d_in[5];
  const float* e2 = (const float*)d_in[6]; const float* p2 = (const float*)d_in[7];
  const float* e3 = (const float*)d_in[8]; const float* p3 = (const float*)d_in[9];
  const float* qkvw = (const float*)d_in[10];
  const float* rnet = (const float*)d_in[11];
  const float* ow   = (const float*)d_in[12];
  const float* rwb  = (const float*)d_in[13];
  const float* rrb  = (const float*)d_in[14];
  const float* ln1g = (const float*)d_in[15];
  const float* ln1b = (const float*)d_in[16];
  const float* fw1  = (const float*)d_in[17];
  const float* fb1  = (const float*)d_in[18];
  const float* fw2  = (const float*)d_in[19];
  const float* fb2  = (const float*)d_in[20];
  const float* ln2g = (const float*)d_in[21];
  const float* ln2b = (const float*)d_in[22];
  float* out = (float*)d_out;

  // -------- workspace layout --------
  char* p = (char*)d_ws;
  p += (size_t)2048 * 1024 * 4;                                           // 8 MB (reserved)
  bf16*  cat0 = (bf16*)p;             p += (size_t)5 * 4096 * 1024 * 2;   // 40 MB (cats[0..4]; upper = residual)
  bf16*  pe   = (bf16*)p;             p += (size_t)1024 * 1024 * 2;       // 2 MB
  bf16*  rkb  = (bf16*)p;             p += (size_t)4 * 1024 * 1024 * 2;   // 8 MB (all layers, [p][1024])
  bf16*  rkn  = (bf16*)p;             p += (size_t)(4 * 16 * 1024 * 64 + 8192) * 2; // 8 MB + 16 KB guard
  bf16*  wh   = (bf16*)p;             p += (size_t)4096 * 3072 * 2;       // 24 MB
  bf16*  vt   = (bf16*)p;             p += (size_t)64 * 64 * 1024 * 2;    // 8 MB (j-blocked V^T)
  bf16*  kb   = (bf16*)p;             p += (size_t)64 * 1024 * 64 * 2;    // 8 MB (packed K)
  bf16*  qkvT = (bf16*)p;             p += (size_t)4 * 3072 * 1024 * 2;   // 24 MB
  bf16*  rnT  = (bf16*)p;             p += (size_t)4 * 1024 * 1024 * 2;   // 8 MB
  bf16*  oT   = (bf16*)p;             p += (size_t)4 * 1024 * 1024 * 2;   // 8 MB
  bf16*  f1T  = (bf16*)p;             p += (size_t)4 * 4096 * 1024 * 2;   // 32 MB
  bf16*  f2T  = (bf16*)p;             p += (size_t)4 * 4096 * 1024 * 2;   // 32 MB
  // 64 MB region A: mid (FFN) / partE (embed, 16 MB fp32)
  bf16*  mid  = (bf16*)p;
  float* partE= (float*)p;
  p += (size_t)4 * 16 * 512 * 1024 * 2;                                   // 64 MB
  // 64 MB region B: Aemb+projT (embed) / attn partials po/pm/pl / partPb (bf16 split-K partials)
  bf16*  Aemb = (bf16*)p;
  bf16*  projT= (bf16*)(p + (size_t)2048 * KEMB * 2);
  bf16*  partPb = (bf16*)p;                                   // 2 x 2048x1024 bf16 = 8 MB
  float* po   = (float*)p;                                    // 2*64*512*64 fp32 = 16 MB
  float* pm   = (float*)(p + (size_t)32 * 1024 * 1024);       // 256 KB
  float* pl   = (float*)(p + (size_t)33 * 1024 * 1024);       // 256 KB
  p += (size_t)4 * 16 * 512 * 1024 * 2;                                   // 64 MB
  bf16*  av   = (bf16*)p;             p += (size_t)2048 * 1024 * 2;       // 4 MB

  // NOTE: partPb (proj/ffn2 partials) and po/pm/pl (attn partials) share region B
  // but are used in disjoint phases. The residual stream lives in the bf16 upper
  // halves of cats[l].

  // -------- upfront: embedding, pos-emb, mems conversion, ALL weight transposes --------
  embA_kernel<<<2048, 256, 0, stream>>>(ids, e0, e1, e2, e3, Aemb);
  projT_kernel<<<dim3(KEMB / 32, 32), 256, 0, stream>>>(p0, p1, p2, p3, projT);
  gemm_bf16<128, 64><<<dim3(16, 16, 2), 256, 0, stream>>>(
      Aemb, 0, 0, KEMB, projT, 0, 0, KEMB, partE, 0, 0, 1024,
      KEMB / 2, 32.f, nullptr, 0, 0, 0, 1, 2, 2097152, nullptr);
  embsum_kernel<<<2048, 256, 0, stream>>>(partE, cat0);
  posemb_kernel<<<1024, 256, 0, stream>>>(pe);
  memsconv_kernel<<<8192, 256, 0, stream>>>(mems, cat0);

  wtrans_kernel<<<dim3(96, 32, 4), 256, 0, stream>>>(qkvw, qkvT, DM, 3072);
  wtrans_kernel<<<dim3(32, 32, 4), 256, 0, stream>>>(rnet, rnT, DM, DM);
  wtrans_kernel<<<dim3(32, 32, 4), 256, 0, stream>>>(ow, oT, DM, DM);
  wtrans_kernel<<<dim3(128, 32, 4), 256, 0, stream>>>(fw1, f1T, DM, DI);
  wtrans_kernel<<<dim3(32, 128, 4), 256, 0, stream>>>(fw2, f2T, DI, DM);

  // rk = pos_emb @ r_net_w for ALL layers (z = layer), then repack to [l][n][p][64]
  gemm_bf16<128, 128><<<dim3(8, 8, 4), 256, 0, stream>>>(
      pe, 0, 0, 1024, rnT, 1048576, 0, 1024, rkb, 1048576, 0, 1024,
      1024, 1.f, nullptr, 0, 0, 1, 1, 1, 0, nullptr);
  rkpack_kernel<<<dim3(16, 64), 256, 0, stream>>>(rkb, rkn);

  for (int l = 0; l < NL; ++l) {
    bf16* catl = cat0 + (size_t)l * 4194304;
    bf16* resl = catl + (size_t)2048 * 1024;     // residual stream (cat upper)
    // w_heads = cat @ qkv_w -> wh (Q/V cols) + kb (K cols packed, flag 16); XCD swizzle
    gemm_bf16<128, 128><<<dim3(24, 32, 1), 256, 0, stream>>>(
        catl, 0, 0, 1024, qkvT + (size_t)l * 3145728, 0, 0, 1024, wh, 0, 0, 3072,
        1024, 1.f, nullptr, 0, 0, 1 | 8 | 16, 1, 1, 0, kb);

    vt_kernel<<<dim3(16, 64), 256, 0, stream>>>(wh, vt);

    // fused flash attention, split-KV x2 -> partials, then merge -> av (bf16)
    fattn_kernel<<<dim3(64, 8, 2), 256, 0, stream>>>(
        wh, kb, rkn + (size_t)l * 1048576, vt,
        rwb + l * NH * DH, rrb + l * NH * DH, po, pm, pl);
    fmerge_kernel<<<2048, 256, 0, stream>>>(po, pm, pl, av);

    // attn_out = av @ o_w (split-K x2, bf16 partials into partPb), summed in add_ln
    gemm_bf16<128, 64><<<dim3(16, 16, 2), 256, 0, stream>>>(
        av, 0, 0, 1024, oT + (size_t)l * 1048576, 0, 0, 1024, partPb, 0, 0, 1024,
        512, 1.f, nullptr, 0, 0, 1, 1, 2, 2097152, nullptr);
    add_ln_kernel<<<2048, 256, 0, stream>>>(resl, partPb, partPb + 2097152,
                                            ln1g + l * DM, ln1b + l * DM, resl);

    // FFN (ffn1 with XCD-chunked swizzle: 512 % 8 == 0)
    gemm_bf16<128, 128><<<dim3(32, 16, 1), 256, 0, stream>>>(
        resl, 0, 0, 1024, f1T + (size_t)l * 4194304, 0, 0, 1024,
        mid, 0, 0, 4096, 1024, 1.f, fb1 + (size_t)l * DI, 0, 0, 1 | 4 | 8, 1, 1, 0, nullptr);
    gemm_bf16<128, 64><<<dim3(16, 16, 2), 256, 0, stream>>>(
        mid, 0, 0, 4096, f2T + (size_t)l * 4194304, 0, 0, 4096, partPb, 0, 0, 1024,
        2048, 1.f, fb2 + (size_t)l * DM, 0, 0, 1, 1, 2, 2097152, nullptr);
    add_ln_kernel<<<2048, 256, 0, stream>>>(resl, partPb, partPb + 2097152,
                                            ln2g + l * DM, ln2b + l * DM,
                                            cat0 + (size_t)(l + 1) * 4194304 + (size_t)2048 * 1024);
  }

  out_kernel<<<2048, 256, 0, stream>>>(cat0 + (size_t)4 * 4194304 + (size_t)2048 * 1024, out);
}